// Round 15
// baseline (2519.500 us; speedup 1.0000x reference)
//
#include <hip/hip_runtime.h>

#define N1 1000000
#define N2 400000
#define N4 150000
#define N8 60000
#define N16 20000

constexpr float BN_EPS = 1e-5f;

__device__ __forceinline__ float lrelu(float x) { return fmaxf(x, 0.1f * x); }

// Fold all BatchNorm params into scale/shift once per call.
__global__ void k_fold(const float* g0, const float* be0, const float* m0, const float* v0,
                       const float* gR, const float* beR, const float* mR, const float* vR,
                       const float* gD, const float* beD, const float* mD, const float* vD,
                       float* fold) {
  int t = threadIdx.x;
  if (t < 32) {
    float sc = g0[t] * rsqrtf(v0[t] + BN_EPS);
    fold[t] = sc;
    fold[32 + t] = be0[t] - m0[t] * sc;
  }
  if (t < 128) {
    int b = t >> 5, c = t & 31;
    float sc = gR[b * 32 + c] * rsqrtf(vR[b * 32 + c] + BN_EPS);
    fold[64 + b * 64 + c] = sc;
    fold[64 + b * 64 + 32 + c] = beR[b * 32 + c] - mR[b * 32 + c] * sc;
  }
  for (int i = t; i < 320; i += blockDim.x) {
    int b = i >> 6, c = i & 63;
    float sc = gD[b * 64 + c] * rsqrtf(vD[b * 64 + c] + BN_EPS);
    fold[320 + b * 128 + c] = sc;
    fold[320 + b * 128 + 64 + c] = beD[b * 64 + c] - mD[b * 64 + c] * sc;
  }
}

// Build per-segment linked lists. head pre-set to -1. One 4B atomic per row.
__global__ __launch_bounds__(256) void k_fill(const int* __restrict__ idx,
                                              int* head, int* nxt, int n) {
  int i = blockIdx.x * 256 + threadIdx.x;
  if (i < n) nxt[i] = atomicExch(&head[idx[i]], i);
}

// Segment max by chained gather: one wave per segment, one thread per channel.
__global__ __launch_bounds__(256) void k_gmax(
    const float* __restrict__ src, const int* __restrict__ head,
    const int* __restrict__ nxt, float* __restrict__ dst, int nseg) {
  int t = blockIdx.x * 256 + threadIdx.x;
  int seg = t >> 6, ch = t & 63;
  if (seg >= nseg) return;
  float m = -INFINITY;
  for (int p = head[seg]; p >= 0; p = nxt[p])
    m = fmaxf(m, src[(size_t)p * 64 + ch]);
  dst[(size_t)seg * 64 + ch] = (m == -INFINITY) ? 0.0f : m;
}

// ---------------- scalar-weight GEMM kernels, wave-staggered k-loops --------
// Weights wave-uniform -> s_load. LDS rows stride 68/36 (conflict-free b128).
// Every k-loop starts wave w at chunk (cc+w)%nchunk: waves touch DIFFERENT
// weight cache lines at any instant -> sL1-miss windows of one wave overlap
// FMA bursts of others (anti-convoy). FP sum reorder only.

// encoder block 0: x[9] -> h[32] (lrelu,BN) -> out[64] (lrelu)
__global__ __launch_bounds__(256) void k_enc0_s(
    const float* __restrict__ x,
    const float* __restrict__ W1, const float* __restrict__ b1,
    const float* __restrict__ fold,
    const float* __restrict__ W2, const float* __restrict__ b2,
    float* __restrict__ out, int n) {
  __shared__ float xS[64 * 9];
  __shared__ float hS[64 * 36];
  int t = threadIdx.x;
  int lane = t & 63;
  int w = __builtin_amdgcn_readfirstlane(t >> 6);
  int R = blockIdx.x * 64;

  {
    size_t lim = (size_t)n * 9 - 1;
    for (int i = t; i < 576; i += 256) {
      size_t gi = (size_t)R * 9 + i;
      if (gi > lim) gi = lim;
      xS[i] = x[gi];
    }
  }
  __syncthreads();

  {
    const float* W1p = W1 + w * 8;
    float xr[9];
#pragma unroll
    for (int k = 0; k < 9; ++k) xr[k] = xS[lane * 9 + k];
    float acc[8];
#pragma unroll
    for (int c = 0; c < 8; ++c) acc[c] = b1[w * 8 + c];
#pragma unroll
    for (int k = 0; k < 9; ++k) {
#pragma unroll
      for (int c = 0; c < 8; ++c) acc[c] = fmaf(xr[k], W1p[k * 32 + c], acc[c]);
    }
    float4 o0, o1;
    o0.x = lrelu(acc[0]) * fold[w * 8 + 0] + fold[32 + w * 8 + 0];
    o0.y = lrelu(acc[1]) * fold[w * 8 + 1] + fold[32 + w * 8 + 1];
    o0.z = lrelu(acc[2]) * fold[w * 8 + 2] + fold[32 + w * 8 + 2];
    o0.w = lrelu(acc[3]) * fold[w * 8 + 3] + fold[32 + w * 8 + 3];
    o1.x = lrelu(acc[4]) * fold[w * 8 + 4] + fold[32 + w * 8 + 4];
    o1.y = lrelu(acc[5]) * fold[w * 8 + 5] + fold[32 + w * 8 + 5];
    o1.z = lrelu(acc[6]) * fold[w * 8 + 6] + fold[32 + w * 8 + 6];
    o1.w = lrelu(acc[7]) * fold[w * 8 + 7] + fold[32 + w * 8 + 7];
    *(float4*)(hS + lane * 36 + w * 8) = o0;
    *(float4*)(hS + lane * 36 + w * 8 + 4) = o1;
  }
  __syncthreads();

  {
    const float* W2p = W2 + w * 16;
    float o[16];
#pragma unroll
    for (int c = 0; c < 16; ++c) o[c] = b2[w * 16 + c];
#pragma unroll
    for (int cc = 0; cc < 4; ++cc) {
      int k0 = ((cc + w) & 3) << 3;  // stagger
      float4 av0 = *(const float4*)(hS + lane * 36 + k0);
      float4 av1 = *(const float4*)(hS + lane * 36 + k0 + 4);
      float a[8] = {av0.x, av0.y, av0.z, av0.w, av1.x, av1.y, av1.z, av1.w};
#pragma unroll
      for (int j = 0; j < 8; ++j) {
#pragma unroll
        for (int c = 0; c < 16; ++c)
          o[c] = fmaf(a[j], W2p[(k0 + j) * 64 + c], o[c]);
      }
    }
    int gr = R + lane;
    if (gr < n) {
      float* op = out + (size_t)gr * 64 + w * 16;
#pragma unroll
      for (int c = 0; c < 16; ++c) op[c] = lrelu(o[c]);
    }
  }
}

// encoder blocks 1..4: in[64] -> h[32] (lrelu,BN) -> out[64] (lrelu)
__global__ __launch_bounds__(256) void k_encR_s(
    const float* __restrict__ xin,
    const float* __restrict__ W1, const float* __restrict__ b1,
    const float* __restrict__ fold,
    const float* __restrict__ W2, const float* __restrict__ b2,
    float* __restrict__ out, int n) {
  __shared__ float inS[64 * 68];
  __shared__ float hS[64 * 36];
  int t = threadIdx.x;
  int lane = t & 63;
  int w = __builtin_amdgcn_readfirstlane(t >> 6);
  int R = blockIdx.x * 64;

  for (int f = t; f < 1024; f += 256) {
    int row = f >> 4, c4 = (f & 15) << 2;
    int gr = R + row; if (gr >= n) gr = n - 1;
    *(float4*)(inS + row * 68 + c4) = *(const float4*)(xin + (size_t)gr * 64 + c4);
  }
  __syncthreads();

  {
    const float* W1p = W1 + w * 8;
    float acc[8];
#pragma unroll
    for (int c = 0; c < 8; ++c) acc[c] = b1[w * 8 + c];
#pragma unroll
    for (int cc = 0; cc < 8; ++cc) {
      int k0 = ((cc + w) & 7) << 3;  // stagger
      float4 av0 = *(const float4*)(inS + lane * 68 + k0);
      float4 av1 = *(const float4*)(inS + lane * 68 + k0 + 4);
      float a[8] = {av0.x, av0.y, av0.z, av0.w, av1.x, av1.y, av1.z, av1.w};
#pragma unroll
      for (int j = 0; j < 8; ++j) {
#pragma unroll
        for (int c = 0; c < 8; ++c)
          acc[c] = fmaf(a[j], W1p[(k0 + j) * 32 + c], acc[c]);
      }
    }
    float4 o0, o1;
    o0.x = lrelu(acc[0]) * fold[w * 8 + 0] + fold[32 + w * 8 + 0];
    o0.y = lrelu(acc[1]) * fold[w * 8 + 1] + fold[32 + w * 8 + 1];
    o0.z = lrelu(acc[2]) * fold[w * 8 + 2] + fold[32 + w * 8 + 2];
    o0.w = lrelu(acc[3]) * fold[w * 8 + 3] + fold[32 + w * 8 + 3];
    o1.x = lrelu(acc[4]) * fold[w * 8 + 4] + fold[32 + w * 8 + 4];
    o1.y = lrelu(acc[5]) * fold[w * 8 + 5] + fold[32 + w * 8 + 5];
    o1.z = lrelu(acc[6]) * fold[w * 8 + 6] + fold[32 + w * 8 + 6];
    o1.w = lrelu(acc[7]) * fold[w * 8 + 7] + fold[32 + w * 8 + 7];
    *(float4*)(hS + lane * 36 + w * 8) = o0;
    *(float4*)(hS + lane * 36 + w * 8 + 4) = o1;
  }
  __syncthreads();

  {
    const float* W2p = W2 + w * 16;
    float o[16];
#pragma unroll
    for (int c = 0; c < 16; ++c) o[c] = b2[w * 16 + c];
#pragma unroll
    for (int cc = 0; cc < 4; ++cc) {
      int k0 = ((cc + w) & 3) << 3;  // stagger
      float4 av0 = *(const float4*)(hS + lane * 36 + k0);
      float4 av1 = *(const float4*)(hS + lane * 36 + k0 + 4);
      float a[8] = {av0.x, av0.y, av0.z, av0.w, av1.x, av1.y, av1.z, av1.w};
#pragma unroll
      for (int j = 0; j < 8; ++j) {
#pragma unroll
        for (int c = 0; c < 16; ++c)
          o[c] = fmaf(a[j], W2p[(k0 + j) * 64 + c], o[c]);
      }
    }
    int gr = R + lane;
    if (gr < n) {
      float* op = out + (size_t)gr * 64 + w * 16;
#pragma unroll
      for (int c = 0; c < 16; ++c) op[c] = lrelu(o[c]);
    }
  }
}

// lastT = src @ decW[64:128] + decb. 512 thr, 8-col x 2-row, 128-row tile.
__global__ __launch_bounds__(512) void k_lastT(
    const float* __restrict__ src, const float* __restrict__ decW,
    const float* __restrict__ decb, float* __restrict__ lT, int n) {
  __shared__ float sS[128 * 68];
  int t = threadIdx.x;
  int lane = t & 63;
  int w = __builtin_amdgcn_readfirstlane(t >> 6);  // 0..7
  int R = blockIdx.x * 128;

  for (int f = t; f < 2048; f += 512) {
    int row = f >> 4, c4 = (f & 15) << 2;
    int gr = R + row; if (gr >= n) gr = n - 1;
    *(float4*)(sS + row * 68 + c4) = *(const float4*)(src + (size_t)gr * 64 + c4);
  }
  __syncthreads();

  const float* Dp = decW + 64 * 64 + w * 8;
  float o0[8], o1[8];
#pragma unroll
  for (int c = 0; c < 8; ++c) { o0[c] = decb[w * 8 + c]; o1[c] = o0[c]; }
#pragma unroll
  for (int cc = 0; cc < 8; ++cc) {
    int k0 = ((cc + w) & 7) << 3;  // stagger
    float4 av0 = *(const float4*)(sS + lane * 68 + k0);
    float4 av1 = *(const float4*)(sS + lane * 68 + k0 + 4);
    float4 bv0 = *(const float4*)(sS + (lane + 64) * 68 + k0);
    float4 bv1 = *(const float4*)(sS + (lane + 64) * 68 + k0 + 4);
    float a[8] = {av0.x, av0.y, av0.z, av0.w, av1.x, av1.y, av1.z, av1.w};
    float b[8] = {bv0.x, bv0.y, bv0.z, bv0.w, bv1.x, bv1.y, bv1.z, bv1.w};
#pragma unroll
    for (int j = 0; j < 8; ++j) {
#pragma unroll
      for (int c = 0; c < 8; ++c) {
        float wv = Dp[(k0 + j) * 64 + c];
        o0[c] = fmaf(a[j], wv, o0[c]);
        o1[c] = fmaf(b[j], wv, o1[c]);
      }
    }
  }
  int g0 = R + lane, g1 = R + 64 + lane;
  if (g0 < n) {
    float* op = lT + (size_t)g0 * 64 + w * 8;
#pragma unroll
    for (int c = 0; c < 8; ++c) op[c] = o0[c];
  }
  if (g1 < n) {
    float* op = lT + (size_t)g1 * 64 + w * 8;
#pragma unroll
    for (int c = 0; c < 8; ++c) op[c] = o1[c];
  }
}

// decoder: out = lrelu(BN(lrelu(cur@mlpW+mlpb) @ decW[0:64] + lastT[lrow]))
// In place. 512 thr (8 waves), 8-col x 2-row, 128-row tile, 34.8 KB LDS.
__global__ __launch_bounds__(512) void k_dec2(
    float* inout, const float* __restrict__ lT, const int* __restrict__ idx,
    const float* __restrict__ mlpW, const float* __restrict__ mlpb,
    const float* __restrict__ decW, const float* __restrict__ fold, int n) {
  __shared__ float curS[128 * 68];
  int t = threadIdx.x;
  int lane = t & 63;
  int w = __builtin_amdgcn_readfirstlane(t >> 6);  // 0..7
  int R = blockIdx.x * 128;

  for (int f = t; f < 2048; f += 512) {
    int row = f >> 4, c4 = (f & 15) << 2;
    int gr = R + row; if (gr >= n) gr = n - 1;
    *(float4*)(curS + row * 68 + c4) = *(const float4*)(inout + (size_t)gr * 64 + c4);
  }
  __syncthreads();

  // phase 1: skip cols 8w..8w+7 for rows lane, lane+64; K=64, staggered
  float s0[8], s1[8];
  {
    const float* Mp = mlpW + w * 8;
#pragma unroll
    for (int c = 0; c < 8; ++c) { s0[c] = mlpb[w * 8 + c]; s1[c] = s0[c]; }
#pragma unroll
    for (int cc = 0; cc < 8; ++cc) {
      int k0 = ((cc + w) & 7) << 3;  // stagger
      float4 av0 = *(const float4*)(curS + lane * 68 + k0);
      float4 av1 = *(const float4*)(curS + lane * 68 + k0 + 4);
      float4 bv0 = *(const float4*)(curS + (lane + 64) * 68 + k0);
      float4 bv1 = *(const float4*)(curS + (lane + 64) * 68 + k0 + 4);
      float a[8] = {av0.x, av0.y, av0.z, av0.w, av1.x, av1.y, av1.z, av1.w};
      float b[8] = {bv0.x, bv0.y, bv0.z, bv0.w, bv1.x, bv1.y, bv1.z, bv1.w};
#pragma unroll
      for (int j = 0; j < 8; ++j) {
#pragma unroll
        for (int c = 0; c < 8; ++c) {
          float wv = Mp[(k0 + j) * 64 + c];
          s0[c] = fmaf(a[j], wv, s0[c]);
          s1[c] = fmaf(b[j], wv, s1[c]);
        }
      }
    }
  }
  __syncthreads();  // all reads of curS done
  {
    float4 t0 = {lrelu(s0[0]), lrelu(s0[1]), lrelu(s0[2]), lrelu(s0[3])};
    float4 t1 = {lrelu(s0[4]), lrelu(s0[5]), lrelu(s0[6]), lrelu(s0[7])};
    *(float4*)(curS + lane * 68 + w * 8 + 0) = t0;
    *(float4*)(curS + lane * 68 + w * 8 + 4) = t1;
    float4 u0 = {lrelu(s1[0]), lrelu(s1[1]), lrelu(s1[2]), lrelu(s1[3])};
    float4 u1 = {lrelu(s1[4]), lrelu(s1[5]), lrelu(s1[6]), lrelu(s1[7])};
    *(float4*)(curS + (lane + 64) * 68 + w * 8 + 0) = u0;
    *(float4*)(curS + (lane + 64) * 68 + w * 8 + 4) = u1;
  }
  __syncthreads();

  // phase 2: out = skip @ decW_top + lastT[lrow], K=64, staggered
  {
    int g0r = R + lane; if (g0r >= n) g0r = n - 1;
    int g1r = R + 64 + lane; if (g1r >= n) g1r = n - 1;
    int g0i = idx ? idx[g0r] : g0r;
    int g1i = idx ? idx[g1r] : g1r;
    const float* lpa = lT + (size_t)g0i * 64 + w * 8;
    const float* lpb = lT + (size_t)g1i * 64 + w * 8;
    float4 la0 = *(const float4*)(lpa + 0);
    float4 la1 = *(const float4*)(lpa + 4);
    float4 lb0 = *(const float4*)(lpb + 0);
    float4 lb1 = *(const float4*)(lpb + 4);

    float o0[8], o1[8];
    o0[0] = la0.x; o0[1] = la0.y; o0[2] = la0.z; o0[3] = la0.w;
    o0[4] = la1.x; o0[5] = la1.y; o0[6] = la1.z; o0[7] = la1.w;
    o1[0] = lb0.x; o1[1] = lb0.y; o1[2] = lb0.z; o1[3] = lb0.w;
    o1[4] = lb1.x; o1[5] = lb1.y; o1[6] = lb1.z; o1[7] = lb1.w;

    const float* Dp = decW + w * 8;
#pragma unroll
    for (int cc = 0; cc < 8; ++cc) {
      int k0 = ((cc + w) & 7) << 3;  // stagger
      float4 av0 = *(const float4*)(curS + lane * 68 + k0);
      float4 av1 = *(const float4*)(curS + lane * 68 + k0 + 4);
      float4 bv0 = *(const float4*)(curS + (lane + 64) * 68 + k0);
      float4 bv1 = *(const float4*)(curS + (lane + 64) * 68 + k0 + 4);
      float a[8] = {av0.x, av0.y, av0.z, av0.w, av1.x, av1.y, av1.z, av1.w};
      float b[8] = {bv0.x, bv0.y, bv0.z, bv0.w, bv1.x, bv1.y, bv1.z, bv1.w};
#pragma unroll
      for (int j = 0; j < 8; ++j) {
#pragma unroll
        for (int c = 0; c < 8; ++c) {
          float wv = Dp[(k0 + j) * 64 + c];
          o0[c] = fmaf(a[j], wv, o0[c]);
          o1[c] = fmaf(b[j], wv, o1[c]);
        }
      }
    }
    int g0 = R + lane, g1 = R + 64 + lane;
    if (g0 < n) {
      float* op = inout + (size_t)g0 * 64 + w * 8;
#pragma unroll
      for (int c = 0; c < 8; ++c) {
        float sc = fold[w * 8 + c], sh = fold[64 + w * 8 + c];
        op[c] = lrelu(o0[c] * sc + sh);
      }
    }
    if (g1 < n) {
      float* op = inout + (size_t)g1 * 64 + w * 8;
#pragma unroll
      for (int c = 0; c < 8; ++c) {
        float sc = fold[w * 8 + c], sh = fold[64 + w * 8 + c];
        op[c] = lrelu(o1[c] * sc + sh);
      }
    }
  }
}

extern "C" void kernel_launch(void* const* d_in, const int* in_sizes, int n_in,
                              void* d_out, int out_size, void* d_ws, size_t ws_size,
                              hipStream_t stream) {
  const float* pt   = (const float*)d_in[0];
  const int* inv2   = (const int*)d_in[1];
  const int* inv4   = (const int*)d_in[2];
  const int* inv8   = (const int*)d_in[3];
  const int* inv16  = (const int*)d_in[4];
  const float* e0W1 = (const float*)d_in[5];
  const float* e0b1 = (const float*)d_in[6];
  const float* e0g  = (const float*)d_in[7];
  const float* e0be = (const float*)d_in[8];
  const float* e0m  = (const float*)d_in[9];
  const float* e0v  = (const float*)d_in[10];
  const float* e0W2 = (const float*)d_in[11];
  const float* e0b2 = (const float*)d_in[12];
  const float* eRW1 = (const float*)d_in[13];
  const float* eRb1 = (const float*)d_in[14];
  const float* eRg  = (const float*)d_in[15];
  const float* eRbe = (const float*)d_in[16];
  const float* eRm  = (const float*)d_in[17];
  const float* eRv  = (const float*)d_in[18];
  const float* eRW2 = (const float*)d_in[19];
  const float* eRb2 = (const float*)d_in[20];
  const float* mlpW = (const float*)d_in[21];
  const float* mlpb = (const float*)d_in[22];
  const float* decW = (const float*)d_in[23];
  const float* decb = (const float*)d_in[24];
  const float* decg = (const float*)d_in[25];
  const float* decbe= (const float*)d_in[26];
  const float* decm = (const float*)d_in[27];
  const float* decv = (const float*)d_in[28];

  float* s1 = (float*)d_out;
  float* s2 = s1 + (size_t)N1 * 64;
  float* s3 = s2 + (size_t)N2 * 64;
  float* s4 = s3 + (size_t)N4 * 64;
  float* s5 = s4 + (size_t)N8 * 64;

  // workspace: fold | oA (N2*64 f, reused as lastT) | oB (N4*64 f) | head | nxt
  float* fold = (float*)d_ws;
  float* oA   = fold + 1024;
  float* oB   = oA + (size_t)N2 * 64;
  int* head   = (int*)(oB + (size_t)N4 * 64);
  int* nxt    = head + N2;
  float* lT   = oA;  // free after encoders

  k_fold<<<1, 320, 0, stream>>>(e0g, e0be, e0m, e0v, eRg, eRbe, eRm, eRv,
                                decg, decbe, decm, decv, fold);

  // ---- level 1: enc0 on N1, pool -> oA [N2] ----
  hipMemsetAsync(head, 0xFF, (size_t)N2 * 4, stream);
  k_fill<<<(N1 + 255) / 256, 256, 0, stream>>>(inv2, head, nxt, N1);
  k_enc0_s<<<(N1 + 63) / 64, 256, 0, stream>>>(pt, e0W1, e0b1, fold, e0W2, e0b2, s1, N1);
  k_gmax<<<((size_t)N2 * 64 + 255) / 256, 256, 0, stream>>>(s1, head, nxt, oA, N2);

  // ---- level 2: encR[0] on N2, pool -> oB [N4] ----
  hipMemsetAsync(head, 0xFF, (size_t)N4 * 4, stream);
  k_fill<<<(N2 + 255) / 256, 256, 0, stream>>>(inv4, head, nxt, N2);
  k_encR_s<<<(N2 + 63) / 64, 256, 0, stream>>>(oA, eRW1 + 0 * 2048, eRb1 + 0 * 32,
                                               fold + 64 + 0 * 64, eRW2 + 0 * 2048,
                                               eRb2 + 0 * 64, s2, N2);
  k_gmax<<<((size_t)N4 * 64 + 255) / 256, 256, 0, stream>>>(s2, head, nxt, oB, N4);

  // ---- level 3: encR[1] on N4, pool -> oA [N8] ----
  hipMemsetAsync(head, 0xFF, (size_t)N8 * 4, stream);
  k_fill<<<(N4 + 255) / 256, 256, 0, stream>>>(inv8, head, nxt, N4);
  k_encR_s<<<(N4 + 63) / 64, 256, 0, stream>>>(oB, eRW1 + 1 * 2048, eRb1 + 1 * 32,
                                               fold + 64 + 1 * 64, eRW2 + 1 * 2048,
                                               eRb2 + 1 * 64, s3, N4);
  k_gmax<<<((size_t)N8 * 64 + 255) / 256, 256, 0, stream>>>(s3, head, nxt, oA, N8);

  // ---- level 4: encR[2] on N8, pool -> oB [N16] ----
  hipMemsetAsync(head, 0xFF, (size_t)N16 * 4, stream);
  k_fill<<<(N8 + 255) / 256, 256, 0, stream>>>(inv16, head, nxt, N8);
  k_encR_s<<<(N8 + 63) / 64, 256, 0, stream>>>(oA, eRW1 + 2 * 2048, eRb1 + 2 * 32,
                                               fold + 64 + 2 * 64, eRW2 + 2 * 2048,
                                               eRb2 + 2 * 64, s4, N8);
  k_gmax<<<((size_t)N16 * 64 + 255) / 256, 256, 0, stream>>>(s4, head, nxt, oB, N16);

  // ---- level 5: encR[3] on N16 ----
  k_encR_s<<<(N16 + 63) / 64, 256, 0, stream>>>(oB, eRW1 + 3 * 2048, eRb1 + 3 * 32,
                                                fold + 64 + 3 * 64, eRW2 + 3 * 2048,
                                                eRb2 + 3 * 64, s5, N16);

  // ---- decoders: lastT = prev_out @ decW_bot + decb, then fused dec ----
  k_lastT<<<(N16 + 127) / 128, 512, 0, stream>>>(s5, decW + 0 * 8192, decb + 0 * 64, lT, N16);
  k_dec2<<<(N16 + 127) / 128, 512, 0, stream>>>(s5, lT, nullptr, mlpW + 0 * 4096, mlpb + 0 * 64,
                                                decW + 0 * 8192, fold + 320 + 0 * 128, N16);
  k_lastT<<<(N16 + 127) / 128, 512, 0, stream>>>(s5, decW + 1 * 8192, decb + 1 * 64, lT, N16);
  k_dec2<<<(N8 + 127) / 128, 512, 0, stream>>>(s4, lT, inv16, mlpW + 1 * 4096, mlpb + 1 * 64,
                                               decW + 1 * 8192, fold + 320 + 1 * 128, N8);
  k_lastT<<<(N8 + 127) / 128, 512, 0, stream>>>(s4, decW + 2 * 8192, decb + 2 * 64, lT, N8);
  k_dec2<<<(N4 + 127) / 128, 512, 0, stream>>>(s3, lT, inv8, mlpW + 2 * 4096, mlpb + 2 * 64,
                                               decW + 2 * 8192, fold + 320 + 2 * 128, N4);
  k_lastT<<<(N4 + 127) / 128, 512, 0, stream>>>(s3, decW + 3 * 8192, decb + 3 * 64, lT, N4);
  k_dec2<<<(N2 + 127) / 128, 512, 0, stream>>>(s2, lT, inv4, mlpW + 3 * 4096, mlpb + 3 * 64,
                                               decW + 3 * 8192, fold + 320 + 3 * 128, N2);
  k_lastT<<<(N2 + 127) / 128, 512, 0, stream>>>(s2, decW + 4 * 8192, decb + 4 * 64, lT, N2);
  k_dec2<<<(N1 + 127) / 128, 512, 0, stream>>>(s1, lT, inv2, mlpW + 4 * 4096, mlpb + 4 * 64,
                                               decW + 4 * 8192, fold + 320 + 4 * 128, N1);
}

// Round 16
// 1111.473 us; speedup vs baseline: 2.2668x; 2.2668x over previous
//
#include <hip/hip_runtime.h>

#define N1 1000000
#define N2 400000
#define N4 150000
#define N8 60000
#define N16 20000

constexpr float BN_EPS = 1e-5f;

__device__ __forceinline__ float lrelu(float x) { return fmaxf(x, 0.1f * x); }

// Fold all BatchNorm params into scale/shift once per call.
__global__ void k_fold(const float* g0, const float* be0, const float* m0, const float* v0,
                       const float* gR, const float* beR, const float* mR, const float* vR,
                       const float* gD, const float* beD, const float* mD, const float* vD,
                       float* fold) {
  int t = threadIdx.x;
  if (t < 32) {
    float sc = g0[t] * rsqrtf(v0[t] + BN_EPS);
    fold[t] = sc;
    fold[32 + t] = be0[t] - m0[t] * sc;
  }
  if (t < 128) {
    int b = t >> 5, c = t & 31;
    float sc = gR[b * 32 + c] * rsqrtf(vR[b * 32 + c] + BN_EPS);
    fold[64 + b * 64 + c] = sc;
    fold[64 + b * 64 + 32 + c] = beR[b * 32 + c] - mR[b * 32 + c] * sc;
  }
  for (int i = t; i < 320; i += blockDim.x) {
    int b = i >> 6, c = i & 63;
    float sc = gD[b * 64 + c] * rsqrtf(vD[b * 64 + c] + BN_EPS);
    fold[320 + b * 128 + c] = sc;
    fold[320 + b * 128 + 64 + c] = beD[b * 64 + c] - mD[b * 64 + c] * sc;
  }
}

// Build per-segment linked lists. head pre-set to -1. One 4B atomic per row.
__global__ __launch_bounds__(256) void k_fill(const int* __restrict__ idx,
                                              int* head, int* nxt, int n) {
  int i = blockIdx.x * 256 + threadIdx.x;
  if (i < n) nxt[i] = atomicExch(&head[idx[i]], i);
}

// Segment max by chained gather: one wave per segment, one thread per channel.
__global__ __launch_bounds__(256) void k_gmax(
    const float* __restrict__ src, const int* __restrict__ head,
    const int* __restrict__ nxt, float* __restrict__ dst, int nseg) {
  int t = blockIdx.x * 256 + threadIdx.x;
  int seg = t >> 6, ch = t & 63;
  if (seg >= nseg) return;
  float m = -INFINITY;
  for (int p = head[seg]; p >= 0; p = nxt[p])
    m = fmaxf(m, src[(size_t)p * 64 + ch]);
  dst[(size_t)seg * 64 + ch] = (m == -INFINITY) ? 0.0f : m;
}

// ---------------- scalar-weight GEMM kernels (R10 structure, best measured) --
// lane = output row (64/block), wave w = col slice. Weights wave-uniform ->
// s_load with compile-time offsets; inputs stride-65/33/9 LDS.

// encoder block 0: x[9] -> h[32] (lrelu,BN) -> out[64] (lrelu)
__global__ __launch_bounds__(256) void k_enc0_s(
    const float* __restrict__ x,
    const float* __restrict__ W1, const float* __restrict__ b1,
    const float* __restrict__ fold,
    const float* __restrict__ W2, const float* __restrict__ b2,
    float* __restrict__ out, int n) {
  __shared__ float xS[64 * 9];
  __shared__ float hS[64 * 33];
  int t = threadIdx.x;
  int lane = t & 63;
  int w = __builtin_amdgcn_readfirstlane(t >> 6);
  int R = blockIdx.x * 64;

  {
    size_t lim = (size_t)n * 9 - 1;
    for (int i = t; i < 576; i += 256) {
      size_t gi = (size_t)R * 9 + i;
      if (gi > lim) gi = lim;
      xS[i] = x[gi];
    }
  }
  __syncthreads();

  // phase 1: h cols 8w..8w+7, K=9
  {
    const float* W1p = W1 + w * 8;
    float xr[9];
#pragma unroll
    for (int k = 0; k < 9; ++k) xr[k] = xS[lane * 9 + k];
    float acc[8];
#pragma unroll
    for (int c = 0; c < 8; ++c) acc[c] = b1[w * 8 + c];
#pragma unroll
    for (int k = 0; k < 9; ++k) {
#pragma unroll
      for (int c = 0; c < 8; ++c) acc[c] = fmaf(xr[k], W1p[k * 32 + c], acc[c]);
    }
#pragma unroll
    for (int c = 0; c < 8; ++c) {
      float sc = fold[w * 8 + c], sh = fold[32 + w * 8 + c];
      hS[lane * 33 + w * 8 + c] = lrelu(acc[c]) * sc + sh;
    }
  }
  __syncthreads();

  // phase 2: out cols 16w..16w+15, K=32, chunks of 8
  {
    const float* W2p = W2 + w * 16;
    float o[16];
#pragma unroll
    for (int c = 0; c < 16; ++c) o[c] = b2[w * 16 + c];
    for (int k0 = 0; k0 < 32; k0 += 8) {
      float a[8];
#pragma unroll
      for (int j = 0; j < 8; ++j) a[j] = hS[lane * 33 + k0 + j];
#pragma unroll
      for (int j = 0; j < 8; ++j) {
#pragma unroll
        for (int c = 0; c < 16; ++c)
          o[c] = fmaf(a[j], W2p[(k0 + j) * 64 + c], o[c]);
      }
    }
    int gr = R + lane;
    if (gr < n) {
      float* op = out + (size_t)gr * 64 + w * 16;
#pragma unroll
      for (int c = 0; c < 16; ++c) op[c] = lrelu(o[c]);
    }
  }
}

// encoder blocks 1..4: in[64] -> h[32] (lrelu,BN) -> out[64] (lrelu)
__global__ __launch_bounds__(256) void k_encR_s(
    const float* __restrict__ xin,
    const float* __restrict__ W1, const float* __restrict__ b1,
    const float* __restrict__ fold,
    const float* __restrict__ W2, const float* __restrict__ b2,
    float* __restrict__ out, int n) {
  __shared__ float inS[64 * 65];
  __shared__ float hS[64 * 33];
  int t = threadIdx.x;
  int lane = t & 63;
  int w = __builtin_amdgcn_readfirstlane(t >> 6);
  int R = blockIdx.x * 64;

  for (int f = t; f < 1024; f += 256) {
    int row = f >> 4, c4 = (f & 15) << 2;
    int gr = R + row; if (gr >= n) gr = n - 1;
    float4 v = *(const float4*)(xin + (size_t)gr * 64 + c4);
    inS[row * 65 + c4 + 0] = v.x; inS[row * 65 + c4 + 1] = v.y;
    inS[row * 65 + c4 + 2] = v.z; inS[row * 65 + c4 + 3] = v.w;
  }
  __syncthreads();

  // phase 1: h cols 8w..8w+7, K=64, chunks of 8
  {
    const float* W1p = W1 + w * 8;
    float acc[8];
#pragma unroll
    for (int c = 0; c < 8; ++c) acc[c] = b1[w * 8 + c];
    for (int k0 = 0; k0 < 64; k0 += 8) {
      float a[8];
#pragma unroll
      for (int j = 0; j < 8; ++j) a[j] = inS[lane * 65 + k0 + j];
#pragma unroll
      for (int j = 0; j < 8; ++j) {
#pragma unroll
        for (int c = 0; c < 8; ++c)
          acc[c] = fmaf(a[j], W1p[(k0 + j) * 32 + c], acc[c]);
      }
    }
#pragma unroll
    for (int c = 0; c < 8; ++c) {
      float sc = fold[w * 8 + c], sh = fold[32 + w * 8 + c];
      hS[lane * 33 + w * 8 + c] = lrelu(acc[c]) * sc + sh;
    }
  }
  __syncthreads();

  // phase 2: out cols 16w..16w+15, K=32, chunks of 8
  {
    const float* W2p = W2 + w * 16;
    float o[16];
#pragma unroll
    for (int c = 0; c < 16; ++c) o[c] = b2[w * 16 + c];
    for (int k0 = 0; k0 < 32; k0 += 8) {
      float a[8];
#pragma unroll
      for (int j = 0; j < 8; ++j) a[j] = hS[lane * 33 + k0 + j];
#pragma unroll
      for (int j = 0; j < 8; ++j) {
#pragma unroll
        for (int c = 0; c < 16; ++c)
          o[c] = fmaf(a[j], W2p[(k0 + j) * 64 + c], o[c]);
      }
    }
    int gr = R + lane;
    if (gr < n) {
      float* op = out + (size_t)gr * 64 + w * 16;
#pragma unroll
      for (int c = 0; c < 16; ++c) op[c] = lrelu(o[c]);
    }
  }
}

// lastT = src @ decW[64:128] + decb (used only for decoder level 0 seed)
__global__ __launch_bounds__(256) void k_lastT(
    const float* __restrict__ src, const float* __restrict__ decW,
    const float* __restrict__ decb, float* __restrict__ lT, int n) {
  __shared__ float sS[64 * 65];
  int t = threadIdx.x;
  int lane = t & 63;
  int w = __builtin_amdgcn_readfirstlane(t >> 6);
  int R = blockIdx.x * 64;

  for (int f = t; f < 1024; f += 256) {
    int row = f >> 4, c4 = (f & 15) << 2;
    int gr = R + row; if (gr >= n) gr = n - 1;
    float4 v = *(const float4*)(src + (size_t)gr * 64 + c4);
    sS[row * 65 + c4 + 0] = v.x; sS[row * 65 + c4 + 1] = v.y;
    sS[row * 65 + c4 + 2] = v.z; sS[row * 65 + c4 + 3] = v.w;
  }
  __syncthreads();

  const float* Dp = decW + 64 * 64 + w * 16;  // bottom half rows
  float o[16];
#pragma unroll
  for (int c = 0; c < 16; ++c) o[c] = decb[w * 16 + c];
  for (int k0 = 0; k0 < 64; k0 += 8) {
    float a[8];
#pragma unroll
    for (int j = 0; j < 8; ++j) a[j] = sS[lane * 65 + k0 + j];
#pragma unroll
    for (int j = 0; j < 8; ++j) {
#pragma unroll
      for (int c = 0; c < 16; ++c)
        o[c] = fmaf(a[j], Dp[(k0 + j) * 64 + c], o[c]);
    }
  }
  int gr = R + lane;
  if (gr < n) {
    float* op = lT + (size_t)gr * 64 + w * 16;
#pragma unroll
    for (int c = 0; c < 16; ++c) op[c] = o[c];
  }
}

// decoder: out = lrelu(BN(lrelu(cur@mlpW+mlpb) @ decW[0:64] + lastT[lrow]))
// In place on `inout`. Phase 3 (optional): lTout = out @ decWnB + decbN, the
// NEXT level's lastT, fused here to skip re-reading `inout` globally.
__global__ __launch_bounds__(256) void k_dec2(
    float* inout, const float* __restrict__ lT, const int* __restrict__ idx,
    const float* __restrict__ mlpW, const float* __restrict__ mlpb,
    const float* __restrict__ decW, const float* __restrict__ fold, int n,
    const float* __restrict__ decWnB, const float* __restrict__ decbN,
    float* __restrict__ lTout) {
  __shared__ float curS[64 * 65];
  int t = threadIdx.x;
  int lane = t & 63;
  int w = __builtin_amdgcn_readfirstlane(t >> 6);
  int R = blockIdx.x * 64;

  for (int f = t; f < 1024; f += 256) {
    int row = f >> 4, c4 = (f & 15) << 2;
    int gr = R + row; if (gr >= n) gr = n - 1;
    float4 v = *(const float4*)(inout + (size_t)gr * 64 + c4);
    curS[row * 65 + c4 + 0] = v.x; curS[row * 65 + c4 + 1] = v.y;
    curS[row * 65 + c4 + 2] = v.z; curS[row * 65 + c4 + 3] = v.w;
  }

  // issue lastT gather early (consumed after phase 1)
  int grc = R + lane; if (grc >= n) grc = n - 1;
  int g = idx ? idx[grc] : grc;
  const float* lp = lT + (size_t)g * 64 + w * 16;
  float4 l0 = *(const float4*)(lp + 0);
  float4 l1 = *(const float4*)(lp + 4);
  float4 l2 = *(const float4*)(lp + 8);
  float4 l3 = *(const float4*)(lp + 12);

  __syncthreads();

  // phase 1: skip cols 16w..16w+15, K=64, chunks of 8
  float sk[16];
  {
    const float* Mp = mlpW + w * 16;
#pragma unroll
    for (int c = 0; c < 16; ++c) sk[c] = mlpb[w * 16 + c];
    for (int k0 = 0; k0 < 64; k0 += 8) {
      float a[8];
#pragma unroll
      for (int j = 0; j < 8; ++j) a[j] = curS[lane * 65 + k0 + j];
#pragma unroll
      for (int j = 0; j < 8; ++j) {
#pragma unroll
        for (int c = 0; c < 16; ++c)
          sk[c] = fmaf(a[j], Mp[(k0 + j) * 64 + c], sk[c]);
      }
    }
  }
  __syncthreads();  // all reads of curS done
#pragma unroll
  for (int c = 0; c < 16; ++c)
    curS[lane * 65 + w * 16 + c] = lrelu(sk[c]);
  __syncthreads();

  // phase 2: out cols 16w..16w+15 = skip @ decW_top + lastT[lrow], K=64
  float f16[16];
  {
    float o[16];
    o[0] = l0.x; o[1] = l0.y; o[2] = l0.z; o[3] = l0.w;
    o[4] = l1.x; o[5] = l1.y; o[6] = l1.z; o[7] = l1.w;
    o[8] = l2.x; o[9] = l2.y; o[10] = l2.z; o[11] = l2.w;
    o[12] = l3.x; o[13] = l3.y; o[14] = l3.z; o[15] = l3.w;

    const float* Dp = decW + w * 16;  // top half rows
    for (int k0 = 0; k0 < 64; k0 += 8) {
      float a[8];
#pragma unroll
      for (int j = 0; j < 8; ++j) a[j] = curS[lane * 65 + k0 + j];
#pragma unroll
      for (int j = 0; j < 8; ++j) {
#pragma unroll
        for (int c = 0; c < 16; ++c)
          o[c] = fmaf(a[j], Dp[(k0 + j) * 64 + c], o[c]);
      }
    }
#pragma unroll
    for (int c = 0; c < 16; ++c) {
      float sc = fold[w * 16 + c], sh = fold[64 + w * 16 + c];
      f16[c] = lrelu(o[c] * sc + sh);
    }
    int gr = R + lane;
    if (gr < n) {
      float* op = inout + (size_t)gr * 64 + w * 16;
#pragma unroll
      for (int c = 0; c < 16; ++c) op[c] = f16[c];
    }
  }

  // phase 3 (optional): lTout = f @ decWnB + decbN for the next level
  if (decWnB) {
    __syncthreads();  // phase-2 curS reads done
#pragma unroll
    for (int c = 0; c < 16; ++c)
      curS[lane * 65 + w * 16 + c] = f16[c];
    __syncthreads();

    const float* Dp = decWnB + w * 16;
    float o[16];
#pragma unroll
    for (int c = 0; c < 16; ++c) o[c] = decbN[w * 16 + c];
    for (int k0 = 0; k0 < 64; k0 += 8) {
      float a[8];
#pragma unroll
      for (int j = 0; j < 8; ++j) a[j] = curS[lane * 65 + k0 + j];
#pragma unroll
      for (int j = 0; j < 8; ++j) {
#pragma unroll
        for (int c = 0; c < 16; ++c)
          o[c] = fmaf(a[j], Dp[(k0 + j) * 64 + c], o[c]);
      }
    }
    int gr = R + lane;
    if (gr < n) {
      float* op = lTout + (size_t)gr * 64 + w * 16;
#pragma unroll
      for (int c = 0; c < 16; ++c) op[c] = o[c];
    }
  }
}

extern "C" void kernel_launch(void* const* d_in, const int* in_sizes, int n_in,
                              void* d_out, int out_size, void* d_ws, size_t ws_size,
                              hipStream_t stream) {
  const float* pt   = (const float*)d_in[0];
  const int* inv2   = (const int*)d_in[1];
  const int* inv4   = (const int*)d_in[2];
  const int* inv8   = (const int*)d_in[3];
  const int* inv16  = (const int*)d_in[4];
  const float* e0W1 = (const float*)d_in[5];
  const float* e0b1 = (const float*)d_in[6];
  const float* e0g  = (const float*)d_in[7];
  const float* e0be = (const float*)d_in[8];
  const float* e0m  = (const float*)d_in[9];
  const float* e0v  = (const float*)d_in[10];
  const float* e0W2 = (const float*)d_in[11];
  const float* e0b2 = (const float*)d_in[12];
  const float* eRW1 = (const float*)d_in[13];
  const float* eRb1 = (const float*)d_in[14];
  const float* eRg  = (const float*)d_in[15];
  const float* eRbe = (const float*)d_in[16];
  const float* eRm  = (const float*)d_in[17];
  const float* eRv  = (const float*)d_in[18];
  const float* eRW2 = (const float*)d_in[19];
  const float* eRb2 = (const float*)d_in[20];
  const float* mlpW = (const float*)d_in[21];
  const float* mlpb = (const float*)d_in[22];
  const float* decW = (const float*)d_in[23];
  const float* decb = (const float*)d_in[24];
  const float* decg = (const float*)d_in[25];
  const float* decbe= (const float*)d_in[26];
  const float* decm = (const float*)d_in[27];
  const float* decv = (const float*)d_in[28];

  float* s1 = (float*)d_out;
  float* s2 = s1 + (size_t)N1 * 64;
  float* s3 = s2 + (size_t)N2 * 64;
  float* s4 = s3 + (size_t)N4 * 64;
  float* s5 = s4 + (size_t)N8 * 64;

  // workspace: fold | oA (N2*64 f) | oB (N4*64 f) | head (N2 i) | nxt (N1 i)
  float* fold = (float*)d_ws;
  float* oA   = fold + 1024;
  float* oB   = oA + (size_t)N2 * 64;
  int* head   = (int*)(oB + (size_t)N4 * 64);
  int* nxt    = head + N2;

  k_fold<<<1, 320, 0, stream>>>(e0g, e0be, e0m, e0v, eRg, eRbe, eRm, eRv,
                                decg, decbe, decm, decv, fold);

  // ---- level 1: enc0 on N1, pool -> oA [N2] ----
  hipMemsetAsync(head, 0xFF, (size_t)N2 * 4, stream);
  k_fill<<<(N1 + 255) / 256, 256, 0, stream>>>(inv2, head, nxt, N1);
  k_enc0_s<<<(N1 + 63) / 64, 256, 0, stream>>>(pt, e0W1, e0b1, fold, e0W2, e0b2, s1, N1);
  k_gmax<<<((size_t)N2 * 64 + 255) / 256, 256, 0, stream>>>(s1, head, nxt, oA, N2);

  // ---- level 2: encR[0] on N2, pool -> oB [N4] ----
  hipMemsetAsync(head, 0xFF, (size_t)N4 * 4, stream);
  k_fill<<<(N2 + 255) / 256, 256, 0, stream>>>(inv4, head, nxt, N2);
  k_encR_s<<<(N2 + 63) / 64, 256, 0, stream>>>(oA, eRW1 + 0 * 2048, eRb1 + 0 * 32,
                                               fold + 64 + 0 * 64, eRW2 + 0 * 2048,
                                               eRb2 + 0 * 64, s2, N2);
  k_gmax<<<((size_t)N4 * 64 + 255) / 256, 256, 0, stream>>>(s2, head, nxt, oB, N4);

  // ---- level 3: encR[1] on N4, pool -> oA [N8] ----
  hipMemsetAsync(head, 0xFF, (size_t)N8 * 4, stream);
  k_fill<<<(N4 + 255) / 256, 256, 0, stream>>>(inv8, head, nxt, N4);
  k_encR_s<<<(N4 + 63) / 64, 256, 0, stream>>>(oB, eRW1 + 1 * 2048, eRb1 + 1 * 32,
                                               fold + 64 + 1 * 64, eRW2 + 1 * 2048,
                                               eRb2 + 1 * 64, s3, N4);
  k_gmax<<<((size_t)N8 * 64 + 255) / 256, 256, 0, stream>>>(s3, head, nxt, oA, N8);

  // ---- level 4: encR[2] on N8, pool -> oB [N16] ----
  hipMemsetAsync(head, 0xFF, (size_t)N16 * 4, stream);
  k_fill<<<(N8 + 255) / 256, 256, 0, stream>>>(inv16, head, nxt, N8);
  k_encR_s<<<(N8 + 63) / 64, 256, 0, stream>>>(oA, eRW1 + 2 * 2048, eRb1 + 2 * 32,
                                               fold + 64 + 2 * 64, eRW2 + 2 * 2048,
                                               eRb2 + 2 * 64, s4, N8);
  k_gmax<<<((size_t)N16 * 64 + 255) / 256, 256, 0, stream>>>(s4, head, nxt, oB, N16);

  // ---- level 5: encR[3] on N16 ----
  k_encR_s<<<(N16 + 63) / 64, 256, 0, stream>>>(oB, eRW1 + 3 * 2048, eRb1 + 3 * 32,
                                                fold + 64 + 3 * 64, eRW2 + 3 * 2048,
                                                eRb2 + 3 * 64, s5, N16);

  // ---- decoders with fused next-level lastT (phase 3) ----
  // lT ping-pong: oA/oB (oA >= N2 rows, oB >= N4 rows)
  // seed: lT0 = p5 @ decW0_bot + decb0  -> oA [N16]
  k_lastT<<<(N16 + 63) / 64, 256, 0, stream>>>(s5, decW + 0 * 8192, decb + 0 * 64, oA, N16);
  // dec0 (p5f on s5), produce lT1 = p5f @ decW1_bot + decb1 -> oB [N16]
  k_dec2<<<(N16 + 63) / 64, 256, 0, stream>>>(s5, oA, nullptr, mlpW + 0 * 4096, mlpb + 0 * 64,
                                              decW + 0 * 8192, fold + 320 + 0 * 128, N16,
                                              decW + 1 * 8192 + 4096, decb + 1 * 64, oB);
  // dec1 (p4f on s4, gather inv16 into lT1=oB), produce lT2 -> oA [N8]
  k_dec2<<<(N8 + 63) / 64, 256, 0, stream>>>(s4, oB, inv16, mlpW + 1 * 4096, mlpb + 1 * 64,
                                             decW + 1 * 8192, fold + 320 + 1 * 128, N8,
                                             decW + 2 * 8192 + 4096, decb + 2 * 64, oA);
  // dec2 (p3f on s3, gather inv8 into lT2=oA), produce lT3 -> oB [N4]
  k_dec2<<<(N4 + 63) / 64, 256, 0, stream>>>(s3, oA, inv8, mlpW + 2 * 4096, mlpb + 2 * 64,
                                             decW + 2 * 8192, fold + 320 + 2 * 128, N4,
                                             decW + 3 * 8192 + 4096, decb + 3 * 64, oB);
  // dec3 (p2f on s2, gather inv4 into lT3=oB), produce lT4 -> oA [N2]
  k_dec2<<<(N2 + 63) / 64, 256, 0, stream>>>(s2, oB, inv4, mlpW + 3 * 4096, mlpb + 3 * 64,
                                             decW + 3 * 8192, fold + 320 + 3 * 128, N2,
                                             decW + 4 * 8192 + 4096, decb + 4 * 64, oA);
  // dec4 (p1f on s1, gather inv2 into lT4=oA), no phase 3
  k_dec2<<<(N1 + 63) / 64, 256, 0, stream>>>(s1, oA, inv2, mlpW + 4 * 4096, mlpb + 4 * 64,
                                             decW + 4 * 8192, fold + 320 + 4 * 128, N1,
                                             nullptr, nullptr, nullptr);
}

// Round 17
// 1093.384 us; speedup vs baseline: 2.3043x; 1.0165x over previous
//
#include <hip/hip_runtime.h>

#define N1 1000000
#define N2 400000
#define N4 150000
#define N8 60000
#define N16 20000

constexpr float BN_EPS = 1e-5f;

typedef _Float16 h2 __attribute__((ext_vector_type(2)));

__device__ __forceinline__ float lrelu(float x) { return fmaxf(x, 0.1f * x); }

__device__ __forceinline__ unsigned pk(float x, float y) {
  h2 h = {(_Float16)x, (_Float16)y};
  unsigned u;
  __builtin_memcpy(&u, &h, 4);
  return u;
}
__device__ __forceinline__ h2 uph(unsigned u) {
  h2 h;
  __builtin_memcpy(&h, &u, 4);
  return h;
}
__device__ __forceinline__ float fdot2(h2 a, h2 b, float c) {
  return __builtin_amdgcn_fdot2(a, b, c, false);
}

// Fold all BatchNorm params into scale/shift once per call.
__global__ void k_fold(const float* g0, const float* be0, const float* m0, const float* v0,
                       const float* gR, const float* beR, const float* mR, const float* vR,
                       const float* gD, const float* beD, const float* mD, const float* vD,
                       float* fold) {
  int t = threadIdx.x;
  if (t < 32) {
    float sc = g0[t] * rsqrtf(v0[t] + BN_EPS);
    fold[t] = sc;
    fold[32 + t] = be0[t] - m0[t] * sc;
  }
  if (t < 128) {
    int b = t >> 5, c = t & 31;
    float sc = gR[b * 32 + c] * rsqrtf(vR[b * 32 + c] + BN_EPS);
    fold[64 + b * 64 + c] = sc;
    fold[64 + b * 64 + 32 + c] = beR[b * 32 + c] - mR[b * 32 + c] * sc;
  }
  for (int i = t; i < 320; i += blockDim.x) {
    int b = i >> 6, c = i & 63;
    float sc = gD[b * 64 + c] * rsqrtf(vD[b * 64 + c] + BN_EPS);
    fold[320 + b * 128 + c] = sc;
    fold[320 + b * 128 + 64 + c] = beD[b * 64 + c] - mD[b * 64 + c] * sc;
  }
}

// Pack fp32 [2P][C] -> half2-pair [P][C] (pair along k).
__global__ __launch_bounds__(256) void k_pack(const float* __restrict__ s,
                                              unsigned* __restrict__ d, int total, int C) {
  int i = blockIdx.x * 256 + threadIdx.x;
  if (i >= total) return;
  int p = i / C, c = i - p * C;
  d[i] = pk(s[(2 * p) * C + c], s[(2 * p + 1) * C + c]);
}

// Build per-segment linked lists. head pre-set to -1. One 4B atomic per row.
__global__ __launch_bounds__(256) void k_fill(const int* __restrict__ idx,
                                              int* head, int* nxt, int n) {
  int i = blockIdx.x * 256 + threadIdx.x;
  if (i < n) nxt[i] = atomicExch(&head[idx[i]], i);
}

// Segment max by chained gather: one wave per segment, one thread per channel.
__global__ __launch_bounds__(256) void k_gmax(
    const float* __restrict__ src, const int* __restrict__ head,
    const int* __restrict__ nxt, float* __restrict__ dst, int nseg) {
  int t = blockIdx.x * 256 + threadIdx.x;
  int seg = t >> 6, ch = t & 63;
  if (seg >= nseg) return;
  float m = -INFINITY;
  for (int p = head[seg]; p >= 0; p = nxt[p])
    m = fmaxf(m, src[(size_t)p * 64 + ch]);
  dst[(size_t)seg * 64 + ch] = (m == -INFINITY) ? 0.0f : m;
}

// ---------------- fp16-dot2 GEMM kernels ----------------
// lane = output row (64/block), wave w = col slice. Weights packed k-pairwise
// (half2) -> wave-uniform s_load of u32; activations in LDS as half2 pairs
// (stride 34/18 uints: 2-way bank alias only, free). fp32 accumulate via
// v_dot2_f32_f16: halves VALU instrs, weight bytes, and LDS reads per MAC.

// encoder block 0: x[9] -> h[32] (lrelu,BN, fp32 K=9) -> out[64] (fp16 dot2)
__global__ __launch_bounds__(256) void k_enc0_s(
    const float* __restrict__ x,
    const float* __restrict__ W1, const float* __restrict__ b1,
    const float* __restrict__ fold,
    const unsigned* __restrict__ W2p, const float* __restrict__ b2,
    float* __restrict__ out, int n) {
  __shared__ float xS[64 * 9];
  __shared__ unsigned hP[64 * 18];
  int t = threadIdx.x;
  int lane = t & 63;
  int w = __builtin_amdgcn_readfirstlane(t >> 6);
  int R = blockIdx.x * 64;

  {
    size_t lim = (size_t)n * 9 - 1;
    for (int i = t; i < 576; i += 256) {
      size_t gi = (size_t)R * 9 + i;
      if (gi > lim) gi = lim;
      xS[i] = x[gi];
    }
  }
  __syncthreads();

  // phase 1 (fp32): h cols 8w..8w+7, K=9; pack pairs into hP
  {
    const float* W1p = W1 + w * 8;
    float xr[9];
#pragma unroll
    for (int k = 0; k < 9; ++k) xr[k] = xS[lane * 9 + k];
    float acc[8];
#pragma unroll
    for (int c = 0; c < 8; ++c) acc[c] = b1[w * 8 + c];
#pragma unroll
    for (int k = 0; k < 9; ++k) {
#pragma unroll
      for (int c = 0; c < 8; ++c) acc[c] = fmaf(xr[k], W1p[k * 32 + c], acc[c]);
    }
    float v[8];
#pragma unroll
    for (int c = 0; c < 8; ++c)
      v[c] = lrelu(acc[c]) * fold[w * 8 + c] + fold[32 + w * 8 + c];
#pragma unroll
    for (int j = 0; j < 4; ++j)
      hP[lane * 18 + w * 4 + j] = pk(v[2 * j], v[2 * j + 1]);
  }
  __syncthreads();

  // phase 2: out cols 16w..16w+15, 16 k-pairs, chunks of 8
  {
    const unsigned* Wp = W2p + w * 16;
    float o[16];
#pragma unroll
    for (int c = 0; c < 16; ++c) o[c] = b2[w * 16 + c];
    for (int k0 = 0; k0 < 16; k0 += 8) {
      unsigned au[8];
#pragma unroll
      for (int j = 0; j < 8; ++j) au[j] = hP[lane * 18 + k0 + j];
#pragma unroll
      for (int j = 0; j < 8; ++j) {
        h2 a = uph(au[j]);
#pragma unroll
        for (int c = 0; c < 16; ++c)
          o[c] = fdot2(a, uph(Wp[(k0 + j) * 64 + c]), o[c]);
      }
    }
    int gr = R + lane;
    if (gr < n) {
      float* op = out + (size_t)gr * 64 + w * 16;
#pragma unroll
      for (int c = 0; c < 16; ++c) op[c] = lrelu(o[c]);
    }
  }
}

// encoder blocks 1..4: in[64] -> h[32] (lrelu,BN) -> out[64]
__global__ __launch_bounds__(256) void k_encR_s(
    const float* __restrict__ xin,
    const unsigned* __restrict__ W1p, const float* __restrict__ b1,
    const float* __restrict__ fold,
    const unsigned* __restrict__ W2p, const float* __restrict__ b2,
    float* __restrict__ out, int n) {
  __shared__ unsigned inP[64 * 34];
  __shared__ unsigned hP[64 * 18];
  int t = threadIdx.x;
  int lane = t & 63;
  int w = __builtin_amdgcn_readfirstlane(t >> 6);
  int R = blockIdx.x * 64;

  for (int f = t; f < 1024; f += 256) {
    int row = f >> 4, c4 = (f & 15) << 2;
    int gr = R + row; if (gr >= n) gr = n - 1;
    float4 v = *(const float4*)(xin + (size_t)gr * 64 + c4);
    inP[row * 34 + (c4 >> 1)] = pk(v.x, v.y);
    inP[row * 34 + (c4 >> 1) + 1] = pk(v.z, v.w);
  }
  __syncthreads();

  // phase 1: h cols 8w..8w+7, 32 k-pairs, chunks of 8
  {
    const unsigned* Wp = W1p + w * 8;
    float acc[8];
#pragma unroll
    for (int c = 0; c < 8; ++c) acc[c] = b1[w * 8 + c];
    for (int k0 = 0; k0 < 32; k0 += 8) {
      unsigned au[8];
#pragma unroll
      for (int j = 0; j < 8; ++j) au[j] = inP[lane * 34 + k0 + j];
#pragma unroll
      for (int j = 0; j < 8; ++j) {
        h2 a = uph(au[j]);
#pragma unroll
        for (int c = 0; c < 8; ++c)
          acc[c] = fdot2(a, uph(Wp[(k0 + j) * 32 + c]), acc[c]);
      }
    }
    float v[8];
#pragma unroll
    for (int c = 0; c < 8; ++c)
      v[c] = lrelu(acc[c]) * fold[w * 8 + c] + fold[32 + w * 8 + c];
#pragma unroll
    for (int j = 0; j < 4; ++j)
      hP[lane * 18 + w * 4 + j] = pk(v[2 * j], v[2 * j + 1]);
  }
  __syncthreads();

  // phase 2: out cols 16w..16w+15, 16 k-pairs, chunks of 8
  {
    const unsigned* Wp = W2p + w * 16;
    float o[16];
#pragma unroll
    for (int c = 0; c < 16; ++c) o[c] = b2[w * 16 + c];
    for (int k0 = 0; k0 < 16; k0 += 8) {
      unsigned au[8];
#pragma unroll
      for (int j = 0; j < 8; ++j) au[j] = hP[lane * 18 + k0 + j];
#pragma unroll
      for (int j = 0; j < 8; ++j) {
        h2 a = uph(au[j]);
#pragma unroll
        for (int c = 0; c < 16; ++c)
          o[c] = fdot2(a, uph(Wp[(k0 + j) * 64 + c]), o[c]);
      }
    }
    int gr = R + lane;
    if (gr < n) {
      float* op = out + (size_t)gr * 64 + w * 16;
#pragma unroll
      for (int c = 0; c < 16; ++c) op[c] = lrelu(o[c]);
    }
  }
}

// lastT = src @ decW_bot + decb (seed for decoder level 0)
__global__ __launch_bounds__(256) void k_lastT(
    const float* __restrict__ src, const unsigned* __restrict__ DpBot,
    const float* __restrict__ decb, float* __restrict__ lT, int n) {
  __shared__ unsigned sP[64 * 34];
  int t = threadIdx.x;
  int lane = t & 63;
  int w = __builtin_amdgcn_readfirstlane(t >> 6);
  int R = blockIdx.x * 64;

  for (int f = t; f < 1024; f += 256) {
    int row = f >> 4, c4 = (f & 15) << 2;
    int gr = R + row; if (gr >= n) gr = n - 1;
    float4 v = *(const float4*)(src + (size_t)gr * 64 + c4);
    sP[row * 34 + (c4 >> 1)] = pk(v.x, v.y);
    sP[row * 34 + (c4 >> 1) + 1] = pk(v.z, v.w);
  }
  __syncthreads();

  const unsigned* Wp = DpBot + w * 16;
  float o[16];
#pragma unroll
  for (int c = 0; c < 16; ++c) o[c] = decb[w * 16 + c];
  for (int k0 = 0; k0 < 32; k0 += 8) {
    unsigned au[8];
#pragma unroll
    for (int j = 0; j < 8; ++j) au[j] = sP[lane * 34 + k0 + j];
#pragma unroll
    for (int j = 0; j < 8; ++j) {
      h2 a = uph(au[j]);
#pragma unroll
      for (int c = 0; c < 16; ++c)
        o[c] = fdot2(a, uph(Wp[(k0 + j) * 64 + c]), o[c]);
    }
  }
  int gr = R + lane;
  if (gr < n) {
    float* op = lT + (size_t)gr * 64 + w * 16;
#pragma unroll
    for (int c = 0; c < 16; ++c) op[c] = o[c];
  }
}

// decoder: out = lrelu(BN(lrelu(cur@mlp) @ decW_top + lastT[lrow])); optional
// phase 3 computes the NEXT level's lastT from the fresh output (fused).
__global__ __launch_bounds__(256) void k_dec2(
    float* inout, const float* __restrict__ lT, const int* __restrict__ idx,
    const unsigned* __restrict__ Mp_, const float* __restrict__ mlpb,
    const unsigned* __restrict__ DpTop, const float* __restrict__ fold, int n,
    const unsigned* __restrict__ DpNextBot, const float* __restrict__ decbN,
    float* __restrict__ lTout) {
  __shared__ unsigned curP[64 * 34];
  int t = threadIdx.x;
  int lane = t & 63;
  int w = __builtin_amdgcn_readfirstlane(t >> 6);
  int R = blockIdx.x * 64;

  for (int f = t; f < 1024; f += 256) {
    int row = f >> 4, c4 = (f & 15) << 2;
    int gr = R + row; if (gr >= n) gr = n - 1;
    float4 v = *(const float4*)(inout + (size_t)gr * 64 + c4);
    curP[row * 34 + (c4 >> 1)] = pk(v.x, v.y);
    curP[row * 34 + (c4 >> 1) + 1] = pk(v.z, v.w);
  }

  // issue lastT gather early (consumed in phase 2)
  int grc = R + lane; if (grc >= n) grc = n - 1;
  int g = idx ? idx[grc] : grc;
  const float* lp = lT + (size_t)g * 64 + w * 16;
  float4 l0 = *(const float4*)(lp + 0);
  float4 l1 = *(const float4*)(lp + 4);
  float4 l2 = *(const float4*)(lp + 8);
  float4 l3 = *(const float4*)(lp + 12);

  __syncthreads();

  // phase 1: skip cols 16w..16w+15, 32 k-pairs
  float sk[16];
  {
    const unsigned* Wp = Mp_ + w * 16;
#pragma unroll
    for (int c = 0; c < 16; ++c) sk[c] = mlpb[w * 16 + c];
    for (int k0 = 0; k0 < 32; k0 += 8) {
      unsigned au[8];
#pragma unroll
      for (int j = 0; j < 8; ++j) au[j] = curP[lane * 34 + k0 + j];
#pragma unroll
      for (int j = 0; j < 8; ++j) {
        h2 a = uph(au[j]);
#pragma unroll
        for (int c = 0; c < 16; ++c)
          sk[c] = fdot2(a, uph(Wp[(k0 + j) * 64 + c]), sk[c]);
      }
    }
  }
  __syncthreads();  // all phase-1 reads of curP done
#pragma unroll
  for (int j = 0; j < 8; ++j)
    curP[lane * 34 + w * 8 + j] = pk(lrelu(sk[2 * j]), lrelu(sk[2 * j + 1]));
  __syncthreads();

  // phase 2: out = skip @ decW_top + lastT, 32 k-pairs
  float fv[16];
  {
    float o[16];
    o[0] = l0.x; o[1] = l0.y; o[2] = l0.z; o[3] = l0.w;
    o[4] = l1.x; o[5] = l1.y; o[6] = l1.z; o[7] = l1.w;
    o[8] = l2.x; o[9] = l2.y; o[10] = l2.z; o[11] = l2.w;
    o[12] = l3.x; o[13] = l3.y; o[14] = l3.z; o[15] = l3.w;

    const unsigned* Wp = DpTop + w * 16;
    for (int k0 = 0; k0 < 32; k0 += 8) {
      unsigned au[8];
#pragma unroll
      for (int j = 0; j < 8; ++j) au[j] = curP[lane * 34 + k0 + j];
#pragma unroll
      for (int j = 0; j < 8; ++j) {
        h2 a = uph(au[j]);
#pragma unroll
        for (int c = 0; c < 16; ++c)
          o[c] = fdot2(a, uph(Wp[(k0 + j) * 64 + c]), o[c]);
      }
    }
#pragma unroll
    for (int c = 0; c < 16; ++c) {
      float sc = fold[w * 16 + c], sh = fold[64 + w * 16 + c];
      fv[c] = lrelu(o[c] * sc + sh);
    }
    int gr = R + lane;
    if (gr < n) {
      float* op = inout + (size_t)gr * 64 + w * 16;
#pragma unroll
      for (int c = 0; c < 16; ++c) op[c] = fv[c];
    }
  }

  // phase 3 (optional): lTout = out @ decWnext_bot + decbN
  if (DpNextBot) {
    __syncthreads();
#pragma unroll
    for (int j = 0; j < 8; ++j)
      curP[lane * 34 + w * 8 + j] = pk(fv[2 * j], fv[2 * j + 1]);
    __syncthreads();

    const unsigned* Wp = DpNextBot + w * 16;
    float o[16];
#pragma unroll
    for (int c = 0; c < 16; ++c) o[c] = decbN[w * 16 + c];
    for (int k0 = 0; k0 < 32; k0 += 8) {
      unsigned au[8];
#pragma unroll
      for (int j = 0; j < 8; ++j) au[j] = curP[lane * 34 + k0 + j];
#pragma unroll
      for (int j = 0; j < 8; ++j) {
        h2 a = uph(au[j]);
#pragma unroll
        for (int c = 0; c < 16; ++c)
          o[c] = fdot2(a, uph(Wp[(k0 + j) * 64 + c]), o[c]);
      }
    }
    int gr = R + lane;
    if (gr < n) {
      float* op = lTout + (size_t)gr * 64 + w * 16;
#pragma unroll
      for (int c = 0; c < 16; ++c) op[c] = o[c];
    }
  }
}

extern "C" void kernel_launch(void* const* d_in, const int* in_sizes, int n_in,
                              void* d_out, int out_size, void* d_ws, size_t ws_size,
                              hipStream_t stream) {
  const float* pt   = (const float*)d_in[0];
  const int* inv2   = (const int*)d_in[1];
  const int* inv4   = (const int*)d_in[2];
  const int* inv8   = (const int*)d_in[3];
  const int* inv16  = (const int*)d_in[4];
  const float* e0W1 = (const float*)d_in[5];
  const float* e0b1 = (const float*)d_in[6];
  const float* e0g  = (const float*)d_in[7];
  const float* e0be = (const float*)d_in[8];
  const float* e0m  = (const float*)d_in[9];
  const float* e0v  = (const float*)d_in[10];
  const float* e0W2 = (const float*)d_in[11];
  const float* e0b2 = (const float*)d_in[12];
  const float* eRW1 = (const float*)d_in[13];
  const float* eRb1 = (const float*)d_in[14];
  const float* eRg  = (const float*)d_in[15];
  const float* eRbe = (const float*)d_in[16];
  const float* eRm  = (const float*)d_in[17];
  const float* eRv  = (const float*)d_in[18];
  const float* eRW2 = (const float*)d_in[19];
  const float* eRb2 = (const float*)d_in[20];
  const float* mlpW = (const float*)d_in[21];
  const float* mlpb = (const float*)d_in[22];
  const float* decW = (const float*)d_in[23];
  const float* decb = (const float*)d_in[24];
  const float* decg = (const float*)d_in[25];
  const float* decbe= (const float*)d_in[26];
  const float* decm = (const float*)d_in[27];
  const float* decv = (const float*)d_in[28];

  float* s1 = (float*)d_out;
  float* s2 = s1 + (size_t)N1 * 64;
  float* s3 = s2 + (size_t)N2 * 64;
  float* s4 = s3 + (size_t)N4 * 64;
  float* s5 = s4 + (size_t)N8 * 64;

  // ws: fold (1024 f) | packed weights (40960 u) | oA | oB | head | nxt
  float* fold = (float*)d_ws;
  unsigned* P_e0W2 = (unsigned*)(fold + 1024);          // 1024 u
  unsigned* P_eRW1 = P_e0W2 + 1024;                     // 4096 u (4 x [32][32])
  unsigned* P_eRW2 = P_eRW1 + 4096;                     // 4096 u (4 x [16][64])
  unsigned* P_mlp  = P_eRW2 + 4096;                     // 10240 u (5 x [32][64])
  unsigned* P_dec  = P_mlp + 10240;                     // 20480 u (5 x [64][64])
  float* oA   = fold + 1024 + 40960;
  float* oB   = oA + (size_t)N2 * 64;
  int* head   = (int*)(oB + (size_t)N4 * 64);
  int* nxt    = head + N2;

  k_fold<<<1, 320, 0, stream>>>(e0g, e0be, e0m, e0v, eRg, eRbe, eRm, eRv,
                                decg, decbe, decm, decv, fold);
  k_pack<<<(1024 + 255) / 256, 256, 0, stream>>>(e0W2, P_e0W2, 1024, 64);
  k_pack<<<(4096 + 255) / 256, 256, 0, stream>>>(eRW1, P_eRW1, 4096, 32);
  k_pack<<<(4096 + 255) / 256, 256, 0, stream>>>(eRW2, P_eRW2, 4096, 64);
  k_pack<<<(10240 + 255) / 256, 256, 0, stream>>>(mlpW, P_mlp, 10240, 64);
  k_pack<<<(20480 + 255) / 256, 256, 0, stream>>>(decW, P_dec, 20480, 64);

  // ---- level 1: enc0 on N1, pool -> oA [N2] ----
  hipMemsetAsync(head, 0xFF, (size_t)N2 * 4, stream);
  k_fill<<<(N1 + 255) / 256, 256, 0, stream>>>(inv2, head, nxt, N1);
  k_enc0_s<<<(N1 + 63) / 64, 256, 0, stream>>>(pt, e0W1, e0b1, fold, P_e0W2, e0b2, s1, N1);
  k_gmax<<<((size_t)N2 * 64 + 255) / 256, 256, 0, stream>>>(s1, head, nxt, oA, N2);

  // ---- level 2: encR[0] on N2, pool -> oB [N4] ----
  hipMemsetAsync(head, 0xFF, (size_t)N4 * 4, stream);
  k_fill<<<(N2 + 255) / 256, 256, 0, stream>>>(inv4, head, nxt, N2);
  k_encR_s<<<(N2 + 63) / 64, 256, 0, stream>>>(oA, P_eRW1 + 0 * 1024, eRb1 + 0 * 32,
                                               fold + 64 + 0 * 64, P_eRW2 + 0 * 1024,
                                               eRb2 + 0 * 64, s2, N2);
  k_gmax<<<((size_t)N4 * 64 + 255) / 256, 256, 0, stream>>>(s2, head, nxt, oB, N4);

  // ---- level 3: encR[1] on N4, pool -> oA [N8] ----
  hipMemsetAsync(head, 0xFF, (size_t)N8 * 4, stream);
  k_fill<<<(N4 + 255) / 256, 256, 0, stream>>>(inv8, head, nxt, N4);
  k_encR_s<<<(N4 + 63) / 64, 256, 0, stream>>>(oB, P_eRW1 + 1 * 1024, eRb1 + 1 * 32,
                                               fold + 64 + 1 * 64, P_eRW2 + 1 * 1024,
                                               eRb2 + 1 * 64, s3, N4);
  k_gmax<<<((size_t)N8 * 64 + 255) / 256, 256, 0, stream>>>(s3, head, nxt, oA, N8);

  // ---- level 4: encR[2] on N8, pool -> oB [N16] ----
  hipMemsetAsync(head, 0xFF, (size_t)N16 * 4, stream);
  k_fill<<<(N8 + 255) / 256, 256, 0, stream>>>(inv16, head, nxt, N8);
  k_encR_s<<<(N8 + 63) / 64, 256, 0, stream>>>(oA, P_eRW1 + 2 * 1024, eRb1 + 2 * 32,
                                               fold + 64 + 2 * 64, P_eRW2 + 2 * 1024,
                                               eRb2 + 2 * 64, s4, N8);
  k_gmax<<<((size_t)N16 * 64 + 255) / 256, 256, 0, stream>>>(s4, head, nxt, oB, N16);

  // ---- level 5: encR[3] on N16 ----
  k_encR_s<<<(N16 + 63) / 64, 256, 0, stream>>>(oB, P_eRW1 + 3 * 1024, eRb1 + 3 * 32,
                                                fold + 64 + 3 * 64, P_eRW2 + 3 * 1024,
                                                eRb2 + 3 * 64, s5, N16);

  // ---- decoders with fused next-level lastT ----
  // decP mat i: top pairs at +i*4096, bottom pairs at +i*4096+2048
  k_lastT<<<(N16 + 63) / 64, 256, 0, stream>>>(s5, P_dec + 0 * 4096 + 2048, decb + 0 * 64,
                                               oA, N16);
  k_dec2<<<(N16 + 63) / 64, 256, 0, stream>>>(s5, oA, nullptr, P_mlp + 0 * 2048, mlpb + 0 * 64,
                                              P_dec + 0 * 4096, fold + 320 + 0 * 128, N16,
                                              P_dec + 1 * 4096 + 2048, decb + 1 * 64, oB);
  k_dec2<<<(N8 + 63) / 64, 256, 0, stream>>>(s4, oB, inv16, P_mlp + 1 * 2048, mlpb + 1 * 64,
                                             P_dec + 1 * 4096, fold + 320 + 1 * 128, N8,
                                             P_dec + 2 * 4096 + 2048, decb + 2 * 64, oA);
  k_dec2<<<(N4 + 63) / 64, 256, 0, stream>>>(s3, oA, inv8, P_mlp + 2 * 2048, mlpb + 2 * 64,
                                             P_dec + 2 * 4096, fold + 320 + 2 * 128, N4,
                                             P_dec + 3 * 4096 + 2048, decb + 3 * 64, oB);
  k_dec2<<<(N2 + 63) / 64, 256, 0, stream>>>(s2, oB, inv4, P_mlp + 3 * 2048, mlpb + 3 * 64,
                                             P_dec + 3 * 4096, fold + 320 + 3 * 128, N2,
                                             P_dec + 4 * 4096 + 2048, decb + 4 * 64, oA);
  k_dec2<<<(N1 + 63) / 64, 256, 0, stream>>>(s1, oA, inv2, P_mlp + 4 * 2048, mlpb + 4 * 64,
                                             P_dec + 4 * 4096, fold + 320 + 4 * 128, N1,
                                             nullptr, nullptr, nullptr);
}

// Round 18
// 910.406 us; speedup vs baseline: 2.7674x; 1.2010x over previous
//
#include <hip/hip_runtime.h>

#define N1 1000000
#define N2 400000
#define N4 150000
#define N8 60000
#define N16 20000

constexpr float BN_EPS = 1e-5f;

typedef _Float16 h2 __attribute__((ext_vector_type(2)));
typedef _Float16 h8 __attribute__((ext_vector_type(8)));
typedef float f4 __attribute__((ext_vector_type(4)));

__device__ __forceinline__ float lrelu(float x) { return fmaxf(x, 0.1f * x); }

__device__ __forceinline__ unsigned pk(float x, float y) {
  h2 h = {(_Float16)x, (_Float16)y};
  unsigned u;
  __builtin_memcpy(&u, &h, 4);
  return u;
}
__device__ __forceinline__ h2 uph(unsigned u) {
  h2 h;
  __builtin_memcpy(&h, &u, 4);
  return h;
}
__device__ __forceinline__ float fdot2(h2 a, h2 b, float c) {
  return __builtin_amdgcn_fdot2(a, b, c, false);
}
__device__ __forceinline__ h8 uph8(uint4 u) {
  h8 h;
  __builtin_memcpy(&h, &u, 16);
  return h;
}

// Fold all BatchNorm params into scale/shift once per call.
__global__ void k_fold(const float* g0, const float* be0, const float* m0, const float* v0,
                       const float* gR, const float* beR, const float* mR, const float* vR,
                       const float* gD, const float* beD, const float* mD, const float* vD,
                       float* fold) {
  int t = threadIdx.x;
  if (t < 32) {
    float sc = g0[t] * rsqrtf(v0[t] + BN_EPS);
    fold[t] = sc;
    fold[32 + t] = be0[t] - m0[t] * sc;
  }
  if (t < 128) {
    int b = t >> 5, c = t & 31;
    float sc = gR[b * 32 + c] * rsqrtf(vR[b * 32 + c] + BN_EPS);
    fold[64 + b * 64 + c] = sc;
    fold[64 + b * 64 + 32 + c] = beR[b * 32 + c] - mR[b * 32 + c] * sc;
  }
  for (int i = t; i < 320; i += blockDim.x) {
    int b = i >> 6, c = i & 63;
    float sc = gD[b * 64 + c] * rsqrtf(vD[b * 64 + c] + BN_EPS);
    fold[320 + b * 128 + c] = sc;
    fold[320 + b * 128 + 64 + c] = beD[b * 64 + c] - mD[b * 64 + c] * sc;
  }
}

// Pack fp32 [2P][C] -> half2-pair [P][C] (pair along k). (fdot2 kernels)
__global__ __launch_bounds__(256) void k_pack(const float* __restrict__ s,
                                              unsigned* __restrict__ d, int total, int C) {
  int i = blockIdx.x * 256 + threadIdx.x;
  if (i >= total) return;
  int p = i / C, c = i - p * C;
  d[i] = pk(s[(2 * p) * C + c], s[(2 * p + 1) * C + c]);
}

// Pack fp32 W[K=64][64] into MFMA B-fragment-linear half2 u32s:
// dst[((ct*2+t)*64 + lane)*4 + q] = pk(W[k0][col], W[k0+1][col]),
//   col = ct*16 + (lane&15),  k0 = t*32 + ((lane>>4)<<3) + 2q.
__global__ __launch_bounds__(256) void k_packB(const float* __restrict__ W,
                                               unsigned* __restrict__ d) {
  int i = blockIdx.x * 256 + threadIdx.x;
  if (i >= 2048) return;
  int ct = i >> 9;            // /512
  int rem = i & 511;
  int t = rem >> 8;           // /256
  int r2 = rem & 255;
  int l = r2 >> 2, q = r2 & 3;
  int col = ct * 16 + (l & 15);
  int k0 = t * 32 + ((l >> 4) << 3) + 2 * q;
  d[i] = pk(W[k0 * 64 + col], W[(k0 + 1) * 64 + col]);
}

// Build per-segment linked lists. head pre-set to -1. One 4B atomic per row.
__global__ __launch_bounds__(256) void k_fill(const int* __restrict__ idx,
                                              int* head, int* nxt, int n) {
  int i = blockIdx.x * 256 + threadIdx.x;
  if (i < n) nxt[i] = atomicExch(&head[idx[i]], i);
}

// Segment max by chained gather: one wave per segment, one thread per channel.
__global__ __launch_bounds__(256) void k_gmax(
    const float* __restrict__ src, const int* __restrict__ head,
    const int* __restrict__ nxt, float* __restrict__ dst, int nseg) {
  int t = blockIdx.x * 256 + threadIdx.x;
  int seg = t >> 6, ch = t & 63;
  if (seg >= nseg) return;
  float m = -INFINITY;
  for (int p = head[seg]; p >= 0; p = nxt[p])
    m = fmaxf(m, src[(size_t)p * 64 + ch]);
  dst[(size_t)seg * 64 + ch] = (m == -INFINITY) ? 0.0f : m;
}

// ---------------- encoder kernels: fdot2 (proven, unchanged) ----------------

__global__ __launch_bounds__(256) void k_enc0_s(
    const float* __restrict__ x,
    const float* __restrict__ W1, const float* __restrict__ b1,
    const float* __restrict__ fold,
    const unsigned* __restrict__ W2p, const float* __restrict__ b2,
    float* __restrict__ out, int n) {
  __shared__ float xS[64 * 9];
  __shared__ unsigned hP[64 * 18];
  int t = threadIdx.x;
  int lane = t & 63;
  int w = __builtin_amdgcn_readfirstlane(t >> 6);
  int R = blockIdx.x * 64;

  {
    size_t lim = (size_t)n * 9 - 1;
    for (int i = t; i < 576; i += 256) {
      size_t gi = (size_t)R * 9 + i;
      if (gi > lim) gi = lim;
      xS[i] = x[gi];
    }
  }
  __syncthreads();

  {
    const float* W1p = W1 + w * 8;
    float xr[9];
#pragma unroll
    for (int k = 0; k < 9; ++k) xr[k] = xS[lane * 9 + k];
    float acc[8];
#pragma unroll
    for (int c = 0; c < 8; ++c) acc[c] = b1[w * 8 + c];
#pragma unroll
    for (int k = 0; k < 9; ++k) {
#pragma unroll
      for (int c = 0; c < 8; ++c) acc[c] = fmaf(xr[k], W1p[k * 32 + c], acc[c]);
    }
    float v[8];
#pragma unroll
    for (int c = 0; c < 8; ++c)
      v[c] = lrelu(acc[c]) * fold[w * 8 + c] + fold[32 + w * 8 + c];
#pragma unroll
    for (int j = 0; j < 4; ++j)
      hP[lane * 18 + w * 4 + j] = pk(v[2 * j], v[2 * j + 1]);
  }
  __syncthreads();

  {
    const unsigned* Wp = W2p + w * 16;
    float o[16];
#pragma unroll
    for (int c = 0; c < 16; ++c) o[c] = b2[w * 16 + c];
    for (int k0 = 0; k0 < 16; k0 += 8) {
      unsigned au[8];
#pragma unroll
      for (int j = 0; j < 8; ++j) au[j] = hP[lane * 18 + k0 + j];
#pragma unroll
      for (int j = 0; j < 8; ++j) {
        h2 a = uph(au[j]);
#pragma unroll
        for (int c = 0; c < 16; ++c)
          o[c] = fdot2(a, uph(Wp[(k0 + j) * 64 + c]), o[c]);
      }
    }
    int gr = R + lane;
    if (gr < n) {
      float* op = out + (size_t)gr * 64 + w * 16;
#pragma unroll
      for (int c = 0; c < 16; ++c) op[c] = lrelu(o[c]);
    }
  }
}

__global__ __launch_bounds__(256) void k_encR_s(
    const float* __restrict__ xin,
    const unsigned* __restrict__ W1p, const float* __restrict__ b1,
    const float* __restrict__ fold,
    const unsigned* __restrict__ W2p, const float* __restrict__ b2,
    float* __restrict__ out, int n) {
  __shared__ unsigned inP[64 * 34];
  __shared__ unsigned hP[64 * 18];
  int t = threadIdx.x;
  int lane = t & 63;
  int w = __builtin_amdgcn_readfirstlane(t >> 6);
  int R = blockIdx.x * 64;

  for (int f = t; f < 1024; f += 256) {
    int row = f >> 4, c4 = (f & 15) << 2;
    int gr = R + row; if (gr >= n) gr = n - 1;
    float4 v = *(const float4*)(xin + (size_t)gr * 64 + c4);
    inP[row * 34 + (c4 >> 1)] = pk(v.x, v.y);
    inP[row * 34 + (c4 >> 1) + 1] = pk(v.z, v.w);
  }
  __syncthreads();

  {
    const unsigned* Wp = W1p + w * 8;
    float acc[8];
#pragma unroll
    for (int c = 0; c < 8; ++c) acc[c] = b1[w * 8 + c];
    for (int k0 = 0; k0 < 32; k0 += 8) {
      unsigned au[8];
#pragma unroll
      for (int j = 0; j < 8; ++j) au[j] = inP[lane * 34 + k0 + j];
#pragma unroll
      for (int j = 0; j < 8; ++j) {
        h2 a = uph(au[j]);
#pragma unroll
        for (int c = 0; c < 8; ++c)
          acc[c] = fdot2(a, uph(Wp[(k0 + j) * 32 + c]), acc[c]);
      }
    }
    float v[8];
#pragma unroll
    for (int c = 0; c < 8; ++c)
      v[c] = lrelu(acc[c]) * fold[w * 8 + c] + fold[32 + w * 8 + c];
#pragma unroll
    for (int j = 0; j < 4; ++j)
      hP[lane * 18 + w * 4 + j] = pk(v[2 * j], v[2 * j + 1]);
  }
  __syncthreads();

  {
    const unsigned* Wp = W2p + w * 16;
    float o[16];
#pragma unroll
    for (int c = 0; c < 16; ++c) o[c] = b2[w * 16 + c];
    for (int k0 = 0; k0 < 16; k0 += 8) {
      unsigned au[8];
#pragma unroll
      for (int j = 0; j < 8; ++j) au[j] = hP[lane * 18 + k0 + j];
#pragma unroll
      for (int j = 0; j < 8; ++j) {
        h2 a = uph(au[j]);
#pragma unroll
        for (int c = 0; c < 16; ++c)
          o[c] = fdot2(a, uph(Wp[(k0 + j) * 64 + c]), o[c]);
      }
    }
    int gr = R + lane;
    if (gr < n) {
      float* op = out + (size_t)gr * 64 + w * 16;
#pragma unroll
      for (int c = 0; c < 16; ++c) op[c] = lrelu(o[c]);
    }
  }
}

// ---------------- MFMA decoder kernels ----------------
// Block = 256 thr (4 waves); tile 64 rows. Wave w owns rows 16w..16w+15.
// LDS buf: [64 rows][36 u32] (= 72 halves/row, 16B-aligned, <=2-way banks).
// A-frag (M=16,K=32): lane l -> row 16w+(l&15), k = (l>>4)*8..+7
//   = ds_read_b128 at u32 off row*36 + t*16 + (l>>4)*4.
// B-frag: fragment-linear packed buffer (k_packB), one dwordx4 per lane.
// D: row = 16w + (l>>4)*4 + reg, col = ct*16 + (l&15)   [verified m89 mapping]

// lastT = src @ decW_bot + decb  (seed, MFMA)
__global__ __launch_bounds__(256) void k_lastT_m(
    const float* __restrict__ src, const unsigned* __restrict__ Fbot,
    const float* __restrict__ decb, float* __restrict__ lT, int n) {
  __shared__ unsigned P[64 * 36];
  int t = threadIdx.x;
  int lane = t & 63;
  int w = __builtin_amdgcn_readfirstlane(t >> 6);
  int R = blockIdx.x * 64;
  int l15 = lane & 15, lg = lane >> 4;

  for (int f = t; f < 1024; f += 256) {
    int row = f >> 4, c4 = (f & 15) << 2;
    int gr = R + row; if (gr >= n) gr = n - 1;
    float4 v = *(const float4*)(src + (size_t)gr * 64 + c4);
    P[row * 36 + (f & 15) * 2] = pk(v.x, v.y);
    P[row * 36 + (f & 15) * 2 + 1] = pk(v.z, v.w);
  }
  __syncthreads();

  int arow = 16 * w + l15;
  h8 a0 = uph8(*(const uint4*)(P + arow * 36 + 0 * 16 + lg * 4));
  h8 a1 = uph8(*(const uint4*)(P + arow * 36 + 1 * 16 + lg * 4));

#pragma unroll
  for (int ct = 0; ct < 4; ++ct) {
    h8 b0 = uph8(*(const uint4*)(Fbot + ((ct * 2 + 0) * 64 + lane) * 4));
    h8 b1 = uph8(*(const uint4*)(Fbot + ((ct * 2 + 1) * 64 + lane) * 4));
    f4 c = {0.f, 0.f, 0.f, 0.f};
    c = __builtin_amdgcn_mfma_f32_16x16x32_f16(a0, b0, c, 0, 0, 0);
    c = __builtin_amdgcn_mfma_f32_16x16x32_f16(a1, b1, c, 0, 0, 0);
    int col = ct * 16 + l15;
    float bias = decb[col];
#pragma unroll
    for (int r = 0; r < 4; ++r) {
      int grow = R + 16 * w + lg * 4 + r;
      if (grow < n) lT[(size_t)grow * 64 + col] = c[r] + bias;
    }
  }
}

// decoder: out = lrelu(BN(lrelu(cur@mlp) @ decTop + lT[lrow])); optional
// phase 3: lTout = out @ decNextBot + decbN (fused next-level lastT).
__global__ __launch_bounds__(256) void k_dec2_m(
    float* inout, const float* __restrict__ lT, const int* __restrict__ idx,
    const unsigned* __restrict__ Fmlp, const float* __restrict__ mlpb,
    const unsigned* __restrict__ Ftop, const float* __restrict__ fold, int n,
    const unsigned* __restrict__ FnextBot, const float* __restrict__ decbN,
    float* __restrict__ lTout) {
  __shared__ unsigned P[64 * 36];
  int t = threadIdx.x;
  int lane = t & 63;
  int w = __builtin_amdgcn_readfirstlane(t >> 6);
  int R = blockIdx.x * 64;
  int l15 = lane & 15, lg = lane >> 4;
  _Float16* H = (_Float16*)P;

  for (int f = t; f < 1024; f += 256) {
    int row = f >> 4, c4 = (f & 15) << 2;
    int gr = R + row; if (gr >= n) gr = n - 1;
    float4 v = *(const float4*)(inout + (size_t)gr * 64 + c4);
    P[row * 36 + (f & 15) * 2] = pk(v.x, v.y);
    P[row * 36 + (f & 15) * 2 + 1] = pk(v.z, v.w);
  }

  // lT gather rows (consumed in phase 2); issue address math early
  int grow_[4], gidx_[4];
#pragma unroll
  for (int r = 0; r < 4; ++r) {
    grow_[r] = R + 16 * w + lg * 4 + r;
    int gcl = grow_[r] >= n ? n - 1 : grow_[r];
    gidx_[r] = idx ? idx[gcl] : gcl;
  }
  float lv[4][4];  // [r][ct]
#pragma unroll
  for (int r = 0; r < 4; ++r) {
#pragma unroll
    for (int ct = 0; ct < 4; ++ct)
      lv[r][ct] = lT[(size_t)gidx_[r] * 64 + ct * 16 + l15];
  }
  __syncthreads();

  int arow = 16 * w + l15;

  // phase 1: skip = lrelu(cur @ mlpW + mlpb)
  float sk[4][4];  // [ct][r]
  {
    h8 a0 = uph8(*(const uint4*)(P + arow * 36 + 0 * 16 + lg * 4));
    h8 a1 = uph8(*(const uint4*)(P + arow * 36 + 1 * 16 + lg * 4));
#pragma unroll
    for (int ct = 0; ct < 4; ++ct) {
      h8 b0 = uph8(*(const uint4*)(Fmlp + ((ct * 2 + 0) * 64 + lane) * 4));
      h8 b1 = uph8(*(const uint4*)(Fmlp + ((ct * 2 + 1) * 64 + lane) * 4));
      f4 c = {0.f, 0.f, 0.f, 0.f};
      c = __builtin_amdgcn_mfma_f32_16x16x32_f16(a0, b0, c, 0, 0, 0);
      c = __builtin_amdgcn_mfma_f32_16x16x32_f16(a1, b1, c, 0, 0, 0);
      float bias = mlpb[ct * 16 + l15];
#pragma unroll
      for (int r = 0; r < 4; ++r) sk[ct][r] = lrelu(c[r] + bias);
    }
  }
  __syncthreads();  // all phase-1 A reads done
#pragma unroll
  for (int ct = 0; ct < 4; ++ct) {
#pragma unroll
    for (int r = 0; r < 4; ++r)
      H[(16 * w + lg * 4 + r) * 72 + ct * 16 + l15] = (_Float16)sk[ct][r];
  }
  __syncthreads();

  // phase 2: out = skip @ decTop + lT, BN, lrelu
  float fv[4][4];  // [ct][r]
  {
    h8 a0 = uph8(*(const uint4*)(P + arow * 36 + 0 * 16 + lg * 4));
    h8 a1 = uph8(*(const uint4*)(P + arow * 36 + 1 * 16 + lg * 4));
#pragma unroll
    for (int ct = 0; ct < 4; ++ct) {
      h8 b0 = uph8(*(const uint4*)(Ftop + ((ct * 2 + 0) * 64 + lane) * 4));
      h8 b1 = uph8(*(const uint4*)(Ftop + ((ct * 2 + 1) * 64 + lane) * 4));
      f4 c = {0.f, 0.f, 0.f, 0.f};
      c = __builtin_amdgcn_mfma_f32_16x16x32_f16(a0, b0, c, 0, 0, 0);
      c = __builtin_amdgcn_mfma_f32_16x16x32_f16(a1, b1, c, 0, 0, 0);
      int col = ct * 16 + l15;
      float sc = fold[col], sh = fold[64 + col];
#pragma unroll
      for (int r = 0; r < 4; ++r) {
        float ov = (c[r] + lv[r][ct]) * sc + sh;
        fv[ct][r] = lrelu(ov);
        if (grow_[r] < n) inout[(size_t)grow_[r] * 64 + col] = fv[ct][r];
      }
    }
  }

  // phase 3 (optional): lTout = out @ decNextBot + decbN
  if (FnextBot) {
    __syncthreads();
#pragma unroll
    for (int ct = 0; ct < 4; ++ct) {
#pragma unroll
      for (int r = 0; r < 4; ++r)
        H[(16 * w + lg * 4 + r) * 72 + ct * 16 + l15] = (_Float16)fv[ct][r];
    }
    __syncthreads();
    h8 a0 = uph8(*(const uint4*)(P + arow * 36 + 0 * 16 + lg * 4));
    h8 a1 = uph8(*(const uint4*)(P + arow * 36 + 1 * 16 + lg * 4));
#pragma unroll
    for (int ct = 0; ct < 4; ++ct) {
      h8 b0 = uph8(*(const uint4*)(FnextBot + ((ct * 2 + 0) * 64 + lane) * 4));
      h8 b1 = uph8(*(const uint4*)(FnextBot + ((ct * 2 + 1) * 64 + lane) * 4));
      f4 c = {0.f, 0.f, 0.f, 0.f};
      c = __builtin_amdgcn_mfma_f32_16x16x32_f16(a0, b0, c, 0, 0, 0);
      c = __builtin_amdgcn_mfma_f32_16x16x32_f16(a1, b1, c, 0, 0, 0);
      int col = ct * 16 + l15;
      float bias = decbN[col];
#pragma unroll
      for (int r = 0; r < 4; ++r)
        if (grow_[r] < n) lTout[(size_t)grow_[r] * 64 + col] = c[r] + bias;
    }
  }
}

extern "C" void kernel_launch(void* const* d_in, const int* in_sizes, int n_in,
                              void* d_out, int out_size, void* d_ws, size_t ws_size,
                              hipStream_t stream) {
  const float* pt   = (const float*)d_in[0];
  const int* inv2   = (const int*)d_in[1];
  const int* inv4   = (const int*)d_in[2];
  const int* inv8   = (const int*)d_in[3];
  const int* inv16  = (const int*)d_in[4];
  const float* e0W1 = (const float*)d_in[5];
  const float* e0b1 = (const float*)d_in[6];
  const float* e0g  = (const float*)d_in[7];
  const float* e0be = (const float*)d_in[8];
  const float* e0m  = (const float*)d_in[9];
  const float* e0v  = (const float*)d_in[10];
  const float* e0W2 = (const float*)d_in[11];
  const float* e0b2 = (const float*)d_in[12];
  const float* eRW1 = (const float*)d_in[13];
  const float* eRb1 = (const float*)d_in[14];
  const float* eRg  = (const float*)d_in[15];
  const float* eRbe = (const float*)d_in[16];
  const float* eRm  = (const float*)d_in[17];
  const float* eRv  = (const float*)d_in[18];
  const float* eRW2 = (const float*)d_in[19];
  const float* eRb2 = (const float*)d_in[20];
  const float* mlpW = (const float*)d_in[21];
  const float* mlpb = (const float*)d_in[22];
  const float* decW = (const float*)d_in[23];
  const float* decb = (const float*)d_in[24];
  const float* decg = (const float*)d_in[25];
  const float* decbe= (const float*)d_in[26];
  const float* decm = (const float*)d_in[27];
  const float* decv = (const float*)d_in[28];

  float* s1 = (float*)d_out;
  float* s2 = s1 + (size_t)N1 * 64;
  float* s3 = s2 + (size_t)N2 * 64;
  float* s4 = s3 + (size_t)N4 * 64;
  float* s5 = s4 + (size_t)N8 * 64;

  // ws: fold | enc packs | MFMA fragment packs | oA | oB | head | nxt
  float* fold = (float*)d_ws;
  unsigned* P_e0W2 = (unsigned*)(fold + 1024);   // 1024 u
  unsigned* P_eRW1 = P_e0W2 + 1024;              // 4096 u
  unsigned* P_eRW2 = P_eRW1 + 4096;              // 4096 u
  unsigned* F_mlp  = P_eRW2 + 4096;              // 5*2048 u
  unsigned* F_top  = F_mlp + 10240;              // 5*2048 u
  unsigned* F_bot  = F_top + 10240;              // 5*2048 u
  float* oA   = (float*)(F_bot + 10240);
  float* oB   = oA + (size_t)N2 * 64;
  int* head   = (int*)(oB + (size_t)N4 * 64);
  int* nxt    = head + N2;

  k_fold<<<1, 320, 0, stream>>>(e0g, e0be, e0m, e0v, eRg, eRbe, eRm, eRv,
                                decg, decbe, decm, decv, fold);
  k_pack<<<4, 256, 0, stream>>>(e0W2, P_e0W2, 1024, 64);
  k_pack<<<16, 256, 0, stream>>>(eRW1, P_eRW1, 4096, 32);
  k_pack<<<16, 256, 0, stream>>>(eRW2, P_eRW2, 4096, 64);
  for (int i = 0; i < 5; ++i) {
    k_packB<<<8, 256, 0, stream>>>(mlpW + i * 4096, F_mlp + i * 2048);
    k_packB<<<8, 256, 0, stream>>>(decW + i * 8192, F_top + i * 2048);
    k_packB<<<8, 256, 0, stream>>>(decW + i * 8192 + 4096, F_bot + i * 2048);
  }

  // ---- level 1: enc0 on N1, pool -> oA [N2] ----
  hipMemsetAsync(head, 0xFF, (size_t)N2 * 4, stream);
  k_fill<<<(N1 + 255) / 256, 256, 0, stream>>>(inv2, head, nxt, N1);
  k_enc0_s<<<(N1 + 63) / 64, 256, 0, stream>>>(pt, e0W1, e0b1, fold, P_e0W2, e0b2, s1, N1);
  k_gmax<<<((size_t)N2 * 64 + 255) / 256, 256, 0, stream>>>(s1, head, nxt, oA, N2);

  // ---- level 2: encR[0] on N2, pool -> oB [N4] ----
  hipMemsetAsync(head, 0xFF, (size_t)N4 * 4, stream);
  k_fill<<<(N2 + 255) / 256, 256, 0, stream>>>(inv4, head, nxt, N2);
  k_encR_s<<<(N2 + 63) / 64, 256, 0, stream>>>(oA, P_eRW1 + 0 * 1024, eRb1 + 0 * 32,
                                               fold + 64 + 0 * 64, P_eRW2 + 0 * 1024,
                                               eRb2 + 0 * 64, s2, N2);
  k_gmax<<<((size_t)N4 * 64 + 255) / 256, 256, 0, stream>>>(s2, head, nxt, oB, N4);

  // ---- level 3: encR[1] on N4, pool -> oA [N8] ----
  hipMemsetAsync(head, 0xFF, (size_t)N8 * 4, stream);
  k_fill<<<(N4 + 255) / 256, 256, 0, stream>>>(inv8, head, nxt, N4);
  k_encR_s<<<(N4 + 63) / 64, 256, 0, stream>>>(oB, P_eRW1 + 1 * 1024, eRb1 + 1 * 32,
                                               fold + 64 + 1 * 64, P_eRW2 + 1 * 1024,
                                               eRb2 + 1 * 64, s3, N4);
  k_gmax<<<((size_t)N8 * 64 + 255) / 256, 256, 0, stream>>>(s3, head, nxt, oA, N8);

  // ---- level 4: encR[2] on N8, pool -> oB [N16] ----
  hipMemsetAsync(head, 0xFF, (size_t)N16 * 4, stream);
  k_fill<<<(N8 + 255) / 256, 256, 0, stream>>>(inv16, head, nxt, N8);
  k_encR_s<<<(N8 + 63) / 64, 256, 0, stream>>>(oA, P_eRW1 + 2 * 1024, eRb1 + 2 * 32,
                                               fold + 64 + 2 * 64, P_eRW2 + 2 * 1024,
                                               eRb2 + 2 * 64, s4, N8);
  k_gmax<<<((size_t)N16 * 64 + 255) / 256, 256, 0, stream>>>(s4, head, nxt, oB, N16);

  // ---- level 5: encR[3] on N16 ----
  k_encR_s<<<(N16 + 63) / 64, 256, 0, stream>>>(oB, P_eRW1 + 3 * 1024, eRb1 + 3 * 32,
                                                fold + 64 + 3 * 64, P_eRW2 + 3 * 1024,
                                                eRb2 + 3 * 64, s5, N16);

  // ---- decoders (MFMA) with fused next-level lastT ----
  k_lastT_m<<<(N16 + 63) / 64, 256, 0, stream>>>(s5, F_bot + 0 * 2048, decb + 0 * 64, oA, N16);
  k_dec2_m<<<(N16 + 63) / 64, 256, 0, stream>>>(s5, oA, nullptr, F_mlp + 0 * 2048, mlpb + 0 * 64,
                                                F_top + 0 * 2048, fold + 320 + 0 * 128, N16,
                                                F_bot + 1 * 2048, decb + 1 * 64, oB);
  k_dec2_m<<<(N8 + 63) / 64, 256, 0, stream>>>(s4, oB, inv16, F_mlp + 1 * 2048, mlpb + 1 * 64,
                                               F_top + 1 * 2048, fold + 320 + 1 * 128, N8,
                                               F_bot + 2 * 2048, decb + 2 * 64, oA);
  k_dec2_m<<<(N4 + 63) / 64, 256, 0, stream>>>(s3, oA, inv8, F_mlp + 2 * 2048, mlpb + 2 * 64,
                                               F_top + 2 * 2048, fold + 320 + 2 * 128, N4,
                                               F_bot + 3 * 2048, decb + 3 * 64, oB);
  k_dec2_m<<<(N2 + 63) / 64, 256, 0, stream>>>(s2, oB, inv4, F_mlp + 3 * 2048, mlpb + 3 * 64,
                                               F_top + 3 * 2048, fold + 320 + 3 * 128, N2,
                                               F_bot + 4 * 2048, decb + 4 * 64, oA);
  k_dec2_m<<<(N1 + 63) / 64, 256, 0, stream>>>(s1, oA, inv2, F_mlp + 4 * 2048, mlpb + 4 * 64,
                                               F_top + 4 * 2048, fold + 320 + 4 * 128, N1,
                                               nullptr, nullptr, nullptr);
}

// Round 19
// 862.044 us; speedup vs baseline: 2.9227x; 1.0561x over previous
//
#include <hip/hip_runtime.h>

#define N1 1000000
#define N2 400000
#define N4 150000
#define N8 60000
#define N16 20000

constexpr float BN_EPS = 1e-5f;

typedef _Float16 h2 __attribute__((ext_vector_type(2)));
typedef _Float16 h8 __attribute__((ext_vector_type(8)));
typedef float f4 __attribute__((ext_vector_type(4)));

__device__ __forceinline__ float lrelu(float x) { return fmaxf(x, 0.1f * x); }

__device__ __forceinline__ unsigned pk(float x, float y) {
  h2 h = {(_Float16)x, (_Float16)y};
  unsigned u;
  __builtin_memcpy(&u, &h, 4);
  return u;
}
__device__ __forceinline__ h8 uph8(uint4 u) {
  h8 h;
  __builtin_memcpy(&h, &u, 16);
  return h;
}

// Fold all BatchNorm params into scale/shift once per call.
__global__ void k_fold(const float* g0, const float* be0, const float* m0, const float* v0,
                       const float* gR, const float* beR, const float* mR, const float* vR,
                       const float* gD, const float* beD, const float* mD, const float* vD,
                       float* fold) {
  int t = threadIdx.x;
  if (t < 32) {
    float sc = g0[t] * rsqrtf(v0[t] + BN_EPS);
    fold[t] = sc;
    fold[32 + t] = be0[t] - m0[t] * sc;
  }
  if (t < 128) {
    int b = t >> 5, c = t & 31;
    float sc = gR[b * 32 + c] * rsqrtf(vR[b * 32 + c] + BN_EPS);
    fold[64 + b * 64 + c] = sc;
    fold[64 + b * 64 + 32 + c] = beR[b * 32 + c] - mR[b * 32 + c] * sc;
  }
  for (int i = t; i < 320; i += blockDim.x) {
    int b = i >> 6, c = i & 63;
    float sc = gD[b * 64 + c] * rsqrtf(vD[b * 64 + c] + BN_EPS);
    fold[320 + b * 128 + c] = sc;
    fold[320 + b * 128 + 64 + c] = beD[b * 64 + c] - mD[b * 64 + c] * sc;
  }
}

// Generic MFMA B-fragment pack: W[K][C] (row-major, stride C, K=KT*32) ->
// d[((ct*KT + t)*64 + l)*4 + q] = pk(W[k0][col], W[k0+1][col]),
//   col = ct*16 + (l&15), k0 = t*32 + ((l>>4)<<3) + 2q.  total = (C/16)*KT*256.
__global__ __launch_bounds__(256) void k_packB(const float* __restrict__ W,
                                               unsigned* __restrict__ d,
                                               int C, int KT, int total) {
  int i = blockIdx.x * 256 + threadIdx.x;
  if (i >= total) return;
  int q = i & 3, l = (i >> 2) & 63;
  int rest = i >> 8;
  int t = rest % KT, ct = rest / KT;
  int col = ct * 16 + (l & 15);
  int k0 = t * 32 + ((l >> 4) << 3) + 2 * q;
  d[i] = pk(W[k0 * C + col], W[(k0 + 1) * C + col]);
}

// Build per-segment linked lists. head pre-set to -1. One 4B atomic per row.
__global__ __launch_bounds__(256) void k_fill(const int* __restrict__ idx,
                                              int* head, int* nxt, int n) {
  int i = blockIdx.x * 256 + threadIdx.x;
  if (i < n) nxt[i] = atomicExch(&head[idx[i]], i);
}

// Segment max by chained gather: one wave per segment, one thread per channel.
__global__ __launch_bounds__(256) void k_gmax(
    const float* __restrict__ src, const int* __restrict__ head,
    const int* __restrict__ nxt, float* __restrict__ dst, int nseg) {
  int t = blockIdx.x * 256 + threadIdx.x;
  int seg = t >> 6, ch = t & 63;
  if (seg >= nseg) return;
  float m = -INFINITY;
  for (int p = head[seg]; p >= 0; p = nxt[p])
    m = fmaxf(m, src[(size_t)p * 64 + ch]);
  dst[(size_t)seg * 64 + ch] = (m == -INFINITY) ? 0.0f : m;
}

// ---------------- MFMA GEMM kernels ----------------
// Block = 256 thr (4 waves); tile 64 rows; wave w owns rows 16w..16w+15.
// A (K=64): LDS [64 rows][36 u32]; lane l: row 16w+(l&15), k=(l>>4)*8..+7
//   -> ds_read_b128 at u32 off row*36 + t*16 + (l>>4)*4.
// A (K=32): LDS [64 rows][20 u32] (40 halves, 16B-aligned rows).
// B: fragment-linear packed buffers (k_packB), one dwordx4 per lane.
// D: row = 16w + (l>>4)*4 + reg, col = ct*16 + (l&15)  [verified m89 + R18]

// encoder block 0: x[9] -> h[32] (fp32 K=9, lrelu,BN) -> out[64] (MFMA K=32)
__global__ __launch_bounds__(256) void k_enc0_m(
    const float* __restrict__ x,
    const float* __restrict__ W1, const float* __restrict__ b1,
    const float* __restrict__ fold,
    const unsigned* __restrict__ F2, const float* __restrict__ b2,
    float* __restrict__ out, int n) {
  __shared__ float xS[64 * 9];
  __shared__ unsigned hP[64 * 20];
  int t = threadIdx.x;
  int lane = t & 63;
  int w = __builtin_amdgcn_readfirstlane(t >> 6);
  int R = blockIdx.x * 64;
  int l15 = lane & 15, lg = lane >> 4;

  {
    size_t lim = (size_t)n * 9 - 1;
    for (int i = t; i < 576; i += 256) {
      size_t gi = (size_t)R * 9 + i;
      if (gi > lim) gi = lim;
      xS[i] = x[gi];
    }
  }
  __syncthreads();

  // phase 1 (fp32): h cols 8w..8w+7 for row=lane; K=9; pack into hP
  {
    const float* W1p = W1 + w * 8;
    float xr[9];
#pragma unroll
    for (int k = 0; k < 9; ++k) xr[k] = xS[lane * 9 + k];
    float acc[8];
#pragma unroll
    for (int c = 0; c < 8; ++c) acc[c] = b1[w * 8 + c];
#pragma unroll
    for (int k = 0; k < 9; ++k) {
#pragma unroll
      for (int c = 0; c < 8; ++c) acc[c] = fmaf(xr[k], W1p[k * 32 + c], acc[c]);
    }
    float v[8];
#pragma unroll
    for (int c = 0; c < 8; ++c)
      v[c] = lrelu(acc[c]) * fold[w * 8 + c] + fold[32 + w * 8 + c];
#pragma unroll
    for (int j = 0; j < 4; ++j)
      hP[lane * 20 + w * 4 + j] = pk(v[2 * j], v[2 * j + 1]);
  }
  __syncthreads();

  // phase 2 (MFMA): out = lrelu(h @ W2 + b2), K=32
  {
    int arow = 16 * w + l15;
    h8 a = uph8(*(const uint4*)(hP + arow * 20 + lg * 4));
#pragma unroll
    for (int ct = 0; ct < 4; ++ct) {
      h8 b = uph8(*(const uint4*)(F2 + (ct * 64 + lane) * 4));
      f4 c = {0.f, 0.f, 0.f, 0.f};
      c = __builtin_amdgcn_mfma_f32_16x16x32_f16(a, b, c, 0, 0, 0);
      int col = ct * 16 + l15;
      float bias = b2[col];
#pragma unroll
      for (int r = 0; r < 4; ++r) {
        int grow = R + 16 * w + lg * 4 + r;
        if (grow < n) out[(size_t)grow * 64 + col] = lrelu(c[r] + bias);
      }
    }
  }
}

// encoder blocks 1..4: in[64] -> h[32] (MFMA K=64, lrelu,BN) -> out[64] (MFMA K=32)
__global__ __launch_bounds__(256) void k_encR_m(
    const float* __restrict__ xin,
    const unsigned* __restrict__ F1, const float* __restrict__ b1,
    const float* __restrict__ fold,
    const unsigned* __restrict__ F2, const float* __restrict__ b2,
    float* __restrict__ out, int n) {
  __shared__ unsigned P[64 * 36];
  __shared__ unsigned hP[64 * 20];
  int t = threadIdx.x;
  int lane = t & 63;
  int w = __builtin_amdgcn_readfirstlane(t >> 6);
  int R = blockIdx.x * 64;
  int l15 = lane & 15, lg = lane >> 4;
  _Float16* Hh = (_Float16*)hP;

  for (int f = t; f < 1024; f += 256) {
    int row = f >> 4, c4 = (f & 15) << 2;
    int gr = R + row; if (gr >= n) gr = n - 1;
    float4 v = *(const float4*)(xin + (size_t)gr * 64 + c4);
    P[row * 36 + (f & 15) * 2] = pk(v.x, v.y);
    P[row * 36 + (f & 15) * 2 + 1] = pk(v.z, v.w);
  }
  __syncthreads();

  int arow = 16 * w + l15;

  // phase 1 (MFMA): h = lrelu(x @ W1 + b1) * sc + sh, K=64, 2 col tiles
  {
    h8 a0 = uph8(*(const uint4*)(P + arow * 36 + 0 * 16 + lg * 4));
    h8 a1 = uph8(*(const uint4*)(P + arow * 36 + 1 * 16 + lg * 4));
#pragma unroll
    for (int ct = 0; ct < 2; ++ct) {
      h8 b0 = uph8(*(const uint4*)(F1 + ((ct * 2 + 0) * 64 + lane) * 4));
      h8 b1v = uph8(*(const uint4*)(F1 + ((ct * 2 + 1) * 64 + lane) * 4));
      f4 c = {0.f, 0.f, 0.f, 0.f};
      c = __builtin_amdgcn_mfma_f32_16x16x32_f16(a0, b0, c, 0, 0, 0);
      c = __builtin_amdgcn_mfma_f32_16x16x32_f16(a1, b1v, c, 0, 0, 0);
      int col = ct * 16 + l15;
      float bias = b1[col], sc = fold[col], sh = fold[32 + col];
#pragma unroll
      for (int r = 0; r < 4; ++r) {
        int row = 16 * w + lg * 4 + r;
        Hh[row * 40 + col] = (_Float16)(lrelu(c[r] + bias) * sc + sh);
      }
    }
  }
  __syncthreads();

  // phase 2 (MFMA): out = lrelu(h @ W2 + b2), K=32
  {
    h8 a = uph8(*(const uint4*)(hP + arow * 20 + lg * 4));
#pragma unroll
    for (int ct = 0; ct < 4; ++ct) {
      h8 b = uph8(*(const uint4*)(F2 + (ct * 64 + lane) * 4));
      f4 c = {0.f, 0.f, 0.f, 0.f};
      c = __builtin_amdgcn_mfma_f32_16x16x32_f16(a, b, c, 0, 0, 0);
      int col = ct * 16 + l15;
      float bias = b2[col];
#pragma unroll
      for (int r = 0; r < 4; ++r) {
        int grow = R + 16 * w + lg * 4 + r;
        if (grow < n) out[(size_t)grow * 64 + col] = lrelu(c[r] + bias);
      }
    }
  }
}

// lastT = src @ decW_bot + decb  (seed, MFMA K=64)
__global__ __launch_bounds__(256) void k_lastT_m(
    const float* __restrict__ src, const unsigned* __restrict__ Fbot,
    const float* __restrict__ decb, float* __restrict__ lT, int n) {
  __shared__ unsigned P[64 * 36];
  int t = threadIdx.x;
  int lane = t & 63;
  int w = __builtin_amdgcn_readfirstlane(t >> 6);
  int R = blockIdx.x * 64;
  int l15 = lane & 15, lg = lane >> 4;

  for (int f = t; f < 1024; f += 256) {
    int row = f >> 4, c4 = (f & 15) << 2;
    int gr = R + row; if (gr >= n) gr = n - 1;
    float4 v = *(const float4*)(src + (size_t)gr * 64 + c4);
    P[row * 36 + (f & 15) * 2] = pk(v.x, v.y);
    P[row * 36 + (f & 15) * 2 + 1] = pk(v.z, v.w);
  }
  __syncthreads();

  int arow = 16 * w + l15;
  h8 a0 = uph8(*(const uint4*)(P + arow * 36 + 0 * 16 + lg * 4));
  h8 a1 = uph8(*(const uint4*)(P + arow * 36 + 1 * 16 + lg * 4));

#pragma unroll
  for (int ct = 0; ct < 4; ++ct) {
    h8 b0 = uph8(*(const uint4*)(Fbot + ((ct * 2 + 0) * 64 + lane) * 4));
    h8 b1 = uph8(*(const uint4*)(Fbot + ((ct * 2 + 1) * 64 + lane) * 4));
    f4 c = {0.f, 0.f, 0.f, 0.f};
    c = __builtin_amdgcn_mfma_f32_16x16x32_f16(a0, b0, c, 0, 0, 0);
    c = __builtin_amdgcn_mfma_f32_16x16x32_f16(a1, b1, c, 0, 0, 0);
    int col = ct * 16 + l15;
    float bias = decb[col];
#pragma unroll
    for (int r = 0; r < 4; ++r) {
      int grow = R + 16 * w + lg * 4 + r;
      if (grow < n) lT[(size_t)grow * 64 + col] = c[r] + bias;
    }
  }
}

// decoder: out = lrelu(BN(lrelu(cur@mlp) @ decTop + lT[lrow])); optional
// phase 3: lTout = out @ decNextBot + decbN (fused next-level lastT).
__global__ __launch_bounds__(256) void k_dec2_m(
    float* inout, const float* __restrict__ lT, const int* __restrict__ idx,
    const unsigned* __restrict__ Fmlp, const float* __restrict__ mlpb,
    const unsigned* __restrict__ Ftop, const float* __restrict__ fold, int n,
    const unsigned* __restrict__ FnextBot, const float* __restrict__ decbN,
    float* __restrict__ lTout) {
  __shared__ unsigned P[64 * 36];
  int t = threadIdx.x;
  int lane = t & 63;
  int w = __builtin_amdgcn_readfirstlane(t >> 6);
  int R = blockIdx.x * 64;
  int l15 = lane & 15, lg = lane >> 4;
  _Float16* H = (_Float16*)P;

  for (int f = t; f < 1024; f += 256) {
    int row = f >> 4, c4 = (f & 15) << 2;
    int gr = R + row; if (gr >= n) gr = n - 1;
    float4 v = *(const float4*)(inout + (size_t)gr * 64 + c4);
    P[row * 36 + (f & 15) * 2] = pk(v.x, v.y);
    P[row * 36 + (f & 15) * 2 + 1] = pk(v.z, v.w);
  }

  int grow_[4], gidx_[4];
#pragma unroll
  for (int r = 0; r < 4; ++r) {
    grow_[r] = R + 16 * w + lg * 4 + r;
    int gcl = grow_[r] >= n ? n - 1 : grow_[r];
    gidx_[r] = idx ? idx[gcl] : gcl;
  }
  float lv[4][4];  // [r][ct]
#pragma unroll
  for (int r = 0; r < 4; ++r) {
#pragma unroll
    for (int ct = 0; ct < 4; ++ct)
      lv[r][ct] = lT[(size_t)gidx_[r] * 64 + ct * 16 + l15];
  }
  __syncthreads();

  int arow = 16 * w + l15;

  // phase 1: skip = lrelu(cur @ mlpW + mlpb)
  float sk[4][4];  // [ct][r]
  {
    h8 a0 = uph8(*(const uint4*)(P + arow * 36 + 0 * 16 + lg * 4));
    h8 a1 = uph8(*(const uint4*)(P + arow * 36 + 1 * 16 + lg * 4));
#pragma unroll
    for (int ct = 0; ct < 4; ++ct) {
      h8 b0 = uph8(*(const uint4*)(Fmlp + ((ct * 2 + 0) * 64 + lane) * 4));
      h8 b1 = uph8(*(const uint4*)(Fmlp + ((ct * 2 + 1) * 64 + lane) * 4));
      f4 c = {0.f, 0.f, 0.f, 0.f};
      c = __builtin_amdgcn_mfma_f32_16x16x32_f16(a0, b0, c, 0, 0, 0);
      c = __builtin_amdgcn_mfma_f32_16x16x32_f16(a1, b1, c, 0, 0, 0);
      float bias = mlpb[ct * 16 + l15];
#pragma unroll
      for (int r = 0; r < 4; ++r) sk[ct][r] = lrelu(c[r] + bias);
    }
  }
  __syncthreads();
#pragma unroll
  for (int ct = 0; ct < 4; ++ct) {
#pragma unroll
    for (int r = 0; r < 4; ++r)
      H[(16 * w + lg * 4 + r) * 72 + ct * 16 + l15] = (_Float16)sk[ct][r];
  }
  __syncthreads();

  // phase 2: out = skip @ decTop + lT, BN, lrelu
  float fv[4][4];  // [ct][r]
  {
    h8 a0 = uph8(*(const uint4*)(P + arow * 36 + 0 * 16 + lg * 4));
    h8 a1 = uph8(*(const uint4*)(P + arow * 36 + 1 * 16 + lg * 4));
#pragma unroll
    for (int ct = 0; ct < 4; ++ct) {
      h8 b0 = uph8(*(const uint4*)(Ftop + ((ct * 2 + 0) * 64 + lane) * 4));
      h8 b1 = uph8(*(const uint4*)(Ftop + ((ct * 2 + 1) * 64 + lane) * 4));
      f4 c = {0.f, 0.f, 0.f, 0.f};
      c = __builtin_amdgcn_mfma_f32_16x16x32_f16(a0, b0, c, 0, 0, 0);
      c = __builtin_amdgcn_mfma_f32_16x16x32_f16(a1, b1, c, 0, 0, 0);
      int col = ct * 16 + l15;
      float sc = fold[col], sh = fold[64 + col];
#pragma unroll
      for (int r = 0; r < 4; ++r) {
        float ov = (c[r] + lv[r][ct]) * sc + sh;
        fv[ct][r] = lrelu(ov);
        if (grow_[r] < n) inout[(size_t)grow_[r] * 64 + col] = fv[ct][r];
      }
    }
  }

  // phase 3 (optional): lTout = out @ decNextBot + decbN
  if (FnextBot) {
    __syncthreads();
#pragma unroll
    for (int ct = 0; ct < 4; ++ct) {
#pragma unroll
      for (int r = 0; r < 4; ++r)
        H[(16 * w + lg * 4 + r) * 72 + ct * 16 + l15] = (_Float16)fv[ct][r];
    }
    __syncthreads();
    h8 a0 = uph8(*(const uint4*)(P + arow * 36 + 0 * 16 + lg * 4));
    h8 a1 = uph8(*(const uint4*)(P + arow * 36 + 1 * 16 + lg * 4));
#pragma unroll
    for (int ct = 0; ct < 4; ++ct) {
      h8 b0 = uph8(*(const uint4*)(FnextBot + ((ct * 2 + 0) * 64 + lane) * 4));
      h8 b1 = uph8(*(const uint4*)(FnextBot + ((ct * 2 + 1) * 64 + lane) * 4));
      f4 c = {0.f, 0.f, 0.f, 0.f};
      c = __builtin_amdgcn_mfma_f32_16x16x32_f16(a0, b0, c, 0, 0, 0);
      c = __builtin_amdgcn_mfma_f32_16x16x32_f16(a1, b1, c, 0, 0, 0);
      int col = ct * 16 + l15;
      float bias = decbN[col];
#pragma unroll
      for (int r = 0; r < 4; ++r)
        if (grow_[r] < n) lTout[(size_t)grow_[r] * 64 + col] = c[r] + bias;
    }
  }
}

extern "C" void kernel_launch(void* const* d_in, const int* in_sizes, int n_in,
                              void* d_out, int out_size, void* d_ws, size_t ws_size,
                              hipStream_t stream) {
  const float* pt   = (const float*)d_in[0];
  const int* inv2   = (const int*)d_in[1];
  const int* inv4   = (const int*)d_in[2];
  const int* inv8   = (const int*)d_in[3];
  const int* inv16  = (const int*)d_in[4];
  const float* e0W1 = (const float*)d_in[5];
  const float* e0b1 = (const float*)d_in[6];
  const float* e0g  = (const float*)d_in[7];
  const float* e0be = (const float*)d_in[8];
  const float* e0m  = (const float*)d_in[9];
  const float* e0v  = (const float*)d_in[10];
  const float* e0W2 = (const float*)d_in[11];
  const float* e0b2 = (const float*)d_in[12];
  const float* eRW1 = (const float*)d_in[13];
  const float* eRb1 = (const float*)d_in[14];
  const float* eRg  = (const float*)d_in[15];
  const float* eRbe = (const float*)d_in[16];
  const float* eRm  = (const float*)d_in[17];
  const float* eRv  = (const float*)d_in[18];
  const float* eRW2 = (const float*)d_in[19];
  const float* eRb2 = (const float*)d_in[20];
  const float* mlpW = (const float*)d_in[21];
  const float* mlpb = (const float*)d_in[22];
  const float* decW = (const float*)d_in[23];
  const float* decb = (const float*)d_in[24];
  const float* decg = (const float*)d_in[25];
  const float* decbe= (const float*)d_in[26];
  const float* decm = (const float*)d_in[27];
  const float* decv = (const float*)d_in[28];

  float* s1 = (float*)d_out;
  float* s2 = s1 + (size_t)N1 * 64;
  float* s3 = s2 + (size_t)N2 * 64;
  float* s4 = s3 + (size_t)N4 * 64;
  float* s5 = s4 + (size_t)N8 * 64;

  // ws: fold | F_e0W2 | F_eRW1 | F_eRW2 | F_mlp | F_top | F_bot | oA | oB | head | nxt
  float* fold = (float*)d_ws;
  unsigned* F_e0W2 = (unsigned*)(fold + 1024);   // 1024 u
  unsigned* F_eRW1 = F_e0W2 + 1024;              // 4*1024 u
  unsigned* F_eRW2 = F_eRW1 + 4096;              // 4*1024 u
  unsigned* F_mlp  = F_eRW2 + 4096;              // 5*2048 u
  unsigned* F_top  = F_mlp + 10240;              // 5*2048 u
  unsigned* F_bot  = F_top + 10240;              // 5*2048 u
  float* oA   = (float*)(F_bot + 10240);
  float* oB   = oA + (size_t)N2 * 64;
  int* head   = (int*)(oB + (size_t)N4 * 64);
  int* nxt    = head + N2;

  k_fold<<<1, 320, 0, stream>>>(e0g, e0be, e0m, e0v, eRg, eRbe, eRm, eRv,
                                decg, decbe, decm, decv, fold);
  k_packB<<<4, 256, 0, stream>>>(e0W2, F_e0W2, 64, 1, 1024);
  for (int i = 0; i < 4; ++i) {
    k_packB<<<4, 256, 0, stream>>>(eRW1 + i * 2048, F_eRW1 + i * 1024, 32, 2, 1024);
    k_packB<<<4, 256, 0, stream>>>(eRW2 + i * 2048, F_eRW2 + i * 1024, 64, 1, 1024);
  }
  for (int i = 0; i < 5; ++i) {
    k_packB<<<8, 256, 0, stream>>>(mlpW + i * 4096, F_mlp + i * 2048, 64, 2, 2048);
    k_packB<<<8, 256, 0, stream>>>(decW + i * 8192, F_top + i * 2048, 64, 2, 2048);
    k_packB<<<8, 256, 0, stream>>>(decW + i * 8192 + 4096, F_bot + i * 2048, 64, 2, 2048);
  }

  // ---- level 1: enc0 on N1, pool -> oA [N2] ----
  hipMemsetAsync(head, 0xFF, (size_t)N2 * 4, stream);
  k_fill<<<(N1 + 255) / 256, 256, 0, stream>>>(inv2, head, nxt, N1);
  k_enc0_m<<<(N1 + 63) / 64, 256, 0, stream>>>(pt, e0W1, e0b1, fold, F_e0W2, e0b2, s1, N1);
  k_gmax<<<((size_t)N2 * 64 + 255) / 256, 256, 0, stream>>>(s1, head, nxt, oA, N2);

  // ---- level 2: encR[0] on N2, pool -> oB [N4] ----
  hipMemsetAsync(head, 0xFF, (size_t)N4 * 4, stream);
  k_fill<<<(N2 + 255) / 256, 256, 0, stream>>>(inv4, head, nxt, N2);
  k_encR_m<<<(N2 + 63) / 64, 256, 0, stream>>>(oA, F_eRW1 + 0 * 1024, eRb1 + 0 * 32,
                                               fold + 64 + 0 * 64, F_eRW2 + 0 * 1024,
                                               eRb2 + 0 * 64, s2, N2);
  k_gmax<<<((size_t)N4 * 64 + 255) / 256, 256, 0, stream>>>(s2, head, nxt, oB, N4);

  // ---- level 3: encR[1] on N4, pool -> oA [N8] ----
  hipMemsetAsync(head, 0xFF, (size_t)N8 * 4, stream);
  k_fill<<<(N4 + 255) / 256, 256, 0, stream>>>(inv8, head, nxt, N4);
  k_encR_m<<<(N4 + 63) / 64, 256, 0, stream>>>(oB, F_eRW1 + 1 * 1024, eRb1 + 1 * 32,
                                               fold + 64 + 1 * 64, F_eRW2 + 1 * 1024,
                                               eRb2 + 1 * 64, s3, N4);
  k_gmax<<<((size_t)N8 * 64 + 255) / 256, 256, 0, stream>>>(s3, head, nxt, oA, N8);

  // ---- level 4: encR[2] on N8, pool -> oB [N16] ----
  hipMemsetAsync(head, 0xFF, (size_t)N16 * 4, stream);
  k_fill<<<(N8 + 255) / 256, 256, 0, stream>>>(inv16, head, nxt, N8);
  k_encR_m<<<(N8 + 63) / 64, 256, 0, stream>>>(oA, F_eRW1 + 2 * 1024, eRb1 + 2 * 32,
                                               fold + 64 + 2 * 64, F_eRW2 + 2 * 1024,
                                               eRb2 + 2 * 64, s4, N8);
  k_gmax<<<((size_t)N16 * 64 + 255) / 256, 256, 0, stream>>>(s4, head, nxt, oB, N16);

  // ---- level 5: encR[3] on N16 ----
  k_encR_m<<<(N16 + 63) / 64, 256, 0, stream>>>(oB, F_eRW1 + 3 * 1024, eRb1 + 3 * 32,
                                                fold + 64 + 3 * 64, F_eRW2 + 3 * 1024,
                                                eRb2 + 3 * 64, s5, N16);

  // ---- decoders (MFMA) with fused next-level lastT ----
  k_lastT_m<<<(N16 + 63) / 64, 256, 0, stream>>>(s5, F_bot + 0 * 2048, decb + 0 * 64, oA, N16);
  k_dec2_m<<<(N16 + 63) / 64, 256, 0, stream>>>(s5, oA, nullptr, F_mlp + 0 * 2048, mlpb + 0 * 64,
                                                F_top + 0 * 2048, fold + 320 + 0 * 128, N16,
                                                F_bot + 1 * 2048, decb + 1 * 64, oB);
  k_dec2_m<<<(N8 + 63) / 64, 256, 0, stream>>>(s4, oB, inv16, F_mlp + 1 * 2048, mlpb + 1 * 64,
                                               F_top + 1 * 2048, fold + 320 + 1 * 128, N8,
                                               F_bot + 2 * 2048, decb + 2 * 64, oA);
  k_dec2_m<<<(N4 + 63) / 64, 256, 0, stream>>>(s3, oA, inv8, F_mlp + 2 * 2048, mlpb + 2 * 64,
                                               F_top + 2 * 2048, fold + 320 + 2 * 128, N4,
                                               F_bot + 3 * 2048, decb + 3 * 64, oB);
  k_dec2_m<<<(N2 + 63) / 64, 256, 0, stream>>>(s2, oB, inv4, F_mlp + 3 * 2048, mlpb + 3 * 64,
                                               F_top + 3 * 2048, fold + 320 + 3 * 128, N2,
                                               F_bot + 4 * 2048, decb + 4 * 64, oA);
  k_dec2_m<<<(N1 + 63) / 64, 256, 0, stream>>>(s1, oA, inv2, F_mlp + 4 * 2048, mlpb + 4 * 64,
                                               F_top + 4 * 2048, fold + 320 + 4 * 128, N1,
                                               nullptr, nullptr, nullptr);
}

// Round 20
// 720.288 us; speedup vs baseline: 3.4979x; 1.1968x over previous
//
#include <hip/hip_runtime.h>

#define N1 1000000
#define N2 400000
#define N4 150000
#define N8 60000
#define N16 20000

constexpr float BN_EPS = 1e-5f;

typedef _Float16 h2 __attribute__((ext_vector_type(2)));
typedef _Float16 h8 __attribute__((ext_vector_type(8)));
typedef float f4 __attribute__((ext_vector_type(4)));

__device__ __forceinline__ float lrelu(float x) { return fmaxf(x, 0.1f * x); }

__device__ __forceinline__ unsigned pk(float x, float y) {
  h2 h = {(_Float16)x, (_Float16)y};
  unsigned u;
  __builtin_memcpy(&u, &h, 4);
  return u;
}
__device__ __forceinline__ h8 uph8(uint4 u) {
  h8 h;
  __builtin_memcpy(&h, &u, 16);
  return h;
}

// Fold all BatchNorm params into scale/shift once per call.
__global__ void k_fold(const float* g0, const float* be0, const float* m0, const float* v0,
                       const float* gR, const float* beR, const float* mR, const float* vR,
                       const float* gD, const float* beD, const float* mD, const float* vD,
                       float* fold) {
  int t = threadIdx.x;
  if (t < 32) {
    float sc = g0[t] * rsqrtf(v0[t] + BN_EPS);
    fold[t] = sc;
    fold[32 + t] = be0[t] - m0[t] * sc;
  }
  if (t < 128) {
    int b = t >> 5, c = t & 31;
    float sc = gR[b * 32 + c] * rsqrtf(vR[b * 32 + c] + BN_EPS);
    fold[64 + b * 64 + c] = sc;
    fold[64 + b * 64 + 32 + c] = beR[b * 32 + c] - mR[b * 32 + c] * sc;
  }
  for (int i = t; i < 320; i += blockDim.x) {
    int b = i >> 6, c = i & 63;
    float sc = gD[b * 64 + c] * rsqrtf(vD[b * 64 + c] + BN_EPS);
    fold[320 + b * 128 + c] = sc;
    fold[320 + b * 128 + 64 + c] = beD[b * 64 + c] - mD[b * 64 + c] * sc;
  }
}

// Generic MFMA B-fragment pack: W[K][C] (row-major, stride C, K=KT*32) ->
// d[((ct*KT + t)*64 + l)*4 + q] = pk(W[k0][col], W[k0+1][col]).
__global__ __launch_bounds__(256) void k_packB(const float* __restrict__ W,
                                               unsigned* __restrict__ d,
                                               int C, int KT, int total) {
  int i = blockIdx.x * 256 + threadIdx.x;
  if (i >= total) return;
  int q = i & 3, l = (i >> 2) & 63;
  int rest = i >> 8;
  int t = rest % KT, ct = rest / KT;
  int col = ct * 16 + (l & 15);
  int k0 = t * 32 + ((l >> 4) << 3) + 2 * q;
  d[i] = pk(W[k0 * C + col], W[(k0 + 1) * C + col]);
}

// Build per-segment linked lists. head pre-set to -1. One 4B atomic per row.
__global__ __launch_bounds__(256) void k_fill(const int* __restrict__ idx,
                                              int* head, int* nxt, int n) {
  int i = blockIdx.x * 256 + threadIdx.x;
  if (i < n) nxt[i] = atomicExch(&head[idx[i]], i);
}

// Segment max by chained gather (fp16 in/out; max commutes with fp16 cast).
__global__ __launch_bounds__(256) void k_gmax_h(
    const _Float16* __restrict__ src, const int* __restrict__ head,
    const int* __restrict__ nxt, _Float16* __restrict__ dst, int nseg) {
  int t = blockIdx.x * 256 + threadIdx.x;
  int seg = t >> 6, ch = t & 63;
  if (seg >= nseg) return;
  float m = -INFINITY;
  for (int p = head[seg]; p >= 0; p = nxt[p])
    m = fmaxf(m, (float)src[(size_t)p * 64 + ch]);
  dst[(size_t)seg * 64 + ch] = (_Float16)((m == -INFINITY) ? 0.0f : m);
}

// ---------------- MFMA GEMM kernels (fp16 intermediate storage) -------------
// Block = 256 thr (4 waves); tile 64 rows; wave w owns rows 16w..16w+15.
// A: LDS [64 rows][36 u32] (72 halves stride); lane l: row 16w+(l&15),
//    k=(l>>4)*8..+7 -> ds_read_b128 at u32 off row*36 + t16*16 + (l>>4)*4.
// B: fragment-linear packed buffers (k_packB), one dwordx4 per lane.
// D: row = 16w + (l>>4)*4 + reg, col = ct*16 + (l&15)  [verified R18/R19]
// Outputs to fp16 buffers staged via LDS for coalesced u32 writes.

// encoder block 0: x[9] -> h[32] (fp32 K=9) -> outH[64] fp16 (MFMA K=32)
__global__ __launch_bounds__(256) void k_enc0_m(
    const float* __restrict__ x,
    const float* __restrict__ W1, const float* __restrict__ b1,
    const float* __restrict__ fold,
    const unsigned* __restrict__ F2, const float* __restrict__ b2,
    unsigned* __restrict__ outH, int n) {
  __shared__ float xS[64 * 9];
  __shared__ unsigned hP[64 * 20];
  __shared__ _Float16 oH[64 * 72];
  int t = threadIdx.x;
  int lane = t & 63;
  int w = __builtin_amdgcn_readfirstlane(t >> 6);
  int R = blockIdx.x * 64;
  int l15 = lane & 15, lg = lane >> 4;

  {
    size_t lim = (size_t)n * 9 - 1;
    for (int i = t; i < 576; i += 256) {
      size_t gi = (size_t)R * 9 + i;
      if (gi > lim) gi = lim;
      xS[i] = x[gi];
    }
  }
  __syncthreads();

  // phase 1 (fp32): h cols 8w..8w+7 for row=lane; K=9
  {
    const float* W1p = W1 + w * 8;
    float xr[9];
#pragma unroll
    for (int k = 0; k < 9; ++k) xr[k] = xS[lane * 9 + k];
    float acc[8];
#pragma unroll
    for (int c = 0; c < 8; ++c) acc[c] = b1[w * 8 + c];
#pragma unroll
    for (int k = 0; k < 9; ++k) {
#pragma unroll
      for (int c = 0; c < 8; ++c) acc[c] = fmaf(xr[k], W1p[k * 32 + c], acc[c]);
    }
    float v[8];
#pragma unroll
    for (int c = 0; c < 8; ++c)
      v[c] = lrelu(acc[c]) * fold[w * 8 + c] + fold[32 + w * 8 + c];
#pragma unroll
    for (int j = 0; j < 4; ++j)
      hP[lane * 20 + w * 4 + j] = pk(v[2 * j], v[2 * j + 1]);
  }
  __syncthreads();

  // phase 2 (MFMA): out = lrelu(h @ W2 + b2), K=32 -> oH -> coalesced write
  {
    int arow = 16 * w + l15;
    h8 a = uph8(*(const uint4*)(hP + arow * 20 + lg * 4));
#pragma unroll
    for (int ct = 0; ct < 4; ++ct) {
      h8 b = uph8(*(const uint4*)(F2 + (ct * 64 + lane) * 4));
      f4 c = {0.f, 0.f, 0.f, 0.f};
      c = __builtin_amdgcn_mfma_f32_16x16x32_f16(a, b, c, 0, 0, 0);
      int col = ct * 16 + l15;
      float bias = b2[col];
#pragma unroll
      for (int r = 0; r < 4; ++r)
        oH[(16 * w + lg * 4 + r) * 72 + col] = (_Float16)lrelu(c[r] + bias);
    }
  }
  __syncthreads();
  for (int f = t; f < 2048; f += 256) {
    int row = f >> 5, i = f & 31;
    int gr = R + row;
    if (gr < n) outH[(size_t)gr * 32 + i] = ((unsigned*)oH)[row * 36 + i];
  }
}

// encoder blocks 1..4: inH[64] fp16 -> h[32] (MFMA K=64) -> outH[64] fp16
__global__ __launch_bounds__(256) void k_encR_m(
    const unsigned* __restrict__ xinH,
    const unsigned* __restrict__ F1, const float* __restrict__ b1,
    const float* __restrict__ fold,
    const unsigned* __restrict__ F2, const float* __restrict__ b2,
    unsigned* __restrict__ outH, int n) {
  __shared__ unsigned P[64 * 36];
  __shared__ unsigned hP[64 * 20];
  __shared__ _Float16 oH[64 * 72];
  int t = threadIdx.x;
  int lane = t & 63;
  int w = __builtin_amdgcn_readfirstlane(t >> 6);
  int R = blockIdx.x * 64;
  int l15 = lane & 15, lg = lane >> 4;
  _Float16* Hh = (_Float16*)hP;

  for (int f = t; f < 2048; f += 256) {
    int row = f >> 5, i = f & 31;
    int gr = R + row; if (gr >= n) gr = n - 1;
    P[row * 36 + i] = xinH[(size_t)gr * 32 + i];
  }
  __syncthreads();

  int arow = 16 * w + l15;

  // phase 1 (MFMA): h = lrelu(x @ W1 + b1) * sc + sh, K=64
  {
    h8 a0 = uph8(*(const uint4*)(P + arow * 36 + 0 * 16 + lg * 4));
    h8 a1 = uph8(*(const uint4*)(P + arow * 36 + 1 * 16 + lg * 4));
#pragma unroll
    for (int ct = 0; ct < 2; ++ct) {
      h8 b0 = uph8(*(const uint4*)(F1 + ((ct * 2 + 0) * 64 + lane) * 4));
      h8 b1v = uph8(*(const uint4*)(F1 + ((ct * 2 + 1) * 64 + lane) * 4));
      f4 c = {0.f, 0.f, 0.f, 0.f};
      c = __builtin_amdgcn_mfma_f32_16x16x32_f16(a0, b0, c, 0, 0, 0);
      c = __builtin_amdgcn_mfma_f32_16x16x32_f16(a1, b1v, c, 0, 0, 0);
      int col = ct * 16 + l15;
      float bias = b1[col], sc = fold[col], sh = fold[32 + col];
#pragma unroll
      for (int r = 0; r < 4; ++r) {
        int row = 16 * w + lg * 4 + r;
        Hh[row * 40 + col] = (_Float16)(lrelu(c[r] + bias) * sc + sh);
      }
    }
  }
  __syncthreads();

  // phase 2 (MFMA): out = lrelu(h @ W2 + b2), K=32 -> oH -> coalesced write
  {
    h8 a = uph8(*(const uint4*)(hP + arow * 20 + lg * 4));
#pragma unroll
    for (int ct = 0; ct < 4; ++ct) {
      h8 b = uph8(*(const uint4*)(F2 + (ct * 64 + lane) * 4));
      f4 c = {0.f, 0.f, 0.f, 0.f};
      c = __builtin_amdgcn_mfma_f32_16x16x32_f16(a, b, c, 0, 0, 0);
      int col = ct * 16 + l15;
      float bias = b2[col];
#pragma unroll
      for (int r = 0; r < 4; ++r)
        oH[(16 * w + lg * 4 + r) * 72 + col] = (_Float16)lrelu(c[r] + bias);
    }
  }
  __syncthreads();
  for (int f = t; f < 2048; f += 256) {
    int row = f >> 5, i = f & 31;
    int gr = R + row;
    if (gr < n) outH[(size_t)gr * 32 + i] = ((unsigned*)oH)[row * 36 + i];
  }
}

// lastT = srcH @ decW_bot + decb  (seed, MFMA K=64, fp32 out)
__global__ __launch_bounds__(256) void k_lastT_m(
    const unsigned* __restrict__ srcH, const unsigned* __restrict__ Fbot,
    const float* __restrict__ decb, float* __restrict__ lT, int n) {
  __shared__ unsigned P[64 * 36];
  int t = threadIdx.x;
  int lane = t & 63;
  int w = __builtin_amdgcn_readfirstlane(t >> 6);
  int R = blockIdx.x * 64;
  int l15 = lane & 15, lg = lane >> 4;

  for (int f = t; f < 2048; f += 256) {
    int row = f >> 5, i = f & 31;
    int gr = R + row; if (gr >= n) gr = n - 1;
    P[row * 36 + i] = srcH[(size_t)gr * 32 + i];
  }
  __syncthreads();

  int arow = 16 * w + l15;
  h8 a0 = uph8(*(const uint4*)(P + arow * 36 + 0 * 16 + lg * 4));
  h8 a1 = uph8(*(const uint4*)(P + arow * 36 + 1 * 16 + lg * 4));

#pragma unroll
  for (int ct = 0; ct < 4; ++ct) {
    h8 b0 = uph8(*(const uint4*)(Fbot + ((ct * 2 + 0) * 64 + lane) * 4));
    h8 b1 = uph8(*(const uint4*)(Fbot + ((ct * 2 + 1) * 64 + lane) * 4));
    f4 c = {0.f, 0.f, 0.f, 0.f};
    c = __builtin_amdgcn_mfma_f32_16x16x32_f16(a0, b0, c, 0, 0, 0);
    c = __builtin_amdgcn_mfma_f32_16x16x32_f16(a1, b1, c, 0, 0, 0);
    int col = ct * 16 + l15;
    float bias = decb[col];
#pragma unroll
    for (int r = 0; r < 4; ++r) {
      int grow = R + 16 * w + lg * 4 + r;
      if (grow < n) lT[(size_t)grow * 64 + col] = c[r] + bias;
    }
  }
}

// decoder: outF = lrelu(BN(lrelu(curH@mlp) @ decTop + lT[lrow])) (fp32 final);
// optional phase 3: lTout = outF @ decNextBot + decbN.
__global__ __launch_bounds__(256) void k_dec2_m(
    const unsigned* __restrict__ curH, float* __restrict__ outF,
    const float* __restrict__ lT, const int* __restrict__ idx,
    const unsigned* __restrict__ Fmlp, const float* __restrict__ mlpb,
    const unsigned* __restrict__ Ftop, const float* __restrict__ fold, int n,
    const unsigned* __restrict__ FnextBot, const float* __restrict__ decbN,
    float* __restrict__ lTout) {
  __shared__ unsigned P[64 * 36];
  int t = threadIdx.x;
  int lane = t & 63;
  int w = __builtin_amdgcn_readfirstlane(t >> 6);
  int R = blockIdx.x * 64;
  int l15 = lane & 15, lg = lane >> 4;
  _Float16* H = (_Float16*)P;

  for (int f = t; f < 2048; f += 256) {
    int row = f >> 5, i = f & 31;
    int gr = R + row; if (gr >= n) gr = n - 1;
    P[row * 36 + i] = curH[(size_t)gr * 32 + i];
  }

  int grow_[4], gidx_[4];
#pragma unroll
  for (int r = 0; r < 4; ++r) {
    grow_[r] = R + 16 * w + lg * 4 + r;
    int gcl = grow_[r] >= n ? n - 1 : grow_[r];
    gidx_[r] = idx ? idx[gcl] : gcl;
  }
  float lv[4][4];  // [r][ct]
#pragma unroll
  for (int r = 0; r < 4; ++r) {
#pragma unroll
    for (int ct = 0; ct < 4; ++ct)
      lv[r][ct] = lT[(size_t)gidx_[r] * 64 + ct * 16 + l15];
  }
  __syncthreads();

  int arow = 16 * w + l15;

  // phase 1: skip = lrelu(cur @ mlpW + mlpb)
  float sk[4][4];  // [ct][r]
  {
    h8 a0 = uph8(*(const uint4*)(P + arow * 36 + 0 * 16 + lg * 4));
    h8 a1 = uph8(*(const uint4*)(P + arow * 36 + 1 * 16 + lg * 4));
#pragma unroll
    for (int ct = 0; ct < 4; ++ct) {
      h8 b0 = uph8(*(const uint4*)(Fmlp + ((ct * 2 + 0) * 64 + lane) * 4));
      h8 b1 = uph8(*(const uint4*)(Fmlp + ((ct * 2 + 1) * 64 + lane) * 4));
      f4 c = {0.f, 0.f, 0.f, 0.f};
      c = __builtin_amdgcn_mfma_f32_16x16x32_f16(a0, b0, c, 0, 0, 0);
      c = __builtin_amdgcn_mfma_f32_16x16x32_f16(a1, b1, c, 0, 0, 0);
      float bias = mlpb[ct * 16 + l15];
#pragma unroll
      for (int r = 0; r < 4; ++r) sk[ct][r] = lrelu(c[r] + bias);
    }
  }
  __syncthreads();
#pragma unroll
  for (int ct = 0; ct < 4; ++ct) {
#pragma unroll
    for (int r = 0; r < 4; ++r)
      H[(16 * w + lg * 4 + r) * 72 + ct * 16 + l15] = (_Float16)sk[ct][r];
  }
  __syncthreads();

  // phase 2: out = skip @ decTop + lT, BN, lrelu -> fp32 final
  float fv[4][4];  // [ct][r]
  {
    h8 a0 = uph8(*(const uint4*)(P + arow * 36 + 0 * 16 + lg * 4));
    h8 a1 = uph8(*(const uint4*)(P + arow * 36 + 1 * 16 + lg * 4));
#pragma unroll
    for (int ct = 0; ct < 4; ++ct) {
      h8 b0 = uph8(*(const uint4*)(Ftop + ((ct * 2 + 0) * 64 + lane) * 4));
      h8 b1 = uph8(*(const uint4*)(Ftop + ((ct * 2 + 1) * 64 + lane) * 4));
      f4 c = {0.f, 0.f, 0.f, 0.f};
      c = __builtin_amdgcn_mfma_f32_16x16x32_f16(a0, b0, c, 0, 0, 0);
      c = __builtin_amdgcn_mfma_f32_16x16x32_f16(a1, b1, c, 0, 0, 0);
      int col = ct * 16 + l15;
      float sc = fold[col], sh = fold[64 + col];
#pragma unroll
      for (int r = 0; r < 4; ++r) {
        float ov = (c[r] + lv[r][ct]) * sc + sh;
        fv[ct][r] = lrelu(ov);
        if (grow_[r] < n) outF[(size_t)grow_[r] * 64 + col] = fv[ct][r];
      }
    }
  }

  // phase 3 (optional): lTout = out @ decNextBot + decbN
  if (FnextBot) {
    __syncthreads();
#pragma unroll
    for (int ct = 0; ct < 4; ++ct) {
#pragma unroll
      for (int r = 0; r < 4; ++r)
        H[(16 * w + lg * 4 + r) * 72 + ct * 16 + l15] = (_Float16)fv[ct][r];
    }
    __syncthreads();
    h8 a0 = uph8(*(const uint4*)(P + arow * 36 + 0 * 16 + lg * 4));
    h8 a1 = uph8(*(const uint4*)(P + arow * 36 + 1 * 16 + lg * 4));
#pragma unroll
    for (int ct = 0; ct < 4; ++ct) {
      h8 b0 = uph8(*(const uint4*)(FnextBot + ((ct * 2 + 0) * 64 + lane) * 4));
      h8 b1 = uph8(*(const uint4*)(FnextBot + ((ct * 2 + 1) * 64 + lane) * 4));
      f4 c = {0.f, 0.f, 0.f, 0.f};
      c = __builtin_amdgcn_mfma_f32_16x16x32_f16(a0, b0, c, 0, 0, 0);
      c = __builtin_amdgcn_mfma_f32_16x16x32_f16(a1, b1, c, 0, 0, 0);
      int col = ct * 16 + l15;
      float bias = decbN[col];
#pragma unroll
      for (int r = 0; r < 4; ++r)
        if (grow_[r] < n) lTout[(size_t)grow_[r] * 64 + col] = c[r] + bias;
    }
  }
}

extern "C" void kernel_launch(void* const* d_in, const int* in_sizes, int n_in,
                              void* d_out, int out_size, void* d_ws, size_t ws_size,
                              hipStream_t stream) {
  const float* pt   = (const float*)d_in[0];
  const int* inv2   = (const int*)d_in[1];
  const int* inv4   = (const int*)d_in[2];
  const int* inv8   = (const int*)d_in[3];
  const int* inv16  = (const int*)d_in[4];
  const float* e0W1 = (const float*)d_in[5];
  const float* e0b1 = (const float*)d_in[6];
  const float* e0g  = (const float*)d_in[7];
  const float* e0be = (const float*)d_in[8];
  const float* e0m  = (const float*)d_in[9];
  const float* e0v  = (const float*)d_in[10];
  const float* e0W2 = (const float*)d_in[11];
  const float* e0b2 = (const float*)d_in[12];
  const float* eRW1 = (const float*)d_in[13];
  const float* eRb1 = (const float*)d_in[14];
  const float* eRg  = (const float*)d_in[15];
  const float* eRbe = (const float*)d_in[16];
  const float* eRm  = (const float*)d_in[17];
  const float* eRv  = (const float*)d_in[18];
  const float* eRW2 = (const float*)d_in[19];
  const float* eRb2 = (const float*)d_in[20];
  const float* mlpW = (const float*)d_in[21];
  const float* mlpb = (const float*)d_in[22];
  const float* decW = (const float*)d_in[23];
  const float* decb = (const float*)d_in[24];
  const float* decg = (const float*)d_in[25];
  const float* decbe= (const float*)d_in[26];
  const float* decm = (const float*)d_in[27];
  const float* decv = (const float*)d_in[28];

  float* s1 = (float*)d_out;
  float* s2 = s1 + (size_t)N1 * 64;
  float* s3 = s2 + (size_t)N2 * 64;
  float* s4 = s3 + (size_t)N4 * 64;
  float* s5 = s4 + (size_t)N8 * 64;

  // ws: fold | frag packs | pH1..pH5 (fp16 u32) | oAh | oBh | lTA | lTB | head | nxt
  float* fold = (float*)d_ws;
  unsigned* F_e0W2 = (unsigned*)(fold + 1024);   // 1024 u
  unsigned* F_eRW1 = F_e0W2 + 1024;              // 4096 u
  unsigned* F_eRW2 = F_eRW1 + 4096;              // 4096 u
  unsigned* F_mlp  = F_eRW2 + 4096;              // 10240 u
  unsigned* F_top  = F_mlp + 10240;              // 10240 u
  unsigned* F_bot  = F_top + 10240;              // 10240 u
  unsigned* pH1 = F_bot + 10240;                 // N1*32 u
  unsigned* pH2 = pH1 + (size_t)N1 * 32;         // N2*32 u
  unsigned* pH3 = pH2 + (size_t)N2 * 32;         // N4*32 u
  unsigned* pH4 = pH3 + (size_t)N4 * 32;         // N8*32 u
  unsigned* pH5 = pH4 + (size_t)N8 * 32;         // N16*32 u
  unsigned* oAh = pH5 + (size_t)N16 * 32;        // N2*32 u
  unsigned* oBh = oAh + (size_t)N2 * 32;         // N4*32 u
  float* lTA = (float*)(oBh + (size_t)N4 * 32);  // N2*64 f
  float* lTB = lTA + (size_t)N2 * 64;            // N4*64 f
  int* head  = (int*)(lTB + (size_t)N4 * 64);    // N2 i
  int* nxt   = head + N2;                        // N1 i

  k_fold<<<1, 320, 0, stream>>>(e0g, e0be, e0m, e0v, eRg, eRbe, eRm, eRv,
                                decg, decbe, decm, decv, fold);
  k_packB<<<4, 256, 0, stream>>>(e0W2, F_e0W2, 64, 1, 1024);
  for (int i = 0; i < 4; ++i) {
    k_packB<<<4, 256, 0, stream>>>(eRW1 + i * 2048, F_eRW1 + i * 1024, 32, 2, 1024);
    k_packB<<<4, 256, 0, stream>>>(eRW2 + i * 2048, F_eRW2 + i * 1024, 64, 1, 1024);
  }
  for (int i = 0; i < 5; ++i) {
    k_packB<<<8, 256, 0, stream>>>(mlpW + i * 4096, F_mlp + i * 2048, 64, 2, 2048);
    k_packB<<<8, 256, 0, stream>>>(decW + i * 8192, F_top + i * 2048, 64, 2, 2048);
    k_packB<<<8, 256, 0, stream>>>(decW + i * 8192 + 4096, F_bot + i * 2048, 64, 2, 2048);
  }

  // ---- level 1: enc0 on N1 -> pH1, pool -> oAh [N2] ----
  hipMemsetAsync(head, 0xFF, (size_t)N2 * 4, stream);
  k_fill<<<(N1 + 255) / 256, 256, 0, stream>>>(inv2, head, nxt, N1);
  k_enc0_m<<<(N1 + 63) / 64, 256, 0, stream>>>(pt, e0W1, e0b1, fold, F_e0W2, e0b2, pH1, N1);
  k_gmax_h<<<((size_t)N2 * 64 + 255) / 256, 256, 0, stream>>>(
      (const _Float16*)pH1, head, nxt, (_Float16*)oAh, N2);

  // ---- level 2: encR[0] on N2 -> pH2, pool -> oBh [N4] ----
  hipMemsetAsync(head, 0xFF, (size_t)N4 * 4, stream);
  k_fill<<<(N2 + 255) / 256, 256, 0, stream>>>(inv4, head, nxt, N2);
  k_encR_m<<<(N2 + 63) / 64, 256, 0, stream>>>(oAh, F_eRW1 + 0 * 1024, eRb1 + 0 * 32,
                                               fold + 64 + 0 * 64, F_eRW2 + 0 * 1024,
                                               eRb2 + 0 * 64, pH2, N2);
  k_gmax_h<<<((size_t)N4 * 64 + 255) / 256, 256, 0, stream>>>(
      (const _Float16*)pH2, head, nxt, (_Float16*)oBh, N4);

  // ---- level 3: encR[1] on N4 -> pH3, pool -> oAh [N8] ----
  hipMemsetAsync(head, 0xFF, (size_t)N8 * 4, stream);
  k_fill<<<(N4 + 255) / 256, 256, 0, stream>>>(inv8, head, nxt, N4);
  k_encR_m<<<(N4 + 63) / 64, 256, 0, stream>>>(oBh, F_eRW1 + 1 * 1024, eRb1 + 1 * 32,
                                               fold + 64 + 1 * 64, F_eRW2 + 1 * 1024,
                                               eRb2 + 1 * 64, pH3, N4);
  k_gmax_h<<<((size_t)N8 * 64 + 255) / 256, 256, 0, stream>>>(
      (const _Float16*)pH3, head, nxt, (_Float16*)oAh, N8);

  // ---- level 4: encR[2] on N8 -> pH4, pool -> oBh [N16] ----
  hipMemsetAsync(head, 0xFF, (size_t)N16 * 4, stream);
  k_fill<<<(N8 + 255) / 256, 256, 0, stream>>>(inv16, head, nxt, N8);
  k_encR_m<<<(N8 + 63) / 64, 256, 0, stream>>>(oAh, F_eRW1 + 2 * 1024, eRb1 + 2 * 32,
                                               fold + 64 + 2 * 64, F_eRW2 + 2 * 1024,
                                               eRb2 + 2 * 64, pH4, N8);
  k_gmax_h<<<((size_t)N16 * 64 + 255) / 256, 256, 0, stream>>>(
      (const _Float16*)pH4, head, nxt, (_Float16*)oBh, N16);

  // ---- level 5: encR[3] on N16 -> pH5 ----
  k_encR_m<<<(N16 + 63) / 64, 256, 0, stream>>>(oBh, F_eRW1 + 3 * 1024, eRb1 + 3 * 32,
                                                fold + 64 + 3 * 64, F_eRW2 + 3 * 1024,
                                                eRb2 + 3 * 64, pH5, N16);

  // ---- decoders (MFMA, fp16 in / fp32 out) with fused next-level lastT ----
  k_lastT_m<<<(N16 + 63) / 64, 256, 0, stream>>>(pH5, F_bot + 0 * 2048, decb + 0 * 64,
                                                 lTA, N16);
  k_dec2_m<<<(N16 + 63) / 64, 256, 0, stream>>>(pH5, s5, lTA, nullptr,
                                                F_mlp + 0 * 2048, mlpb + 0 * 64,
                                                F_top + 0 * 2048, fold + 320 + 0 * 128, N16,
                                                F_bot + 1 * 2048, decb + 1 * 64, lTB);
  k_dec2_m<<<(N8 + 63) / 64, 256, 0, stream>>>(pH4, s4, lTB, inv16,
                                               F_mlp + 1 * 2048, mlpb + 1 * 64,
                                               F_top + 1 * 2048, fold + 320 + 1 * 128, N8,
                                               F_bot + 2 * 2048, decb + 2 * 64, lTA);
  k_dec2_m<<<(N4 + 63) / 64, 256, 0, stream>>>(pH3, s3, lTA, inv8,
                                               F_mlp + 2 * 2048, mlpb + 2 * 64,
                                               F_top + 2 * 2048, fold + 320 + 2 * 128, N4,
                                               F_bot + 3 * 2048, decb + 3 * 64, lTB);
  k_dec2_m<<<(N2 + 63) / 64, 256, 0, stream>>>(pH2, s2, lTB, inv4,
                                               F_mlp + 3 * 2048, mlpb + 3 * 64,
                                               F_top + 3 * 2048, fold + 320 + 3 * 128, N2,
                                               F_bot + 4 * 2048, decb + 4 * 64, lTA);
  k_dec2_m<<<(N1 + 63) / 64, 256, 0, stream>>>(pH1, s1, lTA, inv2,
                                               F_mlp + 4 * 2048, mlpb + 4 * 64,
                                               F_top + 4 * 2048, fold + 320 + 4 * 128, N1,
                                               nullptr, nullptr, nullptr);
}

// Round 21
// 634.095 us; speedup vs baseline: 3.9734x; 1.1359x over previous
//
#include <hip/hip_runtime.h>

#define N1 1000000
#define N2 400000
#define N4 150000
#define N8 60000
#define N16 20000

constexpr float BN_EPS = 1e-5f;

typedef _Float16 h2 __attribute__((ext_vector_type(2)));
typedef _Float16 h8 __attribute__((ext_vector_type(8)));
typedef float f4 __attribute__((ext_vector_type(4)));

__device__ __forceinline__ float lrelu(float x) { return fmaxf(x, 0.1f * x); }

__device__ __forceinline__ unsigned pk(float x, float y) {
  h2 h = {(_Float16)x, (_Float16)y};
  unsigned u;
  __builtin_memcpy(&u, &h, 4);
  return u;
}
__device__ __forceinline__ h2 uph(unsigned u) {
  h2 h;
  __builtin_memcpy(&h, &u, 4);
  return h;
}
__device__ __forceinline__ h8 uph8(uint4 u) {
  h8 h;
  __builtin_memcpy(&h, &u, 16);
  return h;
}

// Fold all BatchNorm params into scale/shift once per call.
__global__ void k_fold(const float* g0, const float* be0, const float* m0, const float* v0,
                       const float* gR, const float* beR, const float* mR, const float* vR,
                       const float* gD, const float* beD, const float* mD, const float* vD,
                       float* fold) {
  int t = threadIdx.x;
  if (t < 32) {
    float sc = g0[t] * rsqrtf(v0[t] + BN_EPS);
    fold[t] = sc;
    fold[32 + t] = be0[t] - m0[t] * sc;
  }
  if (t < 128) {
    int b = t >> 5, c = t & 31;
    float sc = gR[b * 32 + c] * rsqrtf(vR[b * 32 + c] + BN_EPS);
    fold[64 + b * 64 + c] = sc;
    fold[64 + b * 64 + 32 + c] = beR[b * 32 + c] - mR[b * 32 + c] * sc;
  }
  for (int i = t; i < 320; i += blockDim.x) {
    int b = i >> 6, c = i & 63;
    float sc = gD[b * 64 + c] * rsqrtf(vD[b * 64 + c] + BN_EPS);
    fold[320 + b * 128 + c] = sc;
    fold[320 + b * 128 + 64 + c] = beD[b * 64 + c] - mD[b * 64 + c] * sc;
  }
}

// Generic MFMA B-fragment pack: W[K][C] (row-major, stride C, K=KT*32) ->
// d[((ct*KT + t)*64 + l)*4 + q] = pk(W[k0][col], W[k0+1][col]).
__global__ __launch_bounds__(256) void k_packB(const float* __restrict__ W,
                                               unsigned* __restrict__ d,
                                               int C, int KT, int total) {
  int i = blockIdx.x * 256 + threadIdx.x;
  if (i >= total) return;
  int q = i & 3, l = (i >> 2) & 63;
  int rest = i >> 8;
  int t = rest % KT, ct = rest / KT;
  int col = ct * 16 + (l & 15);
  int k0 = t * 32 + ((l >> 4) << 3) + 2 * q;
  d[i] = pk(W[k0 * C + col], W[(k0 + 1) * C + col]);
}

// Build per-segment linked lists. head pre-set to -1. One 4B atomic per row.
__global__ __launch_bounds__(256) void k_fill(const int* __restrict__ idx,
                                              int* head, int* nxt, int n) {
  int i = blockIdx.x * 256 + threadIdx.x;
  if (i < n) nxt[i] = atomicExch(&head[idx[i]], i);
}

// ---------------- MFMA GEMM kernels (fp16 intermediate storage) -------------
// Block = 256 thr (4 waves); tile 64 rows; wave w owns rows 16w..16w+15.
// A: LDS [64 rows][36 u32] (72 halves stride); lane l: row 16w+(l&15),
//    k=(l>>4)*8..+7 -> ds_read_b128 at u32 off row*36 + t16*16 + (l>>4)*4.
// B: fragment-linear packed buffers (k_packB), one dwordx4 per lane.
// D: row = 16w + (l>>4)*4 + reg, col = ct*16 + (l&15)  [verified R18/R19]

// encoder block 0: x[9] -> h[32] (fp32 K=9) -> outH[64] fp16 (MFMA K=32)
__global__ __launch_bounds__(256) void k_enc0_m(
    const float* __restrict__ x,
    const float* __restrict__ W1, const float* __restrict__ b1,
    const float* __restrict__ fold,
    const unsigned* __restrict__ F2, const float* __restrict__ b2,
    unsigned* __restrict__ outH, int n) {
  __shared__ float xS[64 * 9];
  __shared__ unsigned hP[64 * 20];
  __shared__ _Float16 oH[64 * 72];
  int t = threadIdx.x;
  int lane = t & 63;
  int w = __builtin_amdgcn_readfirstlane(t >> 6);
  int R = blockIdx.x * 64;
  int l15 = lane & 15, lg = lane >> 4;

  {
    size_t lim = (size_t)n * 9 - 1;
    for (int i = t; i < 576; i += 256) {
      size_t gi = (size_t)R * 9 + i;
      if (gi > lim) gi = lim;
      xS[i] = x[gi];
    }
  }
  __syncthreads();

  // phase 1 (fp32): h cols 8w..8w+7 for row=lane; K=9
  {
    const float* W1p = W1 + w * 8;
    float xr[9];
#pragma unroll
    for (int k = 0; k < 9; ++k) xr[k] = xS[lane * 9 + k];
    float acc[8];
#pragma unroll
    for (int c = 0; c < 8; ++c) acc[c] = b1[w * 8 + c];
#pragma unroll
    for (int k = 0; k < 9; ++k) {
#pragma unroll
      for (int c = 0; c < 8; ++c) acc[c] = fmaf(xr[k], W1p[k * 32 + c], acc[c]);
    }
    float v[8];
#pragma unroll
    for (int c = 0; c < 8; ++c)
      v[c] = lrelu(acc[c]) * fold[w * 8 + c] + fold[32 + w * 8 + c];
#pragma unroll
    for (int j = 0; j < 4; ++j)
      hP[lane * 20 + w * 4 + j] = pk(v[2 * j], v[2 * j + 1]);
  }
  __syncthreads();

  // phase 2 (MFMA): out = lrelu(h @ W2 + b2), K=32 -> oH -> coalesced write
  {
    int arow = 16 * w + l15;
    h8 a = uph8(*(const uint4*)(hP + arow * 20 + lg * 4));
#pragma unroll
    for (int ct = 0; ct < 4; ++ct) {
      h8 b = uph8(*(const uint4*)(F2 + (ct * 64 + lane) * 4));
      f4 c = {0.f, 0.f, 0.f, 0.f};
      c = __builtin_amdgcn_mfma_f32_16x16x32_f16(a, b, c, 0, 0, 0);
      int col = ct * 16 + l15;
      float bias = b2[col];
#pragma unroll
      for (int r = 0; r < 4; ++r)
        oH[(16 * w + lg * 4 + r) * 72 + col] = (_Float16)lrelu(c[r] + bias);
    }
  }
  __syncthreads();
  for (int f = t; f < 2048; f += 256) {
    int row = f >> 5, i = f & 31;
    int gr = R + row;
    if (gr < n) outH[(size_t)gr * 32 + i] = ((unsigned*)oH)[row * 36 + i];
  }
}

// encoder blocks 1..4 WITH FUSED SEGMENT-MAX POOLING:
// stages row `seg` by chain-walking max over srcH rows (fp16 pairs; max
// commutes with fp16 cast), then h[32] (MFMA K=64) -> outH[64] fp16.
__global__ __launch_bounds__(256) void k_encR_m(
    const unsigned* __restrict__ srcH, const int* __restrict__ head,
    const int* __restrict__ nxt,
    const unsigned* __restrict__ F1, const float* __restrict__ b1,
    const float* __restrict__ fold,
    const unsigned* __restrict__ F2, const float* __restrict__ b2,
    unsigned* __restrict__ outH, int n) {
  __shared__ unsigned P[64 * 36];
  __shared__ unsigned hP[64 * 20];
  __shared__ _Float16 oH[64 * 72];
  int t = threadIdx.x;
  int lane = t & 63;
  int w = __builtin_amdgcn_readfirstlane(t >> 6);
  int R = blockIdx.x * 64;
  int l15 = lane & 15, lg = lane >> 4;
  _Float16* Hh = (_Float16*)hP;

  // fused pooling stage: 32 u32-pairs per segment-row
  for (int f = t; f < 2048; f += 256) {
    int row = f >> 5, i = f & 31;
    int seg = R + row;
    unsigned ov = 0u;  // pk(0,0)
    if (seg < n) {
      float m0 = -INFINITY, m1 = -INFINITY;
      for (int p = head[seg]; p >= 0; p = nxt[p]) {
        h2 v = uph(srcH[(size_t)p * 32 + i]);
        m0 = fmaxf(m0, (float)v.x);
        m1 = fmaxf(m1, (float)v.y);
      }
      if (m0 == -INFINITY) m0 = 0.0f;
      if (m1 == -INFINITY) m1 = 0.0f;
      ov = pk(m0, m1);
    }
    P[row * 36 + i] = ov;
  }
  __syncthreads();

  int arow = 16 * w + l15;

  // phase 1 (MFMA): h = lrelu(x @ W1 + b1) * sc + sh, K=64
  {
    h8 a0 = uph8(*(const uint4*)(P + arow * 36 + 0 * 16 + lg * 4));
    h8 a1 = uph8(*(const uint4*)(P + arow * 36 + 1 * 16 + lg * 4));
#pragma unroll
    for (int ct = 0; ct < 2; ++ct) {
      h8 b0 = uph8(*(const uint4*)(F1 + ((ct * 2 + 0) * 64 + lane) * 4));
      h8 b1v = uph8(*(const uint4*)(F1 + ((ct * 2 + 1) * 64 + lane) * 4));
      f4 c = {0.f, 0.f, 0.f, 0.f};
      c = __builtin_amdgcn_mfma_f32_16x16x32_f16(a0, b0, c, 0, 0, 0);
      c = __builtin_amdgcn_mfma_f32_16x16x32_f16(a1, b1v, c, 0, 0, 0);
      int col = ct * 16 + l15;
      float bias = b1[col], sc = fold[col], sh = fold[32 + col];
#pragma unroll
      for (int r = 0; r < 4; ++r) {
        int row = 16 * w + lg * 4 + r;
        Hh[row * 40 + col] = (_Float16)(lrelu(c[r] + bias) * sc + sh);
      }
    }
  }
  __syncthreads();

  // phase 2 (MFMA): out = lrelu(h @ W2 + b2), K=32 -> oH -> coalesced write
  {
    h8 a = uph8(*(const uint4*)(hP + arow * 20 + lg * 4));
#pragma unroll
    for (int ct = 0; ct < 4; ++ct) {
      h8 b = uph8(*(const uint4*)(F2 + (ct * 64 + lane) * 4));
      f4 c = {0.f, 0.f, 0.f, 0.f};
      c = __builtin_amdgcn_mfma_f32_16x16x32_f16(a, b, c, 0, 0, 0);
      int col = ct * 16 + l15;
      float bias = b2[col];
#pragma unroll
      for (int r = 0; r < 4; ++r)
        oH[(16 * w + lg * 4 + r) * 72 + col] = (_Float16)lrelu(c[r] + bias);
    }
  }
  __syncthreads();
  for (int f = t; f < 2048; f += 256) {
    int row = f >> 5, i = f & 31;
    int gr = R + row;
    if (gr < n) outH[(size_t)gr * 32 + i] = ((unsigned*)oH)[row * 36 + i];
  }
}

// lastT = srcH @ decW_bot + decb  (seed, MFMA K=64, fp16 out)
__global__ __launch_bounds__(256) void k_lastT_m(
    const unsigned* __restrict__ srcH, const unsigned* __restrict__ Fbot,
    const float* __restrict__ decb, _Float16* __restrict__ lT, int n) {
  __shared__ unsigned P[64 * 36];
  int t = threadIdx.x;
  int lane = t & 63;
  int w = __builtin_amdgcn_readfirstlane(t >> 6);
  int R = blockIdx.x * 64;
  int l15 = lane & 15, lg = lane >> 4;

  for (int f = t; f < 2048; f += 256) {
    int row = f >> 5, i = f & 31;
    int gr = R + row; if (gr >= n) gr = n - 1;
    P[row * 36 + i] = srcH[(size_t)gr * 32 + i];
  }
  __syncthreads();

  int arow = 16 * w + l15;
  h8 a0 = uph8(*(const uint4*)(P + arow * 36 + 0 * 16 + lg * 4));
  h8 a1 = uph8(*(const uint4*)(P + arow * 36 + 1 * 16 + lg * 4));

#pragma unroll
  for (int ct = 0; ct < 4; ++ct) {
    h8 b0 = uph8(*(const uint4*)(Fbot + ((ct * 2 + 0) * 64 + lane) * 4));
    h8 b1 = uph8(*(const uint4*)(Fbot + ((ct * 2 + 1) * 64 + lane) * 4));
    f4 c = {0.f, 0.f, 0.f, 0.f};
    c = __builtin_amdgcn_mfma_f32_16x16x32_f16(a0, b0, c, 0, 0, 0);
    c = __builtin_amdgcn_mfma_f32_16x16x32_f16(a1, b1, c, 0, 0, 0);
    int col = ct * 16 + l15;
    float bias = decb[col];
#pragma unroll
    for (int r = 0; r < 4; ++r) {
      int grow = R + 16 * w + lg * 4 + r;
      if (grow < n) lT[(size_t)grow * 64 + col] = (_Float16)(c[r] + bias);
    }
  }
}

// decoder: outF = lrelu(BN(lrelu(curH@mlp) @ decTop + lT[lrow])) (fp32 final);
// optional phase 3: lTout = outF @ decNextBot + decbN (fp16).
__global__ __launch_bounds__(256) void k_dec2_m(
    const unsigned* __restrict__ curH, float* __restrict__ outF,
    const _Float16* __restrict__ lT, const int* __restrict__ idx,
    const unsigned* __restrict__ Fmlp, const float* __restrict__ mlpb,
    const unsigned* __restrict__ Ftop, const float* __restrict__ fold, int n,
    const unsigned* __restrict__ FnextBot, const float* __restrict__ decbN,
    _Float16* __restrict__ lTout) {
  __shared__ unsigned P[64 * 36];
  int t = threadIdx.x;
  int lane = t & 63;
  int w = __builtin_amdgcn_readfirstlane(t >> 6);
  int R = blockIdx.x * 64;
  int l15 = lane & 15, lg = lane >> 4;
  _Float16* H = (_Float16*)P;

  for (int f = t; f < 2048; f += 256) {
    int row = f >> 5, i = f & 31;
    int gr = R + row; if (gr >= n) gr = n - 1;
    P[row * 36 + i] = curH[(size_t)gr * 32 + i];
  }

  int grow_[4], gidx_[4];
#pragma unroll
  for (int r = 0; r < 4; ++r) {
    grow_[r] = R + 16 * w + lg * 4 + r;
    int gcl = grow_[r] >= n ? n - 1 : grow_[r];
    gidx_[r] = idx ? idx[gcl] : gcl;
  }
  float lv[4][4];  // [r][ct]
#pragma unroll
  for (int r = 0; r < 4; ++r) {
#pragma unroll
    for (int ct = 0; ct < 4; ++ct)
      lv[r][ct] = (float)lT[(size_t)gidx_[r] * 64 + ct * 16 + l15];
  }
  __syncthreads();

  int arow = 16 * w + l15;

  // phase 1: skip = lrelu(cur @ mlpW + mlpb)
  float sk[4][4];  // [ct][r]
  {
    h8 a0 = uph8(*(const uint4*)(P + arow * 36 + 0 * 16 + lg * 4));
    h8 a1 = uph8(*(const uint4*)(P + arow * 36 + 1 * 16 + lg * 4));
#pragma unroll
    for (int ct = 0; ct < 4; ++ct) {
      h8 b0 = uph8(*(const uint4*)(Fmlp + ((ct * 2 + 0) * 64 + lane) * 4));
      h8 b1 = uph8(*(const uint4*)(Fmlp + ((ct * 2 + 1) * 64 + lane) * 4));
      f4 c = {0.f, 0.f, 0.f, 0.f};
      c = __builtin_amdgcn_mfma_f32_16x16x32_f16(a0, b0, c, 0, 0, 0);
      c = __builtin_amdgcn_mfma_f32_16x16x32_f16(a1, b1, c, 0, 0, 0);
      float bias = mlpb[ct * 16 + l15];
#pragma unroll
      for (int r = 0; r < 4; ++r) sk[ct][r] = lrelu(c[r] + bias);
    }
  }
  __syncthreads();
#pragma unroll
  for (int ct = 0; ct < 4; ++ct) {
#pragma unroll
    for (int r = 0; r < 4; ++r)
      H[(16 * w + lg * 4 + r) * 72 + ct * 16 + l15] = (_Float16)sk[ct][r];
  }
  __syncthreads();

  // phase 2: out = skip @ decTop + lT, BN, lrelu -> fp32 final
  float fv[4][4];  // [ct][r]
  {
    h8 a0 = uph8(*(const uint4*)(P + arow * 36 + 0 * 16 + lg * 4));
    h8 a1 = uph8(*(const uint4*)(P + arow * 36 + 1 * 16 + lg * 4));
#pragma unroll
    for (int ct = 0; ct < 4; ++ct) {
      h8 b0 = uph8(*(const uint4*)(Ftop + ((ct * 2 + 0) * 64 + lane) * 4));
      h8 b1 = uph8(*(const uint4*)(Ftop + ((ct * 2 + 1) * 64 + lane) * 4));
      f4 c = {0.f, 0.f, 0.f, 0.f};
      c = __builtin_amdgcn_mfma_f32_16x16x32_f16(a0, b0, c, 0, 0, 0);
      c = __builtin_amdgcn_mfma_f32_16x16x32_f16(a1, b1, c, 0, 0, 0);
      int col = ct * 16 + l15;
      float sc = fold[col], sh = fold[64 + col];
#pragma unroll
      for (int r = 0; r < 4; ++r) {
        float ov = (c[r] + lv[r][ct]) * sc + sh;
        fv[ct][r] = lrelu(ov);
        if (grow_[r] < n) outF[(size_t)grow_[r] * 64 + col] = fv[ct][r];
      }
    }
  }

  // phase 3 (optional): lTout = out @ decNextBot + decbN (fp16)
  if (FnextBot) {
    __syncthreads();
#pragma unroll
    for (int ct = 0; ct < 4; ++ct) {
#pragma unroll
      for (int r = 0; r < 4; ++r)
        H[(16 * w + lg * 4 + r) * 72 + ct * 16 + l15] = (_Float16)fv[ct][r];
    }
    __syncthreads();
    h8 a0 = uph8(*(const uint4*)(P + arow * 36 + 0 * 16 + lg * 4));
    h8 a1 = uph8(*(const uint4*)(P + arow * 36 + 1 * 16 + lg * 4));
#pragma unroll
    for (int ct = 0; ct < 4; ++ct) {
      h8 b0 = uph8(*(const uint4*)(FnextBot + ((ct * 2 + 0) * 64 + lane) * 4));
      h8 b1 = uph8(*(const uint4*)(FnextBot + ((ct * 2 + 1) * 64 + lane) * 4));
      f4 c = {0.f, 0.f, 0.f, 0.f};
      c = __builtin_amdgcn_mfma_f32_16x16x32_f16(a0, b0, c, 0, 0, 0);
      c = __builtin_amdgcn_mfma_f32_16x16x32_f16(a1, b1, c, 0, 0, 0);
      int col = ct * 16 + l15;
      float bias = decbN[col];
#pragma unroll
      for (int r = 0; r < 4; ++r)
        if (grow_[r] < n) lTout[(size_t)grow_[r] * 64 + col] = (_Float16)(c[r] + bias);
    }
  }
}

extern "C" void kernel_launch(void* const* d_in, const int* in_sizes, int n_in,
                              void* d_out, int out_size, void* d_ws, size_t ws_size,
                              hipStream_t stream) {
  const float* pt   = (const float*)d_in[0];
  const int* inv2   = (const int*)d_in[1];
  const int* inv4   = (const int*)d_in[2];
  const int* inv8   = (const int*)d_in[3];
  const int* inv16  = (const int*)d_in[4];
  const float* e0W1 = (const float*)d_in[5];
  const float* e0b1 = (const float*)d_in[6];
  const float* e0g  = (const float*)d_in[7];
  const float* e0be = (const float*)d_in[8];
  const float* e0m  = (const float*)d_in[9];
  const float* e0v  = (const float*)d_in[10];
  const float* e0W2 = (const float*)d_in[11];
  const float* e0b2 = (const float*)d_in[12];
  const float* eRW1 = (const float*)d_in[13];
  const float* eRb1 = (const float*)d_in[14];
  const float* eRg  = (const float*)d_in[15];
  const float* eRbe = (const float*)d_in[16];
  const float* eRm  = (const float*)d_in[17];
  const float* eRv  = (const float*)d_in[18];
  const float* eRW2 = (const float*)d_in[19];
  const float* eRb2 = (const float*)d_in[20];
  const float* mlpW = (const float*)d_in[21];
  const float* mlpb = (const float*)d_in[22];
  const float* decW = (const float*)d_in[23];
  const float* decb = (const float*)d_in[24];
  const float* decg = (const float*)d_in[25];
  const float* decbe= (const float*)d_in[26];
  const float* decm = (const float*)d_in[27];
  const float* decv = (const float*)d_in[28];

  float* s1 = (float*)d_out;
  float* s2 = s1 + (size_t)N1 * 64;
  float* s3 = s2 + (size_t)N2 * 64;
  float* s4 = s3 + (size_t)N4 * 64;
  float* s5 = s4 + (size_t)N8 * 64;

  // ws: fold | frag packs | pH1..pH5 (fp16 u32) | lTA | lTB (fp16) | head | nxt
  float* fold = (float*)d_ws;
  unsigned* F_e0W2 = (unsigned*)(fold + 1024);   // 1024 u
  unsigned* F_eRW1 = F_e0W2 + 1024;              // 4096 u
  unsigned* F_eRW2 = F_eRW1 + 4096;              // 4096 u
  unsigned* F_mlp  = F_eRW2 + 4096;              // 10240 u
  unsigned* F_top  = F_mlp + 10240;              // 10240 u
  unsigned* F_bot  = F_top + 10240;              // 10240 u
  unsigned* pH1 = F_bot + 10240;                 // N1*32 u
  unsigned* pH2 = pH1 + (size_t)N1 * 32;         // N2*32 u
  unsigned* pH3 = pH2 + (size_t)N2 * 32;         // N4*32 u
  unsigned* pH4 = pH3 + (size_t)N4 * 32;         // N8*32 u
  unsigned* pH5 = pH4 + (size_t)N8 * 32;         // N16*32 u
  _Float16* lTA = (_Float16*)(pH5 + (size_t)N16 * 32);  // N2*64 h
  _Float16* lTB = lTA + (size_t)N2 * 64;                // N4*64 h
  int* head  = (int*)(lTB + (size_t)N4 * 64);    // N2 i
  int* nxt   = head + N2;                        // N1 i

  k_fold<<<1, 320, 0, stream>>>(e0g, e0be, e0m, e0v, eRg, eRbe, eRm, eRv,
                                decg, decbe, decm, decv, fold);
  k_packB<<<4, 256, 0, stream>>>(e0W2, F_e0W2, 64, 1, 1024);
  for (int i = 0; i < 4; ++i) {
    k_packB<<<4, 256, 0, stream>>>(eRW1 + i * 2048, F_eRW1 + i * 1024, 32, 2, 1024);
    k_packB<<<4, 256, 0, stream>>>(eRW2 + i * 2048, F_eRW2 + i * 1024, 64, 1, 1024);
  }
  for (int i = 0; i < 5; ++i) {
    k_packB<<<8, 256, 0, stream>>>(mlpW + i * 4096, F_mlp + i * 2048, 64, 2, 2048);
    k_packB<<<8, 256, 0, stream>>>(decW + i * 8192, F_top + i * 2048, 64, 2, 2048);
    k_packB<<<8, 256, 0, stream>>>(decW + i * 8192 + 4096, F_bot + i * 2048, 64, 2, 2048);
  }

  // ---- level 1: enc0 on N1 -> pH1 ----
  hipMemsetAsync(head, 0xFF, (size_t)N2 * 4, stream);
  k_fill<<<(N1 + 255) / 256, 256, 0, stream>>>(inv2, head, nxt, N1);
  k_enc0_m<<<(N1 + 63) / 64, 256, 0, stream>>>(pt, e0W1, e0b1, fold, F_e0W2, e0b2, pH1, N1);

  // ---- level 2: encR[0] fused pool(pH1) -> pH2 [N2] ----
  k_encR_m<<<(N2 + 63) / 64, 256, 0, stream>>>(pH1, head, nxt,
                                               F_eRW1 + 0 * 1024, eRb1 + 0 * 32,
                                               fold + 64 + 0 * 64, F_eRW2 + 0 * 1024,
                                               eRb2 + 0 * 64, pH2, N2);

  // ---- level 3: encR[1] fused pool(pH2) -> pH3 [N4] ----
  hipMemsetAsync(head, 0xFF, (size_t)N4 * 4, stream);
  k_fill<<<(N2 + 255) / 256, 256, 0, stream>>>(inv4, head, nxt, N2);
  k_encR_m<<<(N4 + 63) / 64, 256, 0, stream>>>(pH2, head, nxt,
                                               F_eRW1 + 1 * 1024, eRb1 + 1 * 32,
                                               fold + 64 + 1 * 64, F_eRW2 + 1 * 1024,
                                               eRb2 + 1 * 64, pH3, N4);

  // ---- level 4: encR[2] fused pool(pH3) -> pH4 [N8] ----
  hipMemsetAsync(head, 0xFF, (size_t)N8 * 4, stream);
  k_fill<<<(N4 + 255) / 256, 256, 0, stream>>>(inv8, head, nxt, N4);
  k_encR_m<<<(N8 + 63) / 64, 256, 0, stream>>>(pH3, head, nxt,
                                               F_eRW1 + 2 * 1024, eRb1 + 2 * 32,
                                               fold + 64 + 2 * 64, F_eRW2 + 2 * 1024,
                                               eRb2 + 2 * 64, pH4, N8);

  // ---- level 5: encR[3] fused pool(pH4) -> pH5 [N16] ----
  hipMemsetAsync(head, 0xFF, (size_t)N16 * 4, stream);
  k_fill<<<(N8 + 255) / 256, 256, 0, stream>>>(inv16, head, nxt, N8);
  k_encR_m<<<(N16 + 63) / 64, 256, 0, stream>>>(pH4, head, nxt,
                                                F_eRW1 + 3 * 1024, eRb1 + 3 * 32,
                                                fold + 64 + 3 * 64, F_eRW2 + 3 * 1024,
                                                eRb2 + 3 * 64, pH5, N16);

  // ---- decoders (MFMA, fp16 in / fp32 out) with fused next-level lastT ----
  k_lastT_m<<<(N16 + 63) / 64, 256, 0, stream>>>(pH5, F_bot + 0 * 2048, decb + 0 * 64,
                                                 lTA, N16);
  k_dec2_m<<<(N16 + 63) / 64, 256, 0, stream>>>(pH5, s5, lTA, nullptr,
                                                F_mlp + 0 * 2048, mlpb + 0 * 64,
                                                F_top + 0 * 2048, fold + 320 + 0 * 128, N16,
                                                F_bot + 1 * 2048, decb + 1 * 64, lTB);
  k_dec2_m<<<(N8 + 63) / 64, 256, 0, stream>>>(pH4, s4, lTB, inv16,
                                               F_mlp + 1 * 2048, mlpb + 1 * 64,
                                               F_top + 1 * 2048, fold + 320 + 1 * 128, N8,
                                               F_bot + 2 * 2048, decb + 2 * 64, lTA);
  k_dec2_m<<<(N4 + 63) / 64, 256, 0, stream>>>(pH3, s3, lTA, inv8,
                                               F_mlp + 2 * 2048, mlpb + 2 * 64,
                                               F_top + 2 * 2048, fold + 320 + 2 * 128, N4,
                                               F_bot + 3 * 2048, decb + 3 * 64, lTB);
  k_dec2_m<<<(N2 + 63) / 64, 256, 0, stream>>>(pH2, s2, lTB, inv4,
                                               F_mlp + 3 * 2048, mlpb + 3 * 64,
                                               F_top + 3 * 2048, fold + 320 + 3 * 128, N2,
                                               F_bot + 4 * 2048, decb + 4 * 64, lTA);
  k_dec2_m<<<(N1 + 63) / 64, 256, 0, stream>>>(pH1, s1, lTA, inv2,
                                               F_mlp + 4 * 2048, mlpb + 4 * 64,
                                               F_top + 4 * 2048, fold + 320 + 4 * 128, N1,
                                               nullptr, nullptr, nullptr);
}

// Round 22
// 575.166 us; speedup vs baseline: 4.3805x; 1.1025x over previous
//
#include <hip/hip_runtime.h>

#define N1 1000000
#define N2 400000
#define N4 150000
#define N8 60000
#define N16 20000

constexpr float BN_EPS = 1e-5f;

typedef _Float16 h2 __attribute__((ext_vector_type(2)));
typedef _Float16 h8 __attribute__((ext_vector_type(8)));
typedef float f4 __attribute__((ext_vector_type(4)));

__device__ __forceinline__ float lrelu(float x) { return fmaxf(x, 0.1f * x); }

__device__ __forceinline__ unsigned pk(float x, float y) {
  h2 h = {(_Float16)x, (_Float16)y};
  unsigned u;
  __builtin_memcpy(&u, &h, 4);
  return u;
}
__device__ __forceinline__ h2 uph(unsigned u) {
  h2 h;
  __builtin_memcpy(&h, &u, 4);
  return h;
}
__device__ __forceinline__ h8 uph8(uint4 u) {
  h8 h;
  __builtin_memcpy(&h, &u, 16);
  return h;
}

__device__ __forceinline__ void packB_one(const float* __restrict__ W,
                                          unsigned* __restrict__ d,
                                          int C, int KT, int i) {
  int q = i & 3, l = (i >> 2) & 63;
  int rest = i >> 8;
  int t = rest % KT, ct = rest / KT;
  int col = ct * 16 + (l & 15);
  int k0 = t * 32 + ((l >> 4) << 3) + 2 * q;
  d[i] = pk(W[k0 * C + col], W[(k0 + 1) * C + col]);
}

// One-dispatch prep: all MFMA B-fragment packs + BN folds (flat job index).
__global__ __launch_bounds__(256) void k_prep(
    const float* e0W2, const float* eRW1, const float* eRW2,
    const float* mlpW, const float* decW,
    const float* g0, const float* be0, const float* m0, const float* v0,
    const float* gR, const float* beR, const float* mR, const float* vR,
    const float* gD, const float* beD, const float* mD, const float* vD,
    float* fold,
    unsigned* F_e0W2, unsigned* F_eRW1, unsigned* F_eRW2,
    unsigned* F_mlp, unsigned* F_top, unsigned* F_bot) {
  int g = blockIdx.x * 256 + threadIdx.x;
  if (g < 1024) { packB_one(e0W2, F_e0W2, 64, 1, g); return; }
  g -= 1024;
  if (g < 4096) {
    int i = g & 1023, m = g >> 10;
    packB_one(eRW1 + m * 2048, F_eRW1 + m * 1024, 32, 2, i); return;
  }
  g -= 4096;
  if (g < 4096) {
    int i = g & 1023, m = g >> 10;
    packB_one(eRW2 + m * 2048, F_eRW2 + m * 1024, 64, 1, i); return;
  }
  g -= 4096;
  if (g < 10240) {
    int i = g & 2047, m = g >> 11;
    packB_one(mlpW + m * 4096, F_mlp + m * 2048, 64, 2, i); return;
  }
  g -= 10240;
  if (g < 10240) {
    int i = g & 2047, m = g >> 11;
    packB_one(decW + m * 8192, F_top + m * 2048, 64, 2, i); return;
  }
  g -= 10240;
  if (g < 10240) {
    int i = g & 2047, m = g >> 11;
    packB_one(decW + m * 8192 + 4096, F_bot + m * 2048, 64, 2, i); return;
  }
  g -= 10240;
  if (g < 320) {
    int t = g;
    if (t < 32) {
      float sc = g0[t] * rsqrtf(v0[t] + BN_EPS);
      fold[t] = sc;
      fold[32 + t] = be0[t] - m0[t] * sc;
    }
    if (t < 128) {
      int b = t >> 5, c = t & 31;
      float sc = gR[b * 32 + c] * rsqrtf(vR[b * 32 + c] + BN_EPS);
      fold[64 + b * 64 + c] = sc;
      fold[64 + b * 64 + 32 + c] = beR[b * 32 + c] - mR[b * 32 + c] * sc;
    }
    {
      int b = t >> 6, c = t & 63;
      float sc = gD[b * 64 + c] * rsqrtf(vD[b * 64 + c] + BN_EPS);
      fold[320 + b * 128 + c] = sc;
      fold[320 + b * 128 + 64 + c] = beD[b * 64 + c] - mD[b * 64 + c] * sc;
    }
  }
}

// One-dispatch linked-list build for ALL 4 levels (independent lists).
__global__ __launch_bounds__(256) void k_fill_all(
    const int* __restrict__ inv2, const int* __restrict__ inv4,
    const int* __restrict__ inv8, const int* __restrict__ inv16,
    int* hd2, int* hd3, int* hd4, int* hd5,
    int* nx1, int* nx2, int* nx3, int* nx4) {
  int i = blockIdx.x * 256 + threadIdx.x;
  if (i < N1) { nx1[i] = atomicExch(&hd2[inv2[i]], i); return; }
  i -= N1;
  if (i < N2) { nx2[i] = atomicExch(&hd3[inv4[i]], i); return; }
  i -= N2;
  if (i < N4) { nx3[i] = atomicExch(&hd4[inv8[i]], i); return; }
  i -= N4;
  if (i < N8) { nx4[i] = atomicExch(&hd5[inv16[i]], i); return; }
}

// ---------------- MFMA GEMM kernels (fp16 intermediate storage) -------------
// Block = 256 thr (4 waves); tile 64 rows; wave w owns rows 16w..16w+15.
// A: LDS [64 rows][36 u32]; lane l: row 16w+(l&15), k=(l>>4)*8..+7.
// B: fragment-linear packed buffers; D: row=16w+(l>>4)*4+reg, col=ct*16+(l&15).

// encoder block 0: x[9] -> h[32] (fp32 K=9) -> outH[64] fp16 (MFMA K=32)
__global__ __launch_bounds__(256) void k_enc0_m(
    const float* __restrict__ x,
    const float* __restrict__ W1, const float* __restrict__ b1,
    const float* __restrict__ fold,
    const unsigned* __restrict__ F2, const float* __restrict__ b2,
    unsigned* __restrict__ outH, int n) {
  __shared__ float xS[64 * 9];
  __shared__ unsigned hP[64 * 20];
  __shared__ _Float16 oH[64 * 72];
  int t = threadIdx.x;
  int lane = t & 63;
  int w = __builtin_amdgcn_readfirstlane(t >> 6);
  int R = blockIdx.x * 64;
  int l15 = lane & 15, lg = lane >> 4;

  {
    size_t lim = (size_t)n * 9 - 1;
    for (int i = t; i < 576; i += 256) {
      size_t gi = (size_t)R * 9 + i;
      if (gi > lim) gi = lim;
      xS[i] = x[gi];
    }
  }
  __syncthreads();

  {
    const float* W1p = W1 + w * 8;
    float xr[9];
#pragma unroll
    for (int k = 0; k < 9; ++k) xr[k] = xS[lane * 9 + k];
    float acc[8];
#pragma unroll
    for (int c = 0; c < 8; ++c) acc[c] = b1[w * 8 + c];
#pragma unroll
    for (int k = 0; k < 9; ++k) {
#pragma unroll
      for (int c = 0; c < 8; ++c) acc[c] = fmaf(xr[k], W1p[k * 32 + c], acc[c]);
    }
    float v[8];
#pragma unroll
    for (int c = 0; c < 8; ++c)
      v[c] = lrelu(acc[c]) * fold[w * 8 + c] + fold[32 + w * 8 + c];
#pragma unroll
    for (int j = 0; j < 4; ++j)
      hP[lane * 20 + w * 4 + j] = pk(v[2 * j], v[2 * j + 1]);
  }
  __syncthreads();

  {
    int arow = 16 * w + l15;
    h8 a = uph8(*(const uint4*)(hP + arow * 20 + lg * 4));
#pragma unroll
    for (int ct = 0; ct < 4; ++ct) {
      h8 b = uph8(*(const uint4*)(F2 + (ct * 64 + lane) * 4));
      f4 c = {0.f, 0.f, 0.f, 0.f};
      c = __builtin_amdgcn_mfma_f32_16x16x32_f16(a, b, c, 0, 0, 0);
      int col = ct * 16 + l15;
      float bias = b2[col];
#pragma unroll
      for (int r = 0; r < 4; ++r)
        oH[(16 * w + lg * 4 + r) * 72 + col] = (_Float16)lrelu(c[r] + bias);
    }
  }
  __syncthreads();
  for (int f = t; f < 2048; f += 256) {
    int row = f >> 5, i = f & 31;
    int gr = R + row;
    if (gr < n) outH[(size_t)gr * 32 + i] = ((unsigned*)oH)[row * 36 + i];
  }
}

// encoder blocks 1..4 with fused segment-max pooling (chain-walk staging).
__global__ __launch_bounds__(256) void k_encR_m(
    const unsigned* __restrict__ srcH, const int* __restrict__ head,
    const int* __restrict__ nxt,
    const unsigned* __restrict__ F1, const float* __restrict__ b1,
    const float* __restrict__ fold,
    const unsigned* __restrict__ F2, const float* __restrict__ b2,
    unsigned* __restrict__ outH, int n) {
  __shared__ unsigned P[64 * 36];
  __shared__ unsigned hP[64 * 20];
  __shared__ _Float16 oH[64 * 72];
  int t = threadIdx.x;
  int lane = t & 63;
  int w = __builtin_amdgcn_readfirstlane(t >> 6);
  int R = blockIdx.x * 64;
  int l15 = lane & 15, lg = lane >> 4;
  _Float16* Hh = (_Float16*)hP;

  for (int f = t; f < 2048; f += 256) {
    int row = f >> 5, i = f & 31;
    int seg = R + row;
    unsigned ov = 0u;
    if (seg < n) {
      float m0 = -INFINITY, m1 = -INFINITY;
      for (int p = head[seg]; p >= 0; p = nxt[p]) {
        h2 v = uph(srcH[(size_t)p * 32 + i]);
        m0 = fmaxf(m0, (float)v.x);
        m1 = fmaxf(m1, (float)v.y);
      }
      if (m0 == -INFINITY) m0 = 0.0f;
      if (m1 == -INFINITY) m1 = 0.0f;
      ov = pk(m0, m1);
    }
    P[row * 36 + i] = ov;
  }
  __syncthreads();

  int arow = 16 * w + l15;

  {
    h8 a0 = uph8(*(const uint4*)(P + arow * 36 + 0 * 16 + lg * 4));
    h8 a1 = uph8(*(const uint4*)(P + arow * 36 + 1 * 16 + lg * 4));
#pragma unroll
    for (int ct = 0; ct < 2; ++ct) {
      h8 b0 = uph8(*(const uint4*)(F1 + ((ct * 2 + 0) * 64 + lane) * 4));
      h8 b1v = uph8(*(const uint4*)(F1 + ((ct * 2 + 1) * 64 + lane) * 4));
      f4 c = {0.f, 0.f, 0.f, 0.f};
      c = __builtin_amdgcn_mfma_f32_16x16x32_f16(a0, b0, c, 0, 0, 0);
      c = __builtin_amdgcn_mfma_f32_16x16x32_f16(a1, b1v, c, 0, 0, 0);
      int col = ct * 16 + l15;
      float bias = b1[col], sc = fold[col], sh = fold[32 + col];
#pragma unroll
      for (int r = 0; r < 4; ++r) {
        int row = 16 * w + lg * 4 + r;
        Hh[row * 40 + col] = (_Float16)(lrelu(c[r] + bias) * sc + sh);
      }
    }
  }
  __syncthreads();

  {
    h8 a = uph8(*(const uint4*)(hP + arow * 20 + lg * 4));
#pragma unroll
    for (int ct = 0; ct < 4; ++ct) {
      h8 b = uph8(*(const uint4*)(F2 + (ct * 64 + lane) * 4));
      f4 c = {0.f, 0.f, 0.f, 0.f};
      c = __builtin_amdgcn_mfma_f32_16x16x32_f16(a, b, c, 0, 0, 0);
      int col = ct * 16 + l15;
      float bias = b2[col];
#pragma unroll
      for (int r = 0; r < 4; ++r)
        oH[(16 * w + lg * 4 + r) * 72 + col] = (_Float16)lrelu(c[r] + bias);
    }
  }
  __syncthreads();
  for (int f = t; f < 2048; f += 256) {
    int row = f >> 5, i = f & 31;
    int gr = R + row;
    if (gr < n) outH[(size_t)gr * 32 + i] = ((unsigned*)oH)[row * 36 + i];
  }
}

// lastT = srcH @ decW_bot + decb  (seed, MFMA K=64, fp16 out)
__global__ __launch_bounds__(256) void k_lastT_m(
    const unsigned* __restrict__ srcH, const unsigned* __restrict__ Fbot,
    const float* __restrict__ decb, _Float16* __restrict__ lT, int n) {
  __shared__ unsigned P[64 * 36];
  int t = threadIdx.x;
  int lane = t & 63;
  int w = __builtin_amdgcn_readfirstlane(t >> 6);
  int R = blockIdx.x * 64;
  int l15 = lane & 15, lg = lane >> 4;

  for (int f = t; f < 2048; f += 256) {
    int row = f >> 5, i = f & 31;
    int gr = R + row; if (gr >= n) gr = n - 1;
    P[row * 36 + i] = srcH[(size_t)gr * 32 + i];
  }
  __syncthreads();

  int arow = 16 * w + l15;
  h8 a0 = uph8(*(const uint4*)(P + arow * 36 + 0 * 16 + lg * 4));
  h8 a1 = uph8(*(const uint4*)(P + arow * 36 + 1 * 16 + lg * 4));

#pragma unroll
  for (int ct = 0; ct < 4; ++ct) {
    h8 b0 = uph8(*(const uint4*)(Fbot + ((ct * 2 + 0) * 64 + lane) * 4));
    h8 b1 = uph8(*(const uint4*)(Fbot + ((ct * 2 + 1) * 64 + lane) * 4));
    f4 c = {0.f, 0.f, 0.f, 0.f};
    c = __builtin_amdgcn_mfma_f32_16x16x32_f16(a0, b0, c, 0, 0, 0);
    c = __builtin_amdgcn_mfma_f32_16x16x32_f16(a1, b1, c, 0, 0, 0);
    int col = ct * 16 + l15;
    float bias = decb[col];
#pragma unroll
    for (int r = 0; r < 4; ++r) {
      int grow = R + 16 * w + lg * 4 + r;
      if (grow < n) lT[(size_t)grow * 64 + col] = (_Float16)(c[r] + bias);
    }
  }
}

// decoder: outF = lrelu(BN(lrelu(curH@mlp) @ decTop + lT[lrow])) (fp32 final);
// optional phase 3: lTout = outF @ decNextBot + decbN (fp16).
__global__ __launch_bounds__(256) void k_dec2_m(
    const unsigned* __restrict__ curH, float* __restrict__ outF,
    const _Float16* __restrict__ lT, const int* __restrict__ idx,
    const unsigned* __restrict__ Fmlp, const float* __restrict__ mlpb,
    const unsigned* __restrict__ Ftop, const float* __restrict__ fold, int n,
    const unsigned* __restrict__ FnextBot, const float* __restrict__ decbN,
    _Float16* __restrict__ lTout) {
  __shared__ unsigned P[64 * 36];
  int t = threadIdx.x;
  int lane = t & 63;
  int w = __builtin_amdgcn_readfirstlane(t >> 6);
  int R = blockIdx.x * 64;
  int l15 = lane & 15, lg = lane >> 4;
  _Float16* H = (_Float16*)P;

  for (int f = t; f < 2048; f += 256) {
    int row = f >> 5, i = f & 31;
    int gr = R + row; if (gr >= n) gr = n - 1;
    P[row * 36 + i] = curH[(size_t)gr * 32 + i];
  }

  int grow_[4], gidx_[4];
#pragma unroll
  for (int r = 0; r < 4; ++r) {
    grow_[r] = R + 16 * w + lg * 4 + r;
    int gcl = grow_[r] >= n ? n - 1 : grow_[r];
    gidx_[r] = idx ? idx[gcl] : gcl;
  }
  float lv[4][4];  // [r][ct]
#pragma unroll
  for (int r = 0; r < 4; ++r) {
#pragma unroll
    for (int ct = 0; ct < 4; ++ct)
      lv[r][ct] = (float)lT[(size_t)gidx_[r] * 64 + ct * 16 + l15];
  }
  __syncthreads();

  int arow = 16 * w + l15;

  // phase 1: skip = lrelu(cur @ mlpW + mlpb)
  float sk[4][4];
  {
    h8 a0 = uph8(*(const uint4*)(P + arow * 36 + 0 * 16 + lg * 4));
    h8 a1 = uph8(*(const uint4*)(P + arow * 36 + 1 * 16 + lg * 4));
#pragma unroll
    for (int ct = 0; ct < 4; ++ct) {
      h8 b0 = uph8(*(const uint4*)(Fmlp + ((ct * 2 + 0) * 64 + lane) * 4));
      h8 b1 = uph8(*(const uint4*)(Fmlp + ((ct * 2 + 1) * 64 + lane) * 4));
      f4 c = {0.f, 0.f, 0.f, 0.f};
      c = __builtin_amdgcn_mfma_f32_16x16x32_f16(a0, b0, c, 0, 0, 0);
      c = __builtin_amdgcn_mfma_f32_16x16x32_f16(a1, b1, c, 0, 0, 0);
      float bias = mlpb[ct * 16 + l15];
#pragma unroll
      for (int r = 0; r < 4; ++r) sk[ct][r] = lrelu(c[r] + bias);
    }
  }
  __syncthreads();
#pragma unroll
  for (int ct = 0; ct < 4; ++ct) {
#pragma unroll
    for (int r = 0; r < 4; ++r)
      H[(16 * w + lg * 4 + r) * 72 + ct * 16 + l15] = (_Float16)sk[ct][r];
  }
  __syncthreads();

  // phase 2: out = skip @ decTop + lT, BN, lrelu -> fp32 final
  float fv[4][4];
  {
    h8 a0 = uph8(*(const uint4*)(P + arow * 36 + 0 * 16 + lg * 4));
    h8 a1 = uph8(*(const uint4*)(P + arow * 36 + 1 * 16 + lg * 4));
#pragma unroll
    for (int ct = 0; ct < 4; ++ct) {
      h8 b0 = uph8(*(const uint4*)(Ftop + ((ct * 2 + 0) * 64 + lane) * 4));
      h8 b1 = uph8(*(const uint4*)(Ftop + ((ct * 2 + 1) * 64 + lane) * 4));
      f4 c = {0.f, 0.f, 0.f, 0.f};
      c = __builtin_amdgcn_mfma_f32_16x16x32_f16(a0, b0, c, 0, 0, 0);
      c = __builtin_amdgcn_mfma_f32_16x16x32_f16(a1, b1, c, 0, 0, 0);
      int col = ct * 16 + l15;
      float sc = fold[col], sh = fold[64 + col];
#pragma unroll
      for (int r = 0; r < 4; ++r) {
        float ov = (c[r] + lv[r][ct]) * sc + sh;
        fv[ct][r] = lrelu(ov);
        if (grow_[r] < n) outF[(size_t)grow_[r] * 64 + col] = fv[ct][r];
      }
    }
  }

  // phase 3 (optional): lTout = out @ decNextBot + decbN (fp16)
  if (FnextBot) {
    __syncthreads();
#pragma unroll
    for (int ct = 0; ct < 4; ++ct) {
#pragma unroll
      for (int r = 0; r < 4; ++r)
        H[(16 * w + lg * 4 + r) * 72 + ct * 16 + l15] = (_Float16)fv[ct][r];
    }
    __syncthreads();
    h8 a0 = uph8(*(const uint4*)(P + arow * 36 + 0 * 16 + lg * 4));
    h8 a1 = uph8(*(const uint4*)(P + arow * 36 + 1 * 16 + lg * 4));
#pragma unroll
    for (int ct = 0; ct < 4; ++ct) {
      h8 b0 = uph8(*(const uint4*)(FnextBot + ((ct * 2 + 0) * 64 + lane) * 4));
      h8 b1 = uph8(*(const uint4*)(FnextBot + ((ct * 2 + 1) * 64 + lane) * 4));
      f4 c = {0.f, 0.f, 0.f, 0.f};
      c = __builtin_amdgcn_mfma_f32_16x16x32_f16(a0, b0, c, 0, 0, 0);
      c = __builtin_amdgcn_mfma_f32_16x16x32_f16(a1, b1, c, 0, 0, 0);
      int col = ct * 16 + l15;
      float bias = decbN[col];
#pragma unroll
      for (int r = 0; r < 4; ++r)
        if (grow_[r] < n) lTout[(size_t)grow_[r] * 64 + col] = (_Float16)(c[r] + bias);
    }
  }
}

extern "C" void kernel_launch(void* const* d_in, const int* in_sizes, int n_in,
                              void* d_out, int out_size, void* d_ws, size_t ws_size,
                              hipStream_t stream) {
  const float* pt   = (const float*)d_in[0];
  const int* inv2   = (const int*)d_in[1];
  const int* inv4   = (const int*)d_in[2];
  const int* inv8   = (const int*)d_in[3];
  const int* inv16  = (const int*)d_in[4];
  const float* e0W1 = (const float*)d_in[5];
  const float* e0b1 = (const float*)d_in[6];
  const float* e0g  = (const float*)d_in[7];
  const float* e0be = (const float*)d_in[8];
  const float* e0m  = (const float*)d_in[9];
  const float* e0v  = (const float*)d_in[10];
  const float* e0W2 = (const float*)d_in[11];
  const float* e0b2 = (const float*)d_in[12];
  const float* eRW1 = (const float*)d_in[13];
  const float* eRb1 = (const float*)d_in[14];
  const float* eRg  = (const float*)d_in[15];
  const float* eRbe = (const float*)d_in[16];
  const float* eRm  = (const float*)d_in[17];
  const float* eRv  = (const float*)d_in[18];
  const float* eRW2 = (const float*)d_in[19];
  const float* eRb2 = (const float*)d_in[20];
  const float* mlpW = (const float*)d_in[21];
  const float* mlpb = (const float*)d_in[22];
  const float* decW = (const float*)d_in[23];
  const float* decb = (const float*)d_in[24];
  const float* decg = (const float*)d_in[25];
  const float* decbe= (const float*)d_in[26];
  const float* decm = (const float*)d_in[27];
  const float* decv = (const float*)d_in[28];

  float* s1 = (float*)d_out;
  float* s2 = s1 + (size_t)N1 * 64;
  float* s3 = s2 + (size_t)N2 * 64;
  float* s4 = s3 + (size_t)N4 * 64;
  float* s5 = s4 + (size_t)N8 * 64;

  // ws: fold | frag packs | pH1..pH5 | lTA | lTB | heads (contig) | nxts
  float* fold = (float*)d_ws;
  unsigned* F_e0W2 = (unsigned*)(fold + 1024);   // 1024 u
  unsigned* F_eRW1 = F_e0W2 + 1024;              // 4096 u
  unsigned* F_eRW2 = F_eRW1 + 4096;              // 4096 u
  unsigned* F_mlp  = F_eRW2 + 4096;              // 10240 u
  unsigned* F_top  = F_mlp + 10240;              // 10240 u
  unsigned* F_bot  = F_top + 10240;              // 10240 u
  unsigned* pH1 = F_bot + 10240;                 // N1*32 u
  unsigned* pH2 = pH1 + (size_t)N1 * 32;         // N2*32 u
  unsigned* pH3 = pH2 + (size_t)N2 * 32;         // N4*32 u
  unsigned* pH4 = pH3 + (size_t)N4 * 32;         // N8*32 u
  unsigned* pH5 = pH4 + (size_t)N8 * 32;         // N16*32 u
  _Float16* lTA = (_Float16*)(pH5 + (size_t)N16 * 32);  // N2*64 h
  _Float16* lTB = lTA + (size_t)N2 * 64;                // N4*64 h
  int* hd2 = (int*)(lTB + (size_t)N4 * 64);      // N2
  int* hd3 = hd2 + N2;                           // N4
  int* hd4 = hd3 + N4;                           // N8
  int* hd5 = hd4 + N8;                           // N16
  int* nx1 = hd5 + N16;                          // N1
  int* nx2 = nx1 + N1;                           // N2
  int* nx3 = nx2 + N2;                           // N4
  int* nx4 = nx3 + N4;                           // N8

  // prep: fold + all fragment packs (1 dispatch)
  k_prep<<<(40256 + 255) / 256, 256, 0, stream>>>(
      e0W2, eRW1, eRW2, mlpW, decW,
      e0g, e0be, e0m, e0v, eRg, eRbe, eRm, eRv, decg, decbe, decm, decv,
      fold, F_e0W2, F_eRW1, F_eRW2, F_mlp, F_top, F_bot);

  // all heads reset (contiguous) + all linked lists (1 dispatch each)
  hipMemsetAsync(hd2, 0xFF, (size_t)(N2 + N4 + N8 + N16) * 4, stream);
  k_fill_all<<<(N1 + N2 + N4 + N8 + 255) / 256, 256, 0, stream>>>(
      inv2, inv4, inv8, inv16, hd2, hd3, hd4, hd5, nx1, nx2, nx3, nx4);

  // ---- encoders (fused pooling) ----
  k_enc0_m<<<(N1 + 63) / 64, 256, 0, stream>>>(pt, e0W1, e0b1, fold, F_e0W2, e0b2, pH1, N1);
  k_encR_m<<<(N2 + 63) / 64, 256, 0, stream>>>(pH1, hd2, nx1,
                                               F_eRW1 + 0 * 1024, eRb1 + 0 * 32,
                                               fold + 64 + 0 * 64, F_eRW2 + 0 * 1024,
                                               eRb2 + 0 * 64, pH2, N2);
  k_encR_m<<<(N4 + 63) / 64, 256, 0, stream>>>(pH2, hd3, nx2,
                                               F_eRW1 + 1 * 1024, eRb1 + 1 * 32,
                                               fold + 64 + 1 * 64, F_eRW2 + 1 * 1024,
                                               eRb2 + 1 * 64, pH3, N4);
  k_encR_m<<<(N8 + 63) / 64, 256, 0, stream>>>(pH3, hd4, nx3,
                                               F_eRW1 + 2 * 1024, eRb1 + 2 * 32,
                                               fold + 64 + 2 * 64, F_eRW2 + 2 * 1024,
                                               eRb2 + 2 * 64, pH4, N8);
  k_encR_m<<<(N16 + 63) / 64, 256, 0, stream>>>(pH4, hd5, nx4,
                                                F_eRW1 + 3 * 1024, eRb1 + 3 * 32,
                                                fold + 64 + 3 * 64, F_eRW2 + 3 * 1024,
                                                eRb2 + 3 * 64, pH5, N16);

  // ---- decoders (MFMA, fp16 in / fp32 out) with fused next-level lastT ----
  k_lastT_m<<<(N16 + 63) / 64, 256, 0, stream>>>(pH5, F_bot + 0 * 2048, decb + 0 * 64,
                                                 lTA, N16);
  k_dec2_m<<<(N16 + 63) / 64, 256, 0, stream>>>(pH5, s5, lTA, nullptr,
                                                F_mlp + 0 * 2048, mlpb + 0 * 64,
                                                F_top + 0 * 2048, fold + 320 + 0 * 128, N16,
                                                F_bot + 1 * 2048, decb + 1 * 64, lTB);
  k_dec2_m<<<(N8 + 63) / 64, 256, 0, stream>>>(pH4, s4, lTB, inv16,
                                               F_mlp + 1 * 2048, mlpb + 1 * 64,
                                               F_top + 1 * 2048, fold + 320 + 1 * 128, N8,
                                               F_bot + 2 * 2048, decb + 2 * 64, lTA);
  k_dec2_m<<<(N4 + 63) / 64, 256, 0, stream>>>(pH3, s3, lTA, inv8,
                                               F_mlp + 2 * 2048, mlpb + 2 * 64,
                                               F_top + 2 * 2048, fold + 320 + 2 * 128, N4,
                                               F_bot + 3 * 2048, decb + 3 * 64, lTB);
  k_dec2_m<<<(N2 + 63) / 64, 256, 0, stream>>>(pH2, s2, lTB, inv4,
                                               F_mlp + 3 * 2048, mlpb + 3 * 64,
                                               F_top + 3 * 2048, fold + 320 + 3 * 128, N2,
                                               F_bot + 4 * 2048, decb + 4 * 64, lTA);
  k_dec2_m<<<(N1 + 63) / 64, 256, 0, stream>>>(pH1, s1, lTA, inv2,
                                               F_mlp + 4 * 2048, mlpb + 4 * 64,
                                               F_top + 4 * 2048, fold + 320 + 4 * 128, N1,
                                               nullptr, nullptr, nullptr);
}

// Round 23
// 555.518 us; speedup vs baseline: 4.5354x; 1.0354x over previous
//
#include <hip/hip_runtime.h>

#define N1 1000000
#define N2 400000
#define N4 150000
#define N8 60000
#define N16 20000

constexpr float BN_EPS = 1e-5f;

typedef _Float16 h2 __attribute__((ext_vector_type(2)));
typedef _Float16 h8 __attribute__((ext_vector_type(8)));
typedef float f4 __attribute__((ext_vector_type(4)));

__device__ __forceinline__ float lrelu(float x) { return fmaxf(x, 0.1f * x); }

__device__ __forceinline__ unsigned pk(float x, float y) {
  h2 h = {(_Float16)x, (_Float16)y};
  unsigned u;
  __builtin_memcpy(&u, &h, 4);
  return u;
}
__device__ __forceinline__ h2 uph(unsigned u) {
  h2 h;
  __builtin_memcpy(&h, &u, 4);
  return h;
}
__device__ __forceinline__ h8 uph8(uint4 u) {
  h8 h;
  __builtin_memcpy(&h, &u, 16);
  return h;
}

__device__ __forceinline__ void packB_one(const float* __restrict__ W,
                                          unsigned* __restrict__ d,
                                          int C, int KT, int i) {
  int q = i & 3, l = (i >> 2) & 63;
  int rest = i >> 8;
  int t = rest % KT, ct = rest / KT;
  int col = ct * 16 + (l & 15);
  int k0 = t * 32 + ((l >> 4) << 3) + 2 * q;
  d[i] = pk(W[k0 * C + col], W[(k0 + 1) * C + col]);
}

// One-dispatch prep: all MFMA B-fragment packs + BN folds (flat job index).
__global__ __launch_bounds__(256) void k_prep(
    const float* e0W2, const float* eRW1, const float* eRW2,
    const float* mlpW, const float* decW,
    const float* g0, const float* be0, const float* m0, const float* v0,
    const float* gR, const float* beR, const float* mR, const float* vR,
    const float* gD, const float* beD, const float* mD, const float* vD,
    float* fold,
    unsigned* F_e0W2, unsigned* F_eRW1, unsigned* F_eRW2,
    unsigned* F_mlp, unsigned* F_top, unsigned* F_bot) {
  int g = blockIdx.x * 256 + threadIdx.x;
  if (g < 1024) { packB_one(e0W2, F_e0W2, 64, 1, g); return; }
  g -= 1024;
  if (g < 4096) {
    int i = g & 1023, m = g >> 10;
    packB_one(eRW1 + m * 2048, F_eRW1 + m * 1024, 32, 2, i); return;
  }
  g -= 4096;
  if (g < 4096) {
    int i = g & 1023, m = g >> 10;
    packB_one(eRW2 + m * 2048, F_eRW2 + m * 1024, 64, 1, i); return;
  }
  g -= 4096;
  if (g < 10240) {
    int i = g & 2047, m = g >> 11;
    packB_one(mlpW + m * 4096, F_mlp + m * 2048, 64, 2, i); return;
  }
  g -= 10240;
  if (g < 10240) {
    int i = g & 2047, m = g >> 11;
    packB_one(decW + m * 8192, F_top + m * 2048, 64, 2, i); return;
  }
  g -= 10240;
  if (g < 10240) {
    int i = g & 2047, m = g >> 11;
    packB_one(decW + m * 8192 + 4096, F_bot + m * 2048, 64, 2, i); return;
  }
  g -= 10240;
  if (g < 320) {
    int t = g;
    if (t < 32) {
      float sc = g0[t] * rsqrtf(v0[t] + BN_EPS);
      fold[t] = sc;
      fold[32 + t] = be0[t] - m0[t] * sc;
    }
    if (t < 128) {
      int b = t >> 5, c = t & 31;
      float sc = gR[b * 32 + c] * rsqrtf(vR[b * 32 + c] + BN_EPS);
      fold[64 + b * 64 + c] = sc;
      fold[64 + b * 64 + 32 + c] = beR[b * 32 + c] - mR[b * 32 + c] * sc;
    }
    {
      int b = t >> 6, c = t & 63;
      float sc = gD[b * 64 + c] * rsqrtf(vD[b * 64 + c] + BN_EPS);
      fold[320 + b * 128 + c] = sc;
      fold[320 + b * 128 + 64 + c] = beD[b * 64 + c] - mD[b * 64 + c] * sc;
    }
  }
}

// One-dispatch linked-list build for ALL 4 levels (independent lists).
__global__ __launch_bounds__(256) void k_fill_all(
    const int* __restrict__ inv2, const int* __restrict__ inv4,
    const int* __restrict__ inv8, const int* __restrict__ inv16,
    int* hd2, int* hd3, int* hd4, int* hd5,
    int* nx1, int* nx2, int* nx3, int* nx4) {
  int i = blockIdx.x * 256 + threadIdx.x;
  if (i < N1) { nx1[i] = atomicExch(&hd2[inv2[i]], i); return; }
  i -= N1;
  if (i < N2) { nx2[i] = atomicExch(&hd3[inv4[i]], i); return; }
  i -= N2;
  if (i < N4) { nx3[i] = atomicExch(&hd4[inv8[i]], i); return; }
  i -= N4;
  if (i < N8) { nx4[i] = atomicExch(&hd5[inv16[i]], i); return; }
}

// ---------------- MFMA GEMM kernels (fp16 intermediate storage) -------------
// Block = 256 thr (4 waves); tile 64 rows; wave w owns rows 16w..16w+15.
// A: LDS [64 rows][36 u32]; lane l: row 16w+(l&15), k=(l>>4)*8..+7.
// B: fragment-linear packed buffers; D: row=16w+(l>>4)*4+reg, col=ct*16+(l&15).

// encoder block 0: x[9] -> h[32] (fp32 K=9) -> outH[64] fp16 (MFMA K=32)
__global__ __launch_bounds__(256) void k_enc0_m(
    const float* __restrict__ x,
    const float* __restrict__ W1, const float* __restrict__ b1,
    const float* __restrict__ fold,
    const unsigned* __restrict__ F2, const float* __restrict__ b2,
    unsigned* __restrict__ outH, int n) {
  __shared__ float xS[64 * 9];
  __shared__ unsigned hP[64 * 20];
  __shared__ _Float16 oH[64 * 72];
  int t = threadIdx.x;
  int lane = t & 63;
  int w = __builtin_amdgcn_readfirstlane(t >> 6);
  int R = blockIdx.x * 64;
  int l15 = lane & 15, lg = lane >> 4;

  {
    size_t lim = (size_t)n * 9 - 1;
    for (int i = t; i < 576; i += 256) {
      size_t gi = (size_t)R * 9 + i;
      if (gi > lim) gi = lim;
      xS[i] = x[gi];
    }
  }
  __syncthreads();

  {
    const float* W1p = W1 + w * 8;
    float xr[9];
#pragma unroll
    for (int k = 0; k < 9; ++k) xr[k] = xS[lane * 9 + k];
    float acc[8];
#pragma unroll
    for (int c = 0; c < 8; ++c) acc[c] = b1[w * 8 + c];
#pragma unroll
    for (int k = 0; k < 9; ++k) {
#pragma unroll
      for (int c = 0; c < 8; ++c) acc[c] = fmaf(xr[k], W1p[k * 32 + c], acc[c]);
    }
    float v[8];
#pragma unroll
    for (int c = 0; c < 8; ++c)
      v[c] = lrelu(acc[c]) * fold[w * 8 + c] + fold[32 + w * 8 + c];
#pragma unroll
    for (int j = 0; j < 4; ++j)
      hP[lane * 20 + w * 4 + j] = pk(v[2 * j], v[2 * j + 1]);
  }
  __syncthreads();

  {
    int arow = 16 * w + l15;
    h8 a = uph8(*(const uint4*)(hP + arow * 20 + lg * 4));
#pragma unroll
    for (int ct = 0; ct < 4; ++ct) {
      h8 b = uph8(*(const uint4*)(F2 + (ct * 64 + lane) * 4));
      f4 c = {0.f, 0.f, 0.f, 0.f};
      c = __builtin_amdgcn_mfma_f32_16x16x32_f16(a, b, c, 0, 0, 0);
      int col = ct * 16 + l15;
      float bias = b2[col];
#pragma unroll
      for (int r = 0; r < 4; ++r)
        oH[(16 * w + lg * 4 + r) * 72 + col] = (_Float16)lrelu(c[r] + bias);
    }
  }
  __syncthreads();
  for (int f = t; f < 2048; f += 256) {
    int row = f >> 5, i = f & 31;
    int gr = R + row;
    if (gr < n) outH[(size_t)gr * 32 + i] = ((unsigned*)oH)[row * 36 + i];
  }
}

// encoder blocks 1..4 with fused segment-max pooling (chain-walk staging).
__global__ __launch_bounds__(256) void k_encR_m(
    const unsigned* __restrict__ srcH, const int* __restrict__ head,
    const int* __restrict__ nxt,
    const unsigned* __restrict__ F1, const float* __restrict__ b1,
    const float* __restrict__ fold,
    const unsigned* __restrict__ F2, const float* __restrict__ b2,
    unsigned* __restrict__ outH, int n) {
  __shared__ unsigned P[64 * 36];
  __shared__ unsigned hP[64 * 20];
  __shared__ _Float16 oH[64 * 72];
  int t = threadIdx.x;
  int lane = t & 63;
  int w = __builtin_amdgcn_readfirstlane(t >> 6);
  int R = blockIdx.x * 64;
  int l15 = lane & 15, lg = lane >> 4;
  _Float16* Hh = (_Float16*)hP;

  for (int f = t; f < 2048; f += 256) {
    int row = f >> 5, i = f & 31;
    int seg = R + row;
    unsigned ov = 0u;
    if (seg < n) {
      float m0 = -INFINITY, m1 = -INFINITY;
      for (int p = head[seg]; p >= 0; p = nxt[p]) {
        h2 v = uph(srcH[(size_t)p * 32 + i]);
        m0 = fmaxf(m0, (float)v.x);
        m1 = fmaxf(m1, (float)v.y);
      }
      if (m0 == -INFINITY) m0 = 0.0f;
      if (m1 == -INFINITY) m1 = 0.0f;
      ov = pk(m0, m1);
    }
    P[row * 36 + i] = ov;
  }
  __syncthreads();

  int arow = 16 * w + l15;

  {
    h8 a0 = uph8(*(const uint4*)(P + arow * 36 + 0 * 16 + lg * 4));
    h8 a1 = uph8(*(const uint4*)(P + arow * 36 + 1 * 16 + lg * 4));
#pragma unroll
    for (int ct = 0; ct < 2; ++ct) {
      h8 b0 = uph8(*(const uint4*)(F1 + ((ct * 2 + 0) * 64 + lane) * 4));
      h8 b1v = uph8(*(const uint4*)(F1 + ((ct * 2 + 1) * 64 + lane) * 4));
      f4 c = {0.f, 0.f, 0.f, 0.f};
      c = __builtin_amdgcn_mfma_f32_16x16x32_f16(a0, b0, c, 0, 0, 0);
      c = __builtin_amdgcn_mfma_f32_16x16x32_f16(a1, b1v, c, 0, 0, 0);
      int col = ct * 16 + l15;
      float bias = b1[col], sc = fold[col], sh = fold[32 + col];
#pragma unroll
      for (int r = 0; r < 4; ++r) {
        int row = 16 * w + lg * 4 + r;
        Hh[row * 40 + col] = (_Float16)(lrelu(c[r] + bias) * sc + sh);
      }
    }
  }
  __syncthreads();

  {
    h8 a = uph8(*(const uint4*)(hP + arow * 20 + lg * 4));
#pragma unroll
    for (int ct = 0; ct < 4; ++ct) {
      h8 b = uph8(*(const uint4*)(F2 + (ct * 64 + lane) * 4));
      f4 c = {0.f, 0.f, 0.f, 0.f};
      c = __builtin_amdgcn_mfma_f32_16x16x32_f16(a, b, c, 0, 0, 0);
      int col = ct * 16 + l15;
      float bias = b2[col];
#pragma unroll
      for (int r = 0; r < 4; ++r)
        oH[(16 * w + lg * 4 + r) * 72 + col] = (_Float16)lrelu(c[r] + bias);
    }
  }
  __syncthreads();
  for (int f = t; f < 2048; f += 256) {
    int row = f >> 5, i = f & 31;
    int gr = R + row;
    if (gr < n) outH[(size_t)gr * 32 + i] = ((unsigned*)oH)[row * 36 + i];
  }
}

// lastT = srcH @ decW_bot + decb  (seed, MFMA K=64, fp16 out)
__global__ __launch_bounds__(256) void k_lastT_m(
    const unsigned* __restrict__ srcH, const unsigned* __restrict__ Fbot,
    const float* __restrict__ decb, _Float16* __restrict__ lT, int n) {
  __shared__ unsigned P[64 * 36];
  int t = threadIdx.x;
  int lane = t & 63;
  int w = __builtin_amdgcn_readfirstlane(t >> 6);
  int R = blockIdx.x * 64;
  int l15 = lane & 15, lg = lane >> 4;

  for (int f = t; f < 2048; f += 256) {
    int row = f >> 5, i = f & 31;
    int gr = R + row; if (gr >= n) gr = n - 1;
    P[row * 36 + i] = srcH[(size_t)gr * 32 + i];
  }
  __syncthreads();

  int arow = 16 * w + l15;
  h8 a0 = uph8(*(const uint4*)(P + arow * 36 + 0 * 16 + lg * 4));
  h8 a1 = uph8(*(const uint4*)(P + arow * 36 + 1 * 16 + lg * 4));

#pragma unroll
  for (int ct = 0; ct < 4; ++ct) {
    h8 b0 = uph8(*(const uint4*)(Fbot + ((ct * 2 + 0) * 64 + lane) * 4));
    h8 b1 = uph8(*(const uint4*)(Fbot + ((ct * 2 + 1) * 64 + lane) * 4));
    f4 c = {0.f, 0.f, 0.f, 0.f};
    c = __builtin_amdgcn_mfma_f32_16x16x32_f16(a0, b0, c, 0, 0, 0);
    c = __builtin_amdgcn_mfma_f32_16x16x32_f16(a1, b1, c, 0, 0, 0);
    int col = ct * 16 + l15;
    float bias = decb[col];
#pragma unroll
    for (int r = 0; r < 4; ++r) {
      int grow = R + 16 * w + lg * 4 + r;
      if (grow < n) lT[(size_t)grow * 64 + col] = (_Float16)(c[r] + bias);
    }
  }
}

// decoder: outF = lrelu(BN(lrelu(curH@mlp) @ decTop + lT[lrow])) (fp32 final,
// LDS-staged coalesced float4 stores); optional phase 3: lTout (fp16).
__global__ __launch_bounds__(256) void k_dec2_m(
    const unsigned* __restrict__ curH, float* __restrict__ outF,
    const _Float16* __restrict__ lT, const int* __restrict__ idx,
    const unsigned* __restrict__ Fmlp, const float* __restrict__ mlpb,
    const unsigned* __restrict__ Ftop, const float* __restrict__ fold, int n,
    const unsigned* __restrict__ FnextBot, const float* __restrict__ decbN,
    _Float16* __restrict__ lTout) {
  __shared__ unsigned P[64 * 36];
  __shared__ float oF[64 * 68];
  int t = threadIdx.x;
  int lane = t & 63;
  int w = __builtin_amdgcn_readfirstlane(t >> 6);
  int R = blockIdx.x * 64;
  int l15 = lane & 15, lg = lane >> 4;
  _Float16* H = (_Float16*)P;

  for (int f = t; f < 2048; f += 256) {
    int row = f >> 5, i = f & 31;
    int gr = R + row; if (gr >= n) gr = n - 1;
    P[row * 36 + i] = curH[(size_t)gr * 32 + i];
  }

  int grow_[4], gidx_[4];
#pragma unroll
  for (int r = 0; r < 4; ++r) {
    grow_[r] = R + 16 * w + lg * 4 + r;
    int gcl = grow_[r] >= n ? n - 1 : grow_[r];
    gidx_[r] = idx ? idx[gcl] : gcl;
  }
  float lv[4][4];  // [r][ct]
#pragma unroll
  for (int r = 0; r < 4; ++r) {
#pragma unroll
    for (int ct = 0; ct < 4; ++ct)
      lv[r][ct] = (float)lT[(size_t)gidx_[r] * 64 + ct * 16 + l15];
  }
  __syncthreads();

  int arow = 16 * w + l15;

  // phase 1: skip = lrelu(cur @ mlpW + mlpb)
  float sk[4][4];
  {
    h8 a0 = uph8(*(const uint4*)(P + arow * 36 + 0 * 16 + lg * 4));
    h8 a1 = uph8(*(const uint4*)(P + arow * 36 + 1 * 16 + lg * 4));
#pragma unroll
    for (int ct = 0; ct < 4; ++ct) {
      h8 b0 = uph8(*(const uint4*)(Fmlp + ((ct * 2 + 0) * 64 + lane) * 4));
      h8 b1 = uph8(*(const uint4*)(Fmlp + ((ct * 2 + 1) * 64 + lane) * 4));
      f4 c = {0.f, 0.f, 0.f, 0.f};
      c = __builtin_amdgcn_mfma_f32_16x16x32_f16(a0, b0, c, 0, 0, 0);
      c = __builtin_amdgcn_mfma_f32_16x16x32_f16(a1, b1, c, 0, 0, 0);
      float bias = mlpb[ct * 16 + l15];
#pragma unroll
      for (int r = 0; r < 4; ++r) sk[ct][r] = lrelu(c[r] + bias);
    }
  }
  __syncthreads();
#pragma unroll
  for (int ct = 0; ct < 4; ++ct) {
#pragma unroll
    for (int r = 0; r < 4; ++r)
      H[(16 * w + lg * 4 + r) * 72 + ct * 16 + l15] = (_Float16)sk[ct][r];
  }
  __syncthreads();

  // phase 2: out = skip @ decTop + lT, BN, lrelu -> oF (LDS)
  float fv[4][4];
  {
    h8 a0 = uph8(*(const uint4*)(P + arow * 36 + 0 * 16 + lg * 4));
    h8 a1 = uph8(*(const uint4*)(P + arow * 36 + 1 * 16 + lg * 4));
#pragma unroll
    for (int ct = 0; ct < 4; ++ct) {
      h8 b0 = uph8(*(const uint4*)(Ftop + ((ct * 2 + 0) * 64 + lane) * 4));
      h8 b1 = uph8(*(const uint4*)(Ftop + ((ct * 2 + 1) * 64 + lane) * 4));
      f4 c = {0.f, 0.f, 0.f, 0.f};
      c = __builtin_amdgcn_mfma_f32_16x16x32_f16(a0, b0, c, 0, 0, 0);
      c = __builtin_amdgcn_mfma_f32_16x16x32_f16(a1, b1, c, 0, 0, 0);
      int col = ct * 16 + l15;
      float sc = fold[col], sh = fold[64 + col];
#pragma unroll
      for (int r = 0; r < 4; ++r) {
        float ov = (c[r] + lv[r][ct]) * sc + sh;
        fv[ct][r] = lrelu(ov);
        oF[(16 * w + lg * 4 + r) * 68 + col] = fv[ct][r];
      }
    }
  }
  __syncthreads();
  // coalesced fp32 final store (256B-contiguous float4 per 16 lanes)
  for (int f = t; f < 1024; f += 256) {
    int row = f >> 4, c4 = (f & 15) << 2;
    int gr = R + row;
    if (gr < n)
      *(float4*)(outF + (size_t)gr * 64 + c4) = *(const float4*)(oF + row * 68 + c4);
  }

  // phase 3 (optional): lTout = out @ decNextBot + decbN (fp16)
  if (FnextBot) {
    __syncthreads();
#pragma unroll
    for (int ct = 0; ct < 4; ++ct) {
#pragma unroll
      for (int r = 0; r < 4; ++r)
        H[(16 * w + lg * 4 + r) * 72 + ct * 16 + l15] = (_Float16)fv[ct][r];
    }
    __syncthreads();
    h8 a0 = uph8(*(const uint4*)(P + arow * 36 + 0 * 16 + lg * 4));
    h8 a1 = uph8(*(const uint4*)(P + arow * 36 + 1 * 16 + lg * 4));
#pragma unroll
    for (int ct = 0; ct < 4; ++ct) {
      h8 b0 = uph8(*(const uint4*)(FnextBot + ((ct * 2 + 0) * 64 + lane) * 4));
      h8 b1 = uph8(*(const uint4*)(FnextBot + ((ct * 2 + 1) * 64 + lane) * 4));
      f4 c = {0.f, 0.f, 0.f, 0.f};
      c = __builtin_amdgcn_mfma_f32_16x16x32_f16(a0, b0, c, 0, 0, 0);
      c = __builtin_amdgcn_mfma_f32_16x16x32_f16(a1, b1, c, 0, 0, 0);
      int col = ct * 16 + l15;
      float bias = decbN[col];
#pragma unroll
      for (int r = 0; r < 4; ++r)
        if (grow_[r] < n) lTout[(size_t)grow_[r] * 64 + col] = (_Float16)(c[r] + bias);
    }
  }
}

extern "C" void kernel_launch(void* const* d_in, const int* in_sizes, int n_in,
                              void* d_out, int out_size, void* d_ws, size_t ws_size,
                              hipStream_t stream) {
  const float* pt   = (const float*)d_in[0];
  const int* inv2   = (const int*)d_in[1];
  const int* inv4   = (const int*)d_in[2];
  const int* inv8   = (const int*)d_in[3];
  const int* inv16  = (const int*)d_in[4];
  const float* e0W1 = (const float*)d_in[5];
  const float* e0b1 = (const float*)d_in[6];
  const float* e0g  = (const float*)d_in[7];
  const float* e0be = (const float*)d_in[8];
  const float* e0m  = (const float*)d_in[9];
  const float* e0v  = (const float*)d_in[10];
  const float* e0W2 = (const float*)d_in[11];
  const float* e0b2 = (const float*)d_in[12];
  const float* eRW1 = (const float*)d_in[13];
  const float* eRb1 = (const float*)d_in[14];
  const float* eRg  = (const float*)d_in[15];
  const float* eRbe = (const float*)d_in[16];
  const float* eRm  = (const float*)d_in[17];
  const float* eRv  = (const float*)d_in[18];
  const float* eRW2 = (const float*)d_in[19];
  const float* eRb2 = (const float*)d_in[20];
  const float* mlpW = (const float*)d_in[21];
  const float* mlpb = (const float*)d_in[22];
  const float* decW = (const float*)d_in[23];
  const float* decb = (const float*)d_in[24];
  const float* decg = (const float*)d_in[25];
  const float* decbe= (const float*)d_in[26];
  const float* decm = (const float*)d_in[27];
  const float* decv = (const float*)d_in[28];

  float* s1 = (float*)d_out;
  float* s2 = s1 + (size_t)N1 * 64;
  float* s3 = s2 + (size_t)N2 * 64;
  float* s4 = s3 + (size_t)N4 * 64;
  float* s5 = s4 + (size_t)N8 * 64;

  // ws: fold | frag packs | pH1..pH5 | lTA | lTB | heads (contig) | nxts
  float* fold = (float*)d_ws;
  unsigned* F_e0W2 = (unsigned*)(fold + 1024);   // 1024 u
  unsigned* F_eRW1 = F_e0W2 + 1024;              // 4096 u
  unsigned* F_eRW2 = F_eRW1 + 4096;              // 4096 u
  unsigned* F_mlp  = F_eRW2 + 4096;              // 10240 u
  unsigned* F_top  = F_mlp + 10240;              // 10240 u
  unsigned* F_bot  = F_top + 10240;              // 10240 u
  unsigned* pH1 = F_bot + 10240;                 // N1*32 u
  unsigned* pH2 = pH1 + (size_t)N1 * 32;         // N2*32 u
  unsigned* pH3 = pH2 + (size_t)N2 * 32;         // N4*32 u
  unsigned* pH4 = pH3 + (size_t)N4 * 32;         // N8*32 u
  unsigned* pH5 = pH4 + (size_t)N8 * 32;         // N16*32 u
  _Float16* lTA = (_Float16*)(pH5 + (size_t)N16 * 32);  // N2*64 h
  _Float16* lTB = lTA + (size_t)N2 * 64;                // N4*64 h
  int* hd2 = (int*)(lTB + (size_t)N4 * 64);      // N2
  int* hd3 = hd2 + N2;                           // N4
  int* hd4 = hd3 + N4;                           // N8
  int* hd5 = hd4 + N8;                           // N16
  int* nx1 = hd5 + N16;                          // N1
  int* nx2 = nx1 + N1;                           // N2
  int* nx3 = nx2 + N2;                           // N4
  int* nx4 = nx3 + N4;                           // N8

  k_prep<<<(40256 + 255) / 256, 256, 0, stream>>>(
      e0W2, eRW1, eRW2, mlpW, decW,
      e0g, e0be, e0m, e0v, eRg, eRbe, eRm, eRv, decg, decbe, decm, decv,
      fold, F_e0W2, F_eRW1, F_eRW2, F_mlp, F_top, F_bot);

  hipMemsetAsync(hd2, 0xFF, (size_t)(N2 + N4 + N8 + N16) * 4, stream);
  k_fill_all<<<(N1 + N2 + N4 + N8 + 255) / 256, 256, 0, stream>>>(
      inv2, inv4, inv8, inv16, hd2, hd3, hd4, hd5, nx1, nx2, nx3, nx4);

  // ---- encoders (fused pooling) ----
  k_enc0_m<<<(N1 + 63) / 64, 256, 0, stream>>>(pt, e0W1, e0b1, fold, F_e0W2, e0b2, pH1, N1);
  k_encR_m<<<(N2 + 63) / 64, 256, 0, stream>>>(pH1, hd2, nx1,
                                               F_eRW1 + 0 * 1024, eRb1 + 0 * 32,
                                               fold + 64 + 0 * 64, F_eRW2 + 0 * 1024,
                                               eRb2 + 0 * 64, pH2, N2);
  k_encR_m<<<(N4 + 63) / 64, 256, 0, stream>>>(pH2, hd3, nx2,
                                               F_eRW1 + 1 * 1024, eRb1 + 1 * 32,
                                               fold + 64 + 1 * 64, F_eRW2 + 1 * 1024,
                                               eRb2 + 1 * 64, pH3, N4);
  k_encR_m<<<(N8 + 63) / 64, 256, 0, stream>>>(pH3, hd4, nx3,
                                               F_eRW1 + 2 * 1024, eRb1 + 2 * 32,
                                               fold + 64 + 2 * 64, F_eRW2 + 2 * 1024,
                                               eRb2 + 2 * 64, pH4, N8);
  k_encR_m<<<(N16 + 63) / 64, 256, 0, stream>>>(pH4, hd5, nx4,
                                                F_eRW1 + 3 * 1024, eRb1 + 3 * 32,
                                                fold + 64 + 3 * 64, F_eRW2 + 3 * 1024,
                                                eRb2 + 3 * 64, pH5, N16);

  // ---- decoders (MFMA, fp16 in / fp32 out staged) with fused lastT ----
  k_lastT_m<<<(N16 + 63) / 64, 256, 0, stream>>>(pH5, F_bot + 0 * 2048, decb + 0 * 64,
                                                 lTA, N16);
  k_dec2_m<<<(N16 + 63) / 64, 256, 0, stream>>>(pH5, s5, lTA, nullptr,
                                                F_mlp + 0 * 2048, mlpb + 0 * 64,
                                                F_top + 0 * 2048, fold + 320 + 0 * 128, N16,
                                                F_bot + 1 * 2048, decb + 1 * 64, lTB);
  k_dec2_m<<<(N8 + 63) / 64, 256, 0, stream>>>(pH4, s4, lTB, inv16,
                                               F_mlp + 1 * 2048, mlpb + 1 * 64,
                                               F_top + 1 * 2048, fold + 320 + 1 * 128, N8,
                                               F_bot + 2 * 2048, decb + 2 * 64, lTA);
  k_dec2_m<<<(N4 + 63) / 64, 256, 0, stream>>>(pH3, s3, lTA, inv8,
                                               F_mlp + 2 * 2048, mlpb + 2 * 64,
                                               F_top + 2 * 2048, fold + 320 + 2 * 128, N4,
                                               F_bot + 3 * 2048, decb + 3 * 64, lTB);
  k_dec2_m<<<(N2 + 63) / 64, 256, 0, stream>>>(pH2, s2, lTB, inv4,
                                               F_mlp + 3 * 2048, mlpb + 3 * 64,
                                               F_top + 3 * 2048, fold + 320 + 3 * 128, N2,
                                               F_bot + 4 * 2048, decb + 4 * 64, lTA);
  k_dec2_m<<<(N1 + 63) / 64, 256, 0, stream>>>(pH1, s1, lTA, inv2,
                                               F_mlp + 4 * 2048, mlpb + 4 * 64,
                                               F_top + 4 * 2048, fold + 320 + 4 * 128, N1,
                                               nullptr, nullptr, nullptr);
}

// Round 24
// 543.374 us; speedup vs baseline: 4.6368x; 1.0223x over previous
//
#include <hip/hip_runtime.h>

#define N1 1000000
#define N2 400000
#define N4 150000
#define N8 60000
#define N16 20000

constexpr float BN_EPS = 1e-5f;

typedef _Float16 h2 __attribute__((ext_vector_type(2)));
typedef _Float16 h8 __attribute__((ext_vector_type(8)));
typedef float f4 __attribute__((ext_vector_type(4)));

__device__ __forceinline__ float lrelu(float x) { return fmaxf(x, 0.1f * x); }

__device__ __forceinline__ unsigned pk(float x, float y) {
  h2 h = {(_Float16)x, (_Float16)y};
  unsigned u;
  __builtin_memcpy(&u, &h, 4);
  return u;
}
__device__ __forceinline__ h2 uph(unsigned u) {
  h2 h;
  __builtin_memcpy(&h, &u, 4);
  return h;
}
__device__ __forceinline__ h8 uph8(uint4 u) {
  h8 h;
  __builtin_memcpy(&h, &u, 16);
  return h;
}

__device__ __forceinline__ void packB_one(const float* __restrict__ W,
                                          unsigned* __restrict__ d,
                                          int C, int KT, int i) {
  int q = i & 3, l = (i >> 2) & 63;
  int rest = i >> 8;
  int t = rest % KT, ct = rest / KT;
  int col = ct * 16 + (l & 15);
  int k0 = t * 32 + ((l >> 4) << 3) + 2 * q;
  d[i] = pk(W[k0 * C + col], W[(k0 + 1) * C + col]);
}

// One-dispatch prep: all MFMA B-fragment packs + BN folds (flat job index).
__global__ __launch_bounds__(256) void k_prep(
    const float* e0W2, const float* eRW1, const float* eRW2,
    const float* mlpW, const float* decW,
    const float* g0, const float* be0, const float* m0, const float* v0,
    const float* gR, const float* beR, const float* mR, const float* vR,
    const float* gD, const float* beD, const float* mD, const float* vD,
    float* fold,
    unsigned* F_e0W2, unsigned* F_eRW1, unsigned* F_eRW2,
    unsigned* F_mlp, unsigned* F_top, unsigned* F_bot) {
  int g = blockIdx.x * 256 + threadIdx.x;
  if (g < 1024) { packB_one(e0W2, F_e0W2, 64, 1, g); return; }
  g -= 1024;
  if (g < 4096) {
    int i = g & 1023, m = g >> 10;
    packB_one(eRW1 + m * 2048, F_eRW1 + m * 1024, 32, 2, i); return;
  }
  g -= 4096;
  if (g < 4096) {
    int i = g & 1023, m = g >> 10;
    packB_one(eRW2 + m * 2048, F_eRW2 + m * 1024, 64, 1, i); return;
  }
  g -= 4096;
  if (g < 10240) {
    int i = g & 2047, m = g >> 11;
    packB_one(mlpW + m * 4096, F_mlp + m * 2048, 64, 2, i); return;
  }
  g -= 10240;
  if (g < 10240) {
    int i = g & 2047, m = g >> 11;
    packB_one(decW + m * 8192, F_top + m * 2048, 64, 2, i); return;
  }
  g -= 10240;
  if (g < 10240) {
    int i = g & 2047, m = g >> 11;
    packB_one(decW + m * 8192 + 4096, F_bot + m * 2048, 64, 2, i); return;
  }
  g -= 10240;
  if (g < 320) {
    int t = g;
    if (t < 32) {
      float sc = g0[t] * rsqrtf(v0[t] + BN_EPS);
      fold[t] = sc;
      fold[32 + t] = be0[t] - m0[t] * sc;
    }
    if (t < 128) {
      int b = t >> 5, c = t & 31;
      float sc = gR[b * 32 + c] * rsqrtf(vR[b * 32 + c] + BN_EPS);
      fold[64 + b * 64 + c] = sc;
      fold[64 + b * 64 + 32 + c] = beR[b * 32 + c] - mR[b * 32 + c] * sc;
    }
    {
      int b = t >> 6, c = t & 63;
      float sc = gD[b * 64 + c] * rsqrtf(vD[b * 64 + c] + BN_EPS);
      fold[320 + b * 128 + c] = sc;
      fold[320 + b * 128 + 64 + c] = beD[b * 64 + c] - mD[b * 64 + c] * sc;
    }
  }
}

// One-dispatch linked-list build for ALL 4 levels (independent lists).
__global__ __launch_bounds__(256) void k_fill_all(
    const int* __restrict__ inv2, const int* __restrict__ inv4,
    const int* __restrict__ inv8, const int* __restrict__ inv16,
    int* hd2, int* hd3, int* hd4, int* hd5,
    int* nx1, int* nx2, int* nx3, int* nx4) {
  int i = blockIdx.x * 256 + threadIdx.x;
  if (i < N1) { nx1[i] = atomicExch(&hd2[inv2[i]], i); return; }
  i -= N1;
  if (i < N2) { nx2[i] = atomicExch(&hd3[inv4[i]], i); return; }
  i -= N2;
  if (i < N4) { nx3[i] = atomicExch(&hd4[inv8[i]], i); return; }
  i -= N4;
  if (i < N8) { nx4[i] = atomicExch(&hd5[inv16[i]], i); return; }
}

// ---------------- MFMA GEMM kernels (fp16 intermediate storage) -------------
// Block = 256 thr (4 waves); tile 64 rows; wave w owns rows 16w..16w+15.
// A: LDS [64 rows][36 u32]; lane l: row 16w+(l&15), k=(l>>4)*8..+7.
// B: fragment-linear packed buffers; D: row=16w+(l>>4)*4+reg, col=ct*16+(l&15).

// encoder block 0: x[9] -> h[32] (fp32 K=9) -> outH[64] fp16 (MFMA K=32)
__global__ __launch_bounds__(256) void k_enc0_m(
    const float* __restrict__ x,
    const float* __restrict__ W1, const float* __restrict__ b1,
    const float* __restrict__ fold,
    const unsigned* __restrict__ F2, const float* __restrict__ b2,
    unsigned* __restrict__ outH, int n) {
  __shared__ float xS[64 * 9];
  __shared__ unsigned hP[64 * 20];
  __shared__ _Float16 oH[64 * 72];
  int t = threadIdx.x;
  int lane = t & 63;
  int w = __builtin_amdgcn_readfirstlane(t >> 6);
  int R = blockIdx.x * 64;
  int l15 = lane & 15, lg = lane >> 4;

  {
    size_t lim = (size_t)n * 9 - 1;
    for (int i = t; i < 576; i += 256) {
      size_t gi = (size_t)R * 9 + i;
      if (gi > lim) gi = lim;
      xS[i] = x[gi];
    }
  }
  __syncthreads();

  {
    const float* W1p = W1 + w * 8;
    float xr[9];
#pragma unroll
    for (int k = 0; k < 9; ++k) xr[k] = xS[lane * 9 + k];
    float acc[8];
#pragma unroll
    for (int c = 0; c < 8; ++c) acc[c] = b1[w * 8 + c];
#pragma unroll
    for (int k = 0; k < 9; ++k) {
#pragma unroll
      for (int c = 0; c < 8; ++c) acc[c] = fmaf(xr[k], W1p[k * 32 + c], acc[c]);
    }
    float v[8];
#pragma unroll
    for (int c = 0; c < 8; ++c)
      v[c] = lrelu(acc[c]) * fold[w * 8 + c] + fold[32 + w * 8 + c];
#pragma unroll
    for (int j = 0; j < 4; ++j)
      hP[lane * 20 + w * 4 + j] = pk(v[2 * j], v[2 * j + 1]);
  }
  __syncthreads();

  {
    int arow = 16 * w + l15;
    h8 a = uph8(*(const uint4*)(hP + arow * 20 + lg * 4));
#pragma unroll
    for (int ct = 0; ct < 4; ++ct) {
      h8 b = uph8(*(const uint4*)(F2 + (ct * 64 + lane) * 4));
      f4 c = {0.f, 0.f, 0.f, 0.f};
      c = __builtin_amdgcn_mfma_f32_16x16x32_f16(a, b, c, 0, 0, 0);
      int col = ct * 16 + l15;
      float bias = b2[col];
#pragma unroll
      for (int r = 0; r < 4; ++r)
        oH[(16 * w + lg * 4 + r) * 72 + col] = (_Float16)lrelu(c[r] + bias);
    }
  }
  __syncthreads();
  for (int f = t; f < 2048; f += 256) {
    int row = f >> 5, i = f & 31;
    int gr = R + row;
    if (gr < n) outH[(size_t)gr * 32 + i] = ((unsigned*)oH)[row * 36 + i];
  }
}

// encoder blocks 1..4 with fused segment-max pooling (chain-walk staging).
__global__ __launch_bounds__(256) void k_encR_m(
    const unsigned* __restrict__ srcH, const int* __restrict__ head,
    const int* __restrict__ nxt,
    const unsigned* __restrict__ F1, const float* __restrict__ b1,
    const float* __restrict__ fold,
    const unsigned* __restrict__ F2, const float* __restrict__ b2,
    unsigned* __restrict__ outH, int n) {
  __shared__ unsigned P[64 * 36];
  __shared__ unsigned hP[64 * 20];
  __shared__ _Float16 oH[64 * 72];
  int t = threadIdx.x;
  int lane = t & 63;
  int w = __builtin_amdgcn_readfirstlane(t >> 6);
  int R = blockIdx.x * 64;
  int l15 = lane & 15, lg = lane >> 4;
  _Float16* Hh = (_Float16*)hP;

  for (int f = t; f < 2048; f += 256) {
    int row = f >> 5, i = f & 31;
    int seg = R + row;
    unsigned ov = 0u;
    if (seg < n) {
      float m0 = -INFINITY, m1 = -INFINITY;
      for (int p = head[seg]; p >= 0; p = nxt[p]) {
        h2 v = uph(srcH[(size_t)p * 32 + i]);
        m0 = fmaxf(m0, (float)v.x);
        m1 = fmaxf(m1, (float)v.y);
      }
      if (m0 == -INFINITY) m0 = 0.0f;
      if (m1 == -INFINITY) m1 = 0.0f;
      ov = pk(m0, m1);
    }
    P[row * 36 + i] = ov;
  }
  __syncthreads();

  int arow = 16 * w + l15;

  {
    h8 a0 = uph8(*(const uint4*)(P + arow * 36 + 0 * 16 + lg * 4));
    h8 a1 = uph8(*(const uint4*)(P + arow * 36 + 1 * 16 + lg * 4));
#pragma unroll
    for (int ct = 0; ct < 2; ++ct) {
      h8 b0 = uph8(*(const uint4*)(F1 + ((ct * 2 + 0) * 64 + lane) * 4));
      h8 b1v = uph8(*(const uint4*)(F1 + ((ct * 2 + 1) * 64 + lane) * 4));
      f4 c = {0.f, 0.f, 0.f, 0.f};
      c = __builtin_amdgcn_mfma_f32_16x16x32_f16(a0, b0, c, 0, 0, 0);
      c = __builtin_amdgcn_mfma_f32_16x16x32_f16(a1, b1v, c, 0, 0, 0);
      int col = ct * 16 + l15;
      float bias = b1[col], sc = fold[col], sh = fold[32 + col];
#pragma unroll
      for (int r = 0; r < 4; ++r) {
        int row = 16 * w + lg * 4 + r;
        Hh[row * 40 + col] = (_Float16)(lrelu(c[r] + bias) * sc + sh);
      }
    }
  }
  __syncthreads();

  {
    h8 a = uph8(*(const uint4*)(hP + arow * 20 + lg * 4));
#pragma unroll
    for (int ct = 0; ct < 4; ++ct) {
      h8 b = uph8(*(const uint4*)(F2 + (ct * 64 + lane) * 4));
      f4 c = {0.f, 0.f, 0.f, 0.f};
      c = __builtin_amdgcn_mfma_f32_16x16x32_f16(a, b, c, 0, 0, 0);
      int col = ct * 16 + l15;
      float bias = b2[col];
#pragma unroll
      for (int r = 0; r < 4; ++r)
        oH[(16 * w + lg * 4 + r) * 72 + col] = (_Float16)lrelu(c[r] + bias);
    }
  }
  __syncthreads();
  for (int f = t; f < 2048; f += 256) {
    int row = f >> 5, i = f & 31;
    int gr = R + row;
    if (gr < n) outH[(size_t)gr * 32 + i] = ((unsigned*)oH)[row * 36 + i];
  }
}

// decoder: outF = lrelu(BN(lrelu(curH@mlp) @ decTop + last)) (fp32, LDS-staged
// nontemporal stores). `last` comes from lT[idx[row]] (fp16 gather) OR, when
// FbotSelf != null (level 0, identity gather), computed in-kernel as phase 0:
// last = curH @ FbotSelf + decbSelf. Optional phase 3: lTout (fp16).
__global__ __launch_bounds__(256) void k_dec2_m(
    const unsigned* __restrict__ curH, float* __restrict__ outF,
    const _Float16* __restrict__ lT, const int* __restrict__ idx,
    const unsigned* __restrict__ FbotSelf, const float* __restrict__ decbSelf,
    const unsigned* __restrict__ Fmlp, const float* __restrict__ mlpb,
    const unsigned* __restrict__ Ftop, const float* __restrict__ fold, int n,
    const unsigned* __restrict__ FnextBot, const float* __restrict__ decbN,
    _Float16* __restrict__ lTout) {
  __shared__ unsigned P[64 * 36];
  __shared__ float oF[64 * 68];
  int t = threadIdx.x;
  int lane = t & 63;
  int w = __builtin_amdgcn_readfirstlane(t >> 6);
  int R = blockIdx.x * 64;
  int l15 = lane & 15, lg = lane >> 4;
  _Float16* H = (_Float16*)P;

  for (int f = t; f < 2048; f += 256) {
    int row = f >> 5, i = f & 31;
    int gr = R + row; if (gr >= n) gr = n - 1;
    P[row * 36 + i] = curH[(size_t)gr * 32 + i];
  }

  int grow_[4];
#pragma unroll
  for (int r = 0; r < 4; ++r) grow_[r] = R + 16 * w + lg * 4 + r;

  float lv[4][4];  // [r][ct]
  if (!FbotSelf) {
    // gathered lastT from previous level (random rows, L3-served)
#pragma unroll
    for (int r = 0; r < 4; ++r) {
      int gcl = grow_[r] >= n ? n - 1 : grow_[r];
      int gi = idx ? idx[gcl] : gcl;
#pragma unroll
      for (int ct = 0; ct < 4; ++ct)
        lv[r][ct] = (float)lT[(size_t)gi * 64 + ct * 16 + l15];
    }
  }
  __syncthreads();

  int arow = 16 * w + l15;
  h8 a0c = uph8(*(const uint4*)(P + arow * 36 + 0 * 16 + lg * 4));
  h8 a1c = uph8(*(const uint4*)(P + arow * 36 + 1 * 16 + lg * 4));

  // phase 0 (level 0 only): last = cur @ decW_bot + decb for own rows
  if (FbotSelf) {
#pragma unroll
    for (int ct = 0; ct < 4; ++ct) {
      h8 b0 = uph8(*(const uint4*)(FbotSelf + ((ct * 2 + 0) * 64 + lane) * 4));
      h8 b1 = uph8(*(const uint4*)(FbotSelf + ((ct * 2 + 1) * 64 + lane) * 4));
      f4 c = {0.f, 0.f, 0.f, 0.f};
      c = __builtin_amdgcn_mfma_f32_16x16x32_f16(a0c, b0, c, 0, 0, 0);
      c = __builtin_amdgcn_mfma_f32_16x16x32_f16(a1c, b1, c, 0, 0, 0);
      float bias = decbSelf[ct * 16 + l15];
      // fp16-round to match the gathered-lT path's precision semantics
#pragma unroll
      for (int r = 0; r < 4; ++r) lv[r][ct] = (float)(_Float16)(c[r] + bias);
    }
  }

  // phase 1: skip = lrelu(cur @ mlpW + mlpb)
  float sk[4][4];
  {
#pragma unroll
    for (int ct = 0; ct < 4; ++ct) {
      h8 b0 = uph8(*(const uint4*)(Fmlp + ((ct * 2 + 0) * 64 + lane) * 4));
      h8 b1 = uph8(*(const uint4*)(Fmlp + ((ct * 2 + 1) * 64 + lane) * 4));
      f4 c = {0.f, 0.f, 0.f, 0.f};
      c = __builtin_amdgcn_mfma_f32_16x16x32_f16(a0c, b0, c, 0, 0, 0);
      c = __builtin_amdgcn_mfma_f32_16x16x32_f16(a1c, b1, c, 0, 0, 0);
      float bias = mlpb[ct * 16 + l15];
#pragma unroll
      for (int r = 0; r < 4; ++r) sk[ct][r] = lrelu(c[r] + bias);
    }
  }
  __syncthreads();
#pragma unroll
  for (int ct = 0; ct < 4; ++ct) {
#pragma unroll
    for (int r = 0; r < 4; ++r)
      H[(16 * w + lg * 4 + r) * 72 + ct * 16 + l15] = (_Float16)sk[ct][r];
  }
  __syncthreads();

  // phase 2: out = skip @ decTop + last, BN, lrelu -> oF (LDS)
  float fv[4][4];
  {
    h8 a0 = uph8(*(const uint4*)(P + arow * 36 + 0 * 16 + lg * 4));
    h8 a1 = uph8(*(const uint4*)(P + arow * 36 + 1 * 16 + lg * 4));
#pragma unroll
    for (int ct = 0; ct < 4; ++ct) {
      h8 b0 = uph8(*(const uint4*)(Ftop + ((ct * 2 + 0) * 64 + lane) * 4));
      h8 b1 = uph8(*(const uint4*)(Ftop + ((ct * 2 + 1) * 64 + lane) * 4));
      f4 c = {0.f, 0.f, 0.f, 0.f};
      c = __builtin_amdgcn_mfma_f32_16x16x32_f16(a0, b0, c, 0, 0, 0);
      c = __builtin_amdgcn_mfma_f32_16x16x32_f16(a1, b1, c, 0, 0, 0);
      int col = ct * 16 + l15;
      float sc = fold[col], sh = fold[64 + col];
#pragma unroll
      for (int r = 0; r < 4; ++r) {
        float ov = (c[r] + lv[r][ct]) * sc + sh;
        fv[ct][r] = lrelu(ov);
        oF[(16 * w + lg * 4 + r) * 68 + col] = fv[ct][r];
      }
    }
  }
  __syncthreads();
  // coalesced nontemporal fp32 final store (finals are never re-read)
  for (int f = t; f < 1024; f += 256) {
    int row = f >> 4, c4 = (f & 15) << 2;
    int gr = R + row;
    if (gr < n) {
      const float* src = oF + row * 68 + c4;
      float* dst = outF + (size_t)gr * 64 + c4;
      __builtin_nontemporal_store(src[0], dst + 0);
      __builtin_nontemporal_store(src[1], dst + 1);
      __builtin_nontemporal_store(src[2], dst + 2);
      __builtin_nontemporal_store(src[3], dst + 3);
    }
  }

  // phase 3 (optional): lTout = out @ decNextBot + decbN (fp16)
  if (FnextBot) {
    __syncthreads();
#pragma unroll
    for (int ct = 0; ct < 4; ++ct) {
#pragma unroll
      for (int r = 0; r < 4; ++r)
        H[(16 * w + lg * 4 + r) * 72 + ct * 16 + l15] = (_Float16)fv[ct][r];
    }
    __syncthreads();
    h8 a0 = uph8(*(const uint4*)(P + arow * 36 + 0 * 16 + lg * 4));
    h8 a1 = uph8(*(const uint4*)(P + arow * 36 + 1 * 16 + lg * 4));
#pragma unroll
    for (int ct = 0; ct < 4; ++ct) {
      h8 b0 = uph8(*(const uint4*)(FnextBot + ((ct * 2 + 0) * 64 + lane) * 4));
      h8 b1 = uph8(*(const uint4*)(FnextBot + ((ct * 2 + 1) * 64 + lane) * 4));
      f4 c = {0.f, 0.f, 0.f, 0.f};
      c = __builtin_amdgcn_mfma_f32_16x16x32_f16(a0, b0, c, 0, 0, 0);
      c = __builtin_amdgcn_mfma_f32_16x16x32_f16(a1, b1, c, 0, 0, 0);
      int col = ct * 16 + l15;
      float bias = decbN[col];
#pragma unroll
      for (int r = 0; r < 4; ++r)
        if (grow_[r] < n) lTout[(size_t)grow_[r] * 64 + col] = (_Float16)(c[r] + bias);
    }
  }
}

extern "C" void kernel_launch(void* const* d_in, const int* in_sizes, int n_in,
                              void* d_out, int out_size, void* d_ws, size_t ws_size,
                              hipStream_t stream) {
  const float* pt   = (const float*)d_in[0];
  const int* inv2   = (const int*)d_in[1];
  const int* inv4   = (const int*)d_in[2];
  const int* inv8   = (const int*)d_in[3];
  const int* inv16  = (const int*)d_in[4];
  const float* e0W1 = (const float*)d_in[5];
  const float* e0b1 = (const float*)d_in[6];
  const float* e0g  = (const float*)d_in[7];
  const float* e0be = (const float*)d_in[8];
  const float* e0m  = (const float*)d_in[9];
  const float* e0v  = (const float*)d_in[10];
  const float* e0W2 = (const float*)d_in[11];
  const float* e0b2 = (const float*)d_in[12];
  const float* eRW1 = (const float*)d_in[13];
  const float* eRb1 = (const float*)d_in[14];
  const float* eRg  = (const float*)d_in[15];
  const float* eRbe = (const float*)d_in[16];
  const float* eRm  = (const float*)d_in[17];
  const float* eRv  = (const float*)d_in[18];
  const float* eRW2 = (const float*)d_in[19];
  const float* eRb2 = (const float*)d_in[20];
  const float* mlpW = (const float*)d_in[21];
  const float* mlpb = (const float*)d_in[22];
  const float* decW = (const float*)d_in[23];
  const float* decb = (const float*)d_in[24];
  const float* decg = (const float*)d_in[25];
  const float* decbe= (const float*)d_in[26];
  const float* decm = (const float*)d_in[27];
  const float* decv = (const float*)d_in[28];

  float* s1 = (float*)d_out;
  float* s2 = s1 + (size_t)N1 * 64;
  float* s3 = s2 + (size_t)N2 * 64;
  float* s4 = s3 + (size_t)N4 * 64;
  float* s5 = s4 + (size_t)N8 * 64;

  // ws: fold | frag packs | pH1..pH5 | lTA | lTB | heads (contig) | nxts
  float* fold = (float*)d_ws;
  unsigned* F_e0W2 = (unsigned*)(fold + 1024);   // 1024 u
  unsigned* F_eRW1 = F_e0W2 + 1024;              // 4096 u
  unsigned* F_eRW2 = F_eRW1 + 4096;              // 4096 u
  unsigned* F_mlp  = F_eRW2 + 4096;              // 10240 u
  unsigned* F_top  = F_mlp + 10240;              // 10240 u
  unsigned* F_bot  = F_top + 10240;              // 10240 u
  unsigned* pH1 = F_bot + 10240;                 // N1*32 u
  unsigned* pH2 = pH1 + (size_t)N1 * 32;         // N2*32 u
  unsigned* pH3 = pH2 + (size_t)N2 * 32;         // N4*32 u
  unsigned* pH4 = pH3 + (size_t)N4 * 32;         // N8*32 u
  unsigned* pH5 = pH4 + (size_t)N8 * 32;         // N16*32 u
  _Float16* lTA = (_Float16*)(pH5 + (size_t)N16 * 32);  // N2*64 h
  _Float16* lTB = lTA + (size_t)N2 * 64;                // N4*64 h
  int* hd2 = (int*)(lTB + (size_t)N4 * 64);      // N2
  int* hd3 = hd2 + N2;                           // N4
  int* hd4 = hd3 + N4;                           // N8
  int* hd5 = hd4 + N8;                           // N16
  int* nx1 = hd5 + N16;                          // N1
  int* nx2 = nx1 + N1;                           // N2
  int* nx3 = nx2 + N2;                           // N4
  int* nx4 = nx3 + N4;                           // N8

  k_prep<<<(40256 + 255) / 256, 256, 0, stream>>>(
      e0W2, eRW1, eRW2, mlpW, decW,
      e0g, e0be, e0m, e0v, eRg, eRbe, eRm, eRv, decg, decbe, decm, decv,
      fold, F_e0W2, F_eRW1, F_eRW2, F_mlp, F_top, F_bot);

  hipMemsetAsync(hd2, 0xFF, (size_t)(N2 + N4 + N8 + N16) * 4, stream);
  k_fill_all<<<(N1 + N2 + N4 + N8 + 255) / 256, 256, 0, stream>>>(
      inv2, inv4, inv8, inv16, hd2, hd3, hd4, hd5, nx1, nx2, nx3, nx4);

  // ---- encoders (fused pooling) ----
  k_enc0_m<<<(N1 + 63) / 64, 256, 0, stream>>>(pt, e0W1, e0b1, fold, F_e0W2, e0b2, pH1, N1);
  k_encR_m<<<(N2 + 63) / 64, 256, 0, stream>>>(pH1, hd2, nx1,
                                               F_eRW1 + 0 * 1024, eRb1 + 0 * 32,
                                               fold + 64 + 0 * 64, F_eRW2 + 0 * 1024,
                                               eRb2 + 0 * 64, pH2, N2);
  k_encR_m<<<(N4 + 63) / 64, 256, 0, stream>>>(pH2, hd3, nx2,
                                               F_eRW1 + 1 * 1024, eRb1 + 1 * 32,
                                               fold + 64 + 1 * 64, F_eRW2 + 1 * 1024,
                                               eRb2 + 1 * 64, pH3, N4);
  k_encR_m<<<(N8 + 63) / 64, 256, 0, stream>>>(pH3, hd4, nx3,
                                               F_eRW1 + 2 * 1024, eRb1 + 2 * 32,
                                               fold + 64 + 2 * 64, F_eRW2 + 2 * 1024,
                                               eRb2 + 2 * 64, pH4, N8);
  k_encR_m<<<(N16 + 63) / 64, 256, 0, stream>>>(pH4, hd5, nx4,
                                                F_eRW1 + 3 * 1024, eRb1 + 3 * 32,
                                                fold + 64 + 3 * 64, F_eRW2 + 3 * 1024,
                                                eRb2 + 3 * 64, pH5, N16);

  // ---- decoders: level 0 computes its own `last` in-kernel (phase 0) ----
  k_dec2_m<<<(N16 + 63) / 64, 256, 0, stream>>>(pH5, s5, nullptr, nullptr,
                                                F_bot + 0 * 2048, decb + 0 * 64,
                                                F_mlp + 0 * 2048, mlpb + 0 * 64,
                                                F_top + 0 * 2048, fold + 320 + 0 * 128, N16,
                                                F_bot + 1 * 2048, decb + 1 * 64, lTB);
  k_dec2_m<<<(N8 + 63) / 64, 256, 0, stream>>>(pH4, s4, lTB, inv16, nullptr, nullptr,
                                               F_mlp + 1 * 2048, mlpb + 1 * 64,
                                               F_top + 1 * 2048, fold + 320 + 1 * 128, N8,
                                               F_bot + 2 * 2048, decb + 2 * 64, lTA);
  k_dec2_m<<<(N4 + 63) / 64, 256, 0, stream>>>(pH3, s3, lTA, inv8, nullptr, nullptr,
                                               F_mlp + 2 * 2048, mlpb + 2 * 64,
                                               F_top + 2 * 2048, fold + 320 + 2 * 128, N4,
                                               F_bot + 3 * 2048, decb + 3 * 64, lTB);
  k_dec2_m<<<(N2 + 63) / 64, 256, 0, stream>>>(pH2, s2, lTB, inv4, nullptr, nullptr,
                                               F_mlp + 3 * 2048, mlpb + 3 * 64,
                                               F_top + 3 * 2048, fold + 320 + 3 * 128, N2,
                                               F_bot + 4 * 2048, decb + 4 * 64, lTA);
  k_dec2_m<<<(N1 + 63) / 64, 256, 0, stream>>>(pH1, s1, lTA, inv2, nullptr, nullptr,
                                               F_mlp + 4 * 2048, mlpb + 4 * 64,
                                               F_top + 4 * 2048, fold + 320 + 4 * 128, N1,
                                               nullptr, nullptr, nullptr);
}